// Round 2
// baseline (6092.384 us; speedup 1.0000x reference)
//
#include <hip/hip_runtime.h>
#include <math.h>

// ---------------- sizes ----------------
// x: [32,3,128,128]; conv1 (k4 s2) -> [32,256,63,63]; conv2 (k2 s1) -> [32,256,62,62]
// dt1 (convT k2 s1) -> [32,256,63,63]; dt2 (convT k4 s2) -> [32,3,128,128]
#define NB 32
#define HID 256
#define HW1 (63*63)      // 3969
#define HW2 (62*62)      // 3844
#define T63 ((size_t)NB*HID*HW1)   // 32,514,048
#define T62 ((size_t)NB*HID*HW2)   // 31,490,048
#define NROWS 123008               // T62 / 256
#define KCB 512

// ---------------- zero small scratch (sse + counts) ----------------
__global__ __launch_bounds__(256) void zero_small(float* __restrict__ sse, int* __restrict__ counts) {
    if (threadIdx.x == 0) sse[0] = 0.f;
    for (int i = threadIdx.x; i < KCB; i += 256) counts[i] = 0;
}

// ---------------- conv1: 3->256, k4, s2, bias, relu ----------------
__global__ __launch_bounds__(256) void conv1_relu(
    const float* __restrict__ x, const float* __restrict__ w,
    const float* __restrict__ bias, float* __restrict__ out) {
    int b = blockIdx.x >> 8, co = blockIdx.x & 255;
    int ow = threadIdx.x & 63, oh = (blockIdx.y << 2) + (threadIdx.x >> 6);
    __shared__ float ws[48];
    if (threadIdx.x < 48) ws[threadIdx.x] = w[co*48 + threadIdx.x];
    __syncthreads();
    if (ow >= 63 || oh >= 63) return;
    float acc = bias[co];
    const float* xb = x + (size_t)b*3*128*128;
    int ih0 = oh*2, iw0 = ow*2;
    #pragma unroll
    for (int ci = 0; ci < 3; ++ci)
      #pragma unroll
      for (int kh = 0; kh < 4; ++kh) {
        const float* row = xb + ((size_t)ci*128 + ih0+kh)*128 + iw0;
        #pragma unroll
        for (int kw = 0; kw < 4; ++kw)
            acc = fmaf(row[kw], ws[ci*16+kh*4+kw], acc);
      }
    out[((size_t)(b*HID+co)*63 + oh)*63 + ow] = fmaxf(acc, 0.f);
}

// ---------------- global average pool over spatial ----------------
__global__ __launch_bounds__(256) void gap_kernel(
    const float* __restrict__ x, float* __restrict__ pooled, int HW) {
    int bc = blockIdx.x;
    const float* p = x + (size_t)bc*HW;
    float s = 0.f;
    for (int i = threadIdx.x; i < HW; i += 256) s += p[i];
    __shared__ float lds[4];
    for (int off = 32; off; off >>= 1) s += __shfl_down(s, off, 64);
    if ((threadIdx.x & 63) == 0) lds[threadIdx.x >> 6] = s;
    __syncthreads();
    if (threadIdx.x == 0) pooled[bc] = (lds[0]+lds[1]+lds[2]+lds[3]) / (float)HW;
}

// ---------------- SE MLP: g = sigmoid(relu(s@w1.T+b1)@w2.T+b2) ----------------
__global__ __launch_bounds__(256) void se_mlp(
    const float* __restrict__ pooled, const float* __restrict__ w1,
    const float* __restrict__ b1, const float* __restrict__ w2,
    const float* __restrict__ b2, float* __restrict__ g) {
    int b = blockIdx.x;
    __shared__ float ps[256], hs[16];
    ps[threadIdx.x] = pooled[b*256 + threadIdx.x];
    __syncthreads();
    if (threadIdx.x < 16) {
        float a = b1[threadIdx.x];
        const float* wr = w1 + threadIdx.x*256;
        for (int k = 0; k < 256; ++k) a = fmaf(ps[k], wr[k], a);
        hs[threadIdx.x] = fmaxf(a, 0.f);
    }
    __syncthreads();
    float a = b2[threadIdx.x];
    const float* wr = w2 + threadIdx.x*16;
    #pragma unroll
    for (int j = 0; j < 16; ++j) a = fmaf(hs[j], wr[j], a);
    g[b*256 + threadIdx.x] = 1.f / (1.f + expf(-a));
}

// ---------------- channel mean/max of x*g ----------------
__global__ __launch_bounds__(256) void chanpool(
    const float* __restrict__ x, const float* __restrict__ g,
    float* __restrict__ am, int HW) {
    int b = blockIdx.y;
    int p = blockIdx.x*256 + threadIdx.x;
    if (p >= HW) return;
    const float* xb = x + (size_t)b*256*HW + p;
    const float* gb = g + b*256;
    float s = 0.f, mx = -3.0e38f;
    for (int c = 0; c < 256; ++c) {
        float v = xb[(size_t)c*HW] * gb[c];
        s += v; mx = fmaxf(mx, v);
    }
    am[((size_t)b*2)*HW + p]   = s * (1.f/256.f);
    am[((size_t)b*2+1)*HW + p] = mx;
}

// ---------------- 7x7 spatial conv on [mean,max], sigmoid ----------------
__global__ __launch_bounds__(256) void spatial_conv(
    const float* __restrict__ am, const float* __restrict__ sw,
    float* __restrict__ ss, int H, int W, int transpose) {
    int b = blockIdx.y;
    int p = blockIdx.x*256 + threadIdx.x;
    __shared__ float ws[98];
    if (threadIdx.x < 98) {
        int c = threadIdx.x / 49, k = threadIdx.x % 49;
        int kh = k / 7, kw = k % 7;
        ws[threadIdx.x] = transpose ? sw[c*49 + (6-kh)*7 + (6-kw)]
                                    : sw[c*49 + kh*7 + kw];
    }
    __syncthreads();
    if (p >= H*W) return;
    int oh = p / W, ow = p % W;
    float acc = 0.f;
    #pragma unroll
    for (int c = 0; c < 2; ++c) {
        const float* ab = am + ((size_t)b*2 + c)*H*W;
        for (int kh = 0; kh < 7; ++kh) {
            int ih = oh + kh - 3;
            if (ih < 0 || ih >= H) continue;
            for (int kw = 0; kw < 7; ++kw) {
                int iw = ow + kw - 3;
                if (iw < 0 || iw >= W) continue;
                acc = fmaf(ab[(size_t)ih*W + iw], ws[c*49 + kh*7 + kw], acc);
            }
        }
    }
    ss[(size_t)b*H*W + p] = 1.f / (1.f + expf(-acc));
}

// ---------------- IN-PLACE: x = x*x*g*sig(s) ----------------
__global__ __launch_bounds__(256) void cbam_final(
    float* x, const float* __restrict__ g,
    const float* __restrict__ ss, int HW) {
    int b = blockIdx.y;
    size_t e = (size_t)blockIdx.x*256 + threadIdx.x;
    if (e >= (size_t)256*HW) return;
    int c = (int)(e / HW), p = (int)(e % HW);
    float* px = x + (size_t)b*256*HW + e;
    float xv = *px;
    *px = xv * xv * g[b*256+c] * ss[(size_t)b*HW + p];
}

// ---------------- tiled GEMM conv, k=2, stride 1 (conv2 & dt1) ----------------
__global__ __launch_bounds__(256) void convk2_gemm(
    const float* __restrict__ in, const float* __restrict__ Wc,
    const float* __restrict__ bias, float* __restrict__ out,
    int inH, int inW, int outH, int outW, int pad) {
    int b = blockIdx.y;
    int cg = blockIdx.x >> 6;
    int t  = blockIdx.x & 63;
    int oh0 = (t >> 3) * 8, ow0 = (t & 7) * 8;
    int co0 = cg * 64;
    __shared__ __align__(16) float As[64*68];
    __shared__ __align__(16) float Bs[16*108];   // [16][9][12]
    int it = threadIdx.x >> 4, jt = threadIdx.x & 15;
    int jh = jt >> 2, jw = jt & 3;
    int r0 = jh*2, c0 = jw*2;
    float acc[4][4] = {};
    const float* inb = in + (size_t)b*256*inH*inW;
    for (int cc = 0; cc < 16; ++cc) {
        int ci0 = cc*16;
        __syncthreads();
        for (int tt = threadIdx.x; tt < 16*81; tt += 256) {
            int ci = tt / 81, rc = tt % 81, r = rc / 9, c = rc % 9;
            int gh = oh0 + r - pad, gw = ow0 + c - pad;
            float v = 0.f;
            if (gh >= 0 && gh < inH && gw >= 0 && gw < inW)
                v = inb[((size_t)(ci0+ci)*inH + gh)*inW + gw];
            Bs[ci*108 + r*12 + c] = v;
        }
        #pragma unroll
        for (int k = 0; k < 16; ++k) {
            int t2 = k*256 + threadIdx.x;
            int co = t2 >> 6, l = t2 & 63;
            As[co*68 + l] = Wc[(size_t)(co0+co)*1024 + ci0*4 + l];
        }
        __syncthreads();
        #pragma unroll 4
        for (int ci = 0; ci < 16; ++ci) {
            float patch[3][4];
            #pragma unroll
            for (int r = 0; r < 3; ++r) {
                float2 u = *(const float2*)&Bs[ci*108 + (r0+r)*12 + c0];
                float2 v = *(const float2*)&Bs[ci*108 + (r0+r)*12 + c0 + 2];
                patch[r][0]=u.x; patch[r][1]=u.y; patch[r][2]=v.x; patch[r][3]=v.y;
            }
            float4 A0 = *(const float4*)&As[(it+ 0)*68 + ci*4];
            float4 A1 = *(const float4*)&As[(it+16)*68 + ci*4];
            float4 A2 = *(const float4*)&As[(it+32)*68 + ci*4];
            float4 A3 = *(const float4*)&As[(it+48)*68 + ci*4];
            float av[4][4] = {{A0.x,A0.y,A0.z,A0.w},{A1.x,A1.y,A1.z,A1.w},
                              {A2.x,A2.y,A2.z,A2.w},{A3.x,A3.y,A3.z,A3.w}};
            #pragma unroll
            for (int tap = 0; tap < 4; ++tap) {
                int kh = tap >> 1, kw = tap & 1;
                float bv[4] = { patch[kh][kw],   patch[kh][kw+1],
                                patch[kh+1][kw], patch[kh+1][kw+1] };
                #pragma unroll
                for (int m = 0; m < 4; ++m)
                    #pragma unroll
                    for (int n = 0; n < 4; ++n)
                        acc[m][n] = fmaf(av[m][tap], bv[n], acc[m][n]);
            }
        }
    }
    #pragma unroll
    for (int m = 0; m < 4; ++m) {
        int co = co0 + it + 16*m;
        float bz = bias[co];
        #pragma unroll
        for (int n = 0; n < 4; ++n) {
            int oh = oh0 + r0 + (n >> 1), ow = ow0 + c0 + (n & 1);
            if (oh < outH && ow < outW)
                out[((size_t)(b*256+co)*outH + oh)*outW + ow] = fmaxf(acc[m][n] + bz, 0.f);
        }
    }
}

// ---------------- repack dt1 weights -> canonical [co][ci][kh][kw] ----------------
__global__ __launch_bounds__(256) void repack_dt1(
    const float* __restrict__ w, float* __restrict__ Wc) {
    int t = blockIdx.x*256 + threadIdx.x;
    if (t >= 256*256*4) return;
    int kw = t & 1, kh = (t >> 1) & 1, ci = (t >> 2) & 255, co = t >> 10;
    Wc[t] = w[((size_t)ci*256 + co)*4 + (1-kh)*2 + (1-kw)];
}

// ---------------- codebook norms ----------------
__global__ __launch_bounds__(256) void cb_norm(
    const float* __restrict__ cb, float* __restrict__ cbn) {
    for (int n = threadIdx.x; n < KCB; n += 256) {
        float s = 0.f;
        for (int k = 0; k < 256; ++k) { float v = cb[(size_t)n*256+k]; s = fmaf(v,v,s); }
        cbn[n] = s;
    }
}

// ---------------- VQ assign: argmin_n (cbn[n] - 2*z.cb[n]) ----------------
__global__ __launch_bounds__(256) void vq_assign(
    const float* __restrict__ z, const float* __restrict__ cb,
    const float* __restrict__ cbn, int* __restrict__ idx) {
    __shared__ __align__(16) float zs[16*260];
    __shared__ __align__(16) float cbs[16*260];
    int r0 = blockIdx.x * 16;
    for (int t = threadIdx.x; t < 4096; t += 256) {
        int r = t >> 8, k = t & 255;
        zs[r*260 + k] = z[(size_t)(r0+r)*256 + k];
    }
    int rl = threadIdx.x >> 4, nl = threadIdx.x & 15;
    float bd = 3.0e38f; int bi = 0;
    for (int nc = 0; nc < 32; ++nc) {
        __syncthreads();
        for (int t = threadIdx.x; t < 4096; t += 256) {
            int n = t >> 8, k = t & 255;
            cbs[n*260 + k] = cb[(size_t)(nc*16+n)*256 + k];
        }
        __syncthreads();
        float acc = 0.f;
        #pragma unroll 8
        for (int k = 0; k < 256; k += 4) {
            float4 zv = *(const float4*)&zs[rl*260 + k];
            float4 cv = *(const float4*)&cbs[nl*260 + k];
            acc = fmaf(zv.x, cv.x, acc); acc = fmaf(zv.y, cv.y, acc);
            acc = fmaf(zv.z, cv.z, acc); acc = fmaf(zv.w, cv.w, acc);
        }
        int n = nc*16 + nl;
        float dist = cbn[n] - 2.f*acc;
        if (dist < bd) { bd = dist; bi = n; }
    }
    for (int off = 8; off; off >>= 1) {
        float od = __shfl_xor(bd, off, 64);
        int   oi = __shfl_xor(bi, off, 64);
        if (od < bd || (od == bd && oi < bi)) { bd = od; bi = oi; }
    }
    if (nl == 0) idx[r0 + rl] = bi;
}

// ---------------- IN-PLACE VQ gather + sse + histogram: zq row -> code row ----------------
__global__ __launch_bounds__(256) void vq_gather(
    float* zq, const float* __restrict__ cb,
    const int* __restrict__ idx, float* __restrict__ sse, int* __restrict__ counts) {
    int r = blockIdx.x;
    int id = idx[r];
    float qv = cb[(size_t)id*256 + threadIdx.x];
    float* pz = zq + (size_t)r*256 + threadIdx.x;
    float zv = *pz;
    *pz = qv;
    float d = qv - zv; d *= d;
    __shared__ float lds[4];
    for (int off = 32; off; off >>= 1) d += __shfl_down(d, off, 64);
    if ((threadIdx.x & 63) == 0) lds[threadIdx.x >> 6] = d;
    __syncthreads();
    if (threadIdx.x == 0) {
        atomicAdd(sse, lds[0]+lds[1]+lds[2]+lds[3]);
        atomicAdd(counts + id, 1);
    }
}

// ---------------- loss + perplexity ----------------
__global__ __launch_bounds__(256) void vq_finalize(
    const float* __restrict__ sse, const int* __restrict__ counts,
    float* __restrict__ out) {
    __shared__ float lds[4];
    float h = 0.f;
    for (int n = threadIdx.x; n < KCB; n += 256) {
        float p = (float)counts[n] * (1.f/123008.f);
        h += p * logf(p + 1e-10f);
    }
    for (int off = 32; off; off >>= 1) h += __shfl_down(h, off, 64);
    if ((threadIdx.x & 63) == 0) lds[threadIdx.x >> 6] = h;
    __syncthreads();
    if (threadIdx.x == 0) {
        out[1572864] = 1.25f * sse[0] / 31490048.f;
        out[1572865] = expf(-(lds[0]+lds[1]+lds[2]+lds[3]));
    }
}

// ---------------- dt2: convT 256->3, k4, s2 ----------------
__global__ __launch_bounds__(256) void dt2_kernel(
    const float* __restrict__ d, const float* __restrict__ w,
    const float* __restrict__ bias, float* __restrict__ out) {
    int b = blockIdx.y;
    int co = blockIdx.x / 64;
    int h = (blockIdx.x % 64)*2 + (threadIdx.x >> 7);
    int wpos = threadIdx.x & 127;
    __shared__ float ws[4096];
    for (int t = threadIdx.x; t < 4096; t += 256) {
        int ci = t >> 4, k = t & 15;
        ws[t] = w[(size_t)ci*48 + co*16 + k];
    }
    __syncthreads();
    int kh0 = h & 1, kw0 = wpos & 1;
    int ih0 = (h - kh0) >> 1, iw0 = (wpos - kw0) >> 1;
    bool vh0 = (ih0 < 63), vh1 = (ih0 >= 1);
    bool vw0 = (iw0 < 63), vw1 = (iw0 >= 1);
    float acc = bias[co];
    const float* db = d + (size_t)b*256*HW1;
    for (int ci = 0; ci < 256; ++ci) {
        const float* dc = db + (size_t)ci*HW1;
        const float* wc = ws + ci*16;
        float v00 = (vh0 && vw0) ? dc[ih0*63 + iw0]       : 0.f;
        float v01 = (vh0 && vw1) ? dc[ih0*63 + iw0 - 1]   : 0.f;
        float v10 = (vh1 && vw0) ? dc[(ih0-1)*63 + iw0]   : 0.f;
        float v11 = (vh1 && vw1) ? dc[(ih0-1)*63 + iw0-1] : 0.f;
        acc = fmaf(v00, wc[kh0*4 + kw0],         acc);
        acc = fmaf(v01, wc[kh0*4 + kw0 + 2],     acc);
        acc = fmaf(v10, wc[(kh0+2)*4 + kw0],     acc);
        acc = fmaf(v11, wc[(kh0+2)*4 + kw0 + 2], acc);
    }
    out[((size_t)(b*3+co)*128 + h)*128 + wpos] = acc;
}

// ---------------- launch ----------------
extern "C" void kernel_launch(void* const* d_in, const int* in_sizes, int n_in,
                              void* d_out, int out_size, void* d_ws, size_t ws_size,
                              hipStream_t stream) {
    const float* x      = (const float*)d_in[0];
    const float* ec1_w  = (const float*)d_in[1];
    const float* ec1_b  = (const float*)d_in[2];
    const float* ec2_w  = (const float*)d_in[3];
    const float* ec2_b  = (const float*)d_in[4];
    const float* se1_w1 = (const float*)d_in[5];
    const float* se1_b1 = (const float*)d_in[6];
    const float* se1_w2 = (const float*)d_in[7];
    const float* se1_b2 = (const float*)d_in[8];
    const float* sa1_w  = (const float*)d_in[9];
    const float* se2_w1 = (const float*)d_in[10];
    const float* se2_b1 = (const float*)d_in[11];
    const float* se2_w2 = (const float*)d_in[12];
    const float* se2_b2 = (const float*)d_in[13];
    const float* sa2_w  = (const float*)d_in[14];
    const float* cbk    = (const float*)d_in[15];
    const float* dt1_w  = (const float*)d_in[16];
    const float* dt1_b  = (const float*)d_in[17];
    const float* dt2_w  = (const float*)d_in[18];
    const float* dt2_b  = (const float*)d_in[19];
    const float* dse_w1 = (const float*)d_in[20];
    const float* dse_b1 = (const float*)d_in[21];
    const float* dse_w2 = (const float*)d_in[22];
    const float* dse_b2 = (const float*)d_in[23];
    const float* dsa_w  = (const float*)d_in[24];
    float* out = (float*)d_out;

    // Two big buffers only (~259 MB total): A=T63, C=T62; CBAM + VQ-gather in-place.
    float* A      = (float*)d_ws;
    float* C      = A + T63;
    float* pooled = C + T62;
    float* g      = pooled + 8192;
    float* am     = g + 8192;
    float* ssmap  = am + (size_t)NB*2*HW1;
    float* cbn    = ssmap + (size_t)NB*HW1;
    float* Wc     = cbn + 512;
    float* sse    = Wc + 262144;
    int*   counts = (int*)(sse + 1);
    int*   idx    = counts + 512;

    // prep
    zero_small<<<1, 256, 0, stream>>>(sse, counts);
    repack_dt1<<<1024, 256, 0, stream>>>(dt1_w, Wc);
    cb_norm<<<1, 256, 0, stream>>>(cbk, cbn);

    // encoder conv1 + cbam1 (in-place on A)
    conv1_relu<<<dim3(NB*256, 16), 256, 0, stream>>>(x, ec1_w, ec1_b, A);
    gap_kernel<<<NB*256, 256, 0, stream>>>(A, pooled, HW1);
    se_mlp<<<NB, 256, 0, stream>>>(pooled, se1_w1, se1_b1, se1_w2, se1_b2, g);
    chanpool<<<dim3(16, NB), 256, 0, stream>>>(A, g, am, HW1);
    spatial_conv<<<dim3(16, NB), 256, 0, stream>>>(am, sa1_w, ssmap, 63, 63, 0);
    cbam_final<<<dim3(HW1, NB), 256, 0, stream>>>(A, g, ssmap, HW1);

    // conv2 (A -> C) + cbam2 (in-place on C)  => z in C
    convk2_gemm<<<dim3(256, NB), 256, 0, stream>>>(A, ec2_w, ec2_b, C, 63, 63, 62, 62, 0);
    gap_kernel<<<NB*256, 256, 0, stream>>>(C, pooled, HW2);
    se_mlp<<<NB, 256, 0, stream>>>(pooled, se2_w1, se2_b1, se2_w2, se2_b2, g);
    chanpool<<<dim3(16, NB), 256, 0, stream>>>(C, g, am, HW2);
    spatial_conv<<<dim3(16, NB), 256, 0, stream>>>(am, sa2_w, ssmap, 62, 62, 0);
    cbam_final<<<dim3(HW2, NB), 256, 0, stream>>>(C, g, ssmap, HW2);

    // VQ: z in C -> q in C (in-place)
    vq_assign<<<NROWS/16, 256, 0, stream>>>(C, cbk, cbn, idx);
    vq_gather<<<NROWS, 256, 0, stream>>>(C, cbk, idx, sse, counts);
    vq_finalize<<<1, 256, 0, stream>>>(sse, counts, out);

    // decoder dt1 (C -> A) + cbam3 (in-place on A)
    convk2_gemm<<<dim3(256, NB), 256, 0, stream>>>(C, Wc, dt1_b, A, 62, 62, 63, 63, 1);
    gap_kernel<<<NB*256, 256, 0, stream>>>(A, pooled, HW1);
    se_mlp<<<NB, 256, 0, stream>>>(pooled, dse_w1, dse_b1, dse_w2, dse_b2, g);
    chanpool<<<dim3(16, NB), 256, 0, stream>>>(A, g, am, HW1);
    spatial_conv<<<dim3(16, NB), 256, 0, stream>>>(am, dsa_w, ssmap, 63, 63, 1);
    cbam_final<<<dim3(HW1, NB), 256, 0, stream>>>(A, g, ssmap, HW1);

    // final convT -> out
    dt2_kernel<<<dim3(192, NB), 256, 0, stream>>>(A, dt2_w, dt2_b, out);
}

// Round 3
// 4435.366 us; speedup vs baseline: 1.3736x; 1.3736x over previous
//
#include <hip/hip_runtime.h>
#include <math.h>

// ---------------- sizes ----------------
// x: [32,3,128,128]; conv1 (k4 s2) -> [32,256,63,63]; conv2 (k2 s1) -> [32,256,62,62]
// dt1 (convT k2 s1) -> [32,256,63,63]; dt2 (convT k4 s2) -> [32,3,128,128]
#define NB 32
#define HID 256
#define HW1 (63*63)      // 3969
#define HW2 (62*62)      // 3844
#define T63 ((size_t)NB*HID*HW1)   // 32,514,048
#define T62 ((size_t)NB*HID*HW2)   // 31,490,048
#define NROWS 123008               // T62 / 256
#define KCB 512
#define GATHER_BLOCKS 1024

// ---------------- zero small scratch (sse + counts) ----------------
__global__ __launch_bounds__(256) void zero_small(float* __restrict__ sse, int* __restrict__ counts) {
    if (threadIdx.x == 0) sse[0] = 0.f;
    for (int i = threadIdx.x; i < KCB; i += 256) counts[i] = 0;
}

// ---------------- conv1: 3->256, k4, s2, bias, relu ----------------
__global__ __launch_bounds__(256) void conv1_relu(
    const float* __restrict__ x, const float* __restrict__ w,
    const float* __restrict__ bias, float* __restrict__ out) {
    int b = blockIdx.x >> 8, co = blockIdx.x & 255;
    int ow = threadIdx.x & 63, oh = (blockIdx.y << 2) + (threadIdx.x >> 6);
    __shared__ float ws[48];
    if (threadIdx.x < 48) ws[threadIdx.x] = w[co*48 + threadIdx.x];
    __syncthreads();
    if (ow >= 63 || oh >= 63) return;
    float acc = bias[co];
    const float* xb = x + (size_t)b*3*128*128;
    int ih0 = oh*2, iw0 = ow*2;
    #pragma unroll
    for (int ci = 0; ci < 3; ++ci)
      #pragma unroll
      for (int kh = 0; kh < 4; ++kh) {
        const float* row = xb + ((size_t)ci*128 + ih0+kh)*128 + iw0;
        #pragma unroll
        for (int kw = 0; kw < 4; ++kw)
            acc = fmaf(row[kw], ws[ci*16+kh*4+kw], acc);
      }
    out[((size_t)(b*HID+co)*63 + oh)*63 + ow] = fmaxf(acc, 0.f);
}

// ---------------- global average pool over spatial ----------------
__global__ __launch_bounds__(256) void gap_kernel(
    const float* __restrict__ x, float* __restrict__ pooled, int HW) {
    int bc = blockIdx.x;
    const float* p = x + (size_t)bc*HW;
    float s = 0.f;
    for (int i = threadIdx.x; i < HW; i += 256) s += p[i];
    __shared__ float lds[4];
    for (int off = 32; off; off >>= 1) s += __shfl_down(s, off, 64);
    if ((threadIdx.x & 63) == 0) lds[threadIdx.x >> 6] = s;
    __syncthreads();
    if (threadIdx.x == 0) pooled[bc] = (lds[0]+lds[1]+lds[2]+lds[3]) / (float)HW;
}

// ---------------- SE MLP: g = sigmoid(relu(s@w1.T+b1)@w2.T+b2) ----------------
__global__ __launch_bounds__(256) void se_mlp(
    const float* __restrict__ pooled, const float* __restrict__ w1,
    const float* __restrict__ b1, const float* __restrict__ w2,
    const float* __restrict__ b2, float* __restrict__ g) {
    int b = blockIdx.x;
    __shared__ float ps[256], hs[16];
    ps[threadIdx.x] = pooled[b*256 + threadIdx.x];
    __syncthreads();
    if (threadIdx.x < 16) {
        float a = b1[threadIdx.x];
        const float* wr = w1 + threadIdx.x*256;
        for (int k = 0; k < 256; ++k) a = fmaf(ps[k], wr[k], a);
        hs[threadIdx.x] = fmaxf(a, 0.f);
    }
    __syncthreads();
    float a = b2[threadIdx.x];
    const float* wr = w2 + threadIdx.x*16;
    #pragma unroll
    for (int j = 0; j < 16; ++j) a = fmaf(hs[j], wr[j], a);
    g[b*256 + threadIdx.x] = 1.f / (1.f + expf(-a));
}

// ---------------- channel mean/max of x*g ----------------
__global__ __launch_bounds__(256) void chanpool(
    const float* __restrict__ x, const float* __restrict__ g,
    float* __restrict__ am, int HW) {
    int b = blockIdx.y;
    int p = blockIdx.x*256 + threadIdx.x;
    if (p >= HW) return;
    const float* xb = x + (size_t)b*256*HW + p;
    const float* gb = g + b*256;
    float s = 0.f, mx = -3.0e38f;
    for (int c = 0; c < 256; ++c) {
        float v = xb[(size_t)c*HW] * gb[c];
        s += v; mx = fmaxf(mx, v);
    }
    am[((size_t)b*2)*HW + p]   = s * (1.f/256.f);
    am[((size_t)b*2+1)*HW + p] = mx;
}

// ---------------- 7x7 spatial conv on [mean,max], sigmoid ----------------
__global__ __launch_bounds__(256) void spatial_conv(
    const float* __restrict__ am, const float* __restrict__ sw,
    float* __restrict__ ss, int H, int W, int transpose) {
    int b = blockIdx.y;
    int p = blockIdx.x*256 + threadIdx.x;
    __shared__ float ws[98];
    if (threadIdx.x < 98) {
        int c = threadIdx.x / 49, k = threadIdx.x % 49;
        int kh = k / 7, kw = k % 7;
        ws[threadIdx.x] = transpose ? sw[c*49 + (6-kh)*7 + (6-kw)]
                                    : sw[c*49 + kh*7 + kw];
    }
    __syncthreads();
    if (p >= H*W) return;
    int oh = p / W, ow = p % W;
    float acc = 0.f;
    #pragma unroll
    for (int c = 0; c < 2; ++c) {
        const float* ab = am + ((size_t)b*2 + c)*H*W;
        for (int kh = 0; kh < 7; ++kh) {
            int ih = oh + kh - 3;
            if (ih < 0 || ih >= H) continue;
            for (int kw = 0; kw < 7; ++kw) {
                int iw = ow + kw - 3;
                if (iw < 0 || iw >= W) continue;
                acc = fmaf(ab[(size_t)ih*W + iw], ws[c*49 + kh*7 + kw], acc);
            }
        }
    }
    ss[(size_t)b*H*W + p] = 1.f / (1.f + expf(-acc));
}

// ---------------- IN-PLACE: x = x*x*g*sig(s) ----------------
__global__ __launch_bounds__(256) void cbam_final(
    float* x, const float* __restrict__ g,
    const float* __restrict__ ss, int HW) {
    int b = blockIdx.y;
    size_t e = (size_t)blockIdx.x*256 + threadIdx.x;
    if (e >= (size_t)256*HW) return;
    int c = (int)(e / HW), p = (int)(e % HW);
    float* px = x + (size_t)b*256*HW + e;
    float xv = *px;
    *px = xv * xv * g[b*256+c] * ss[(size_t)b*HW + p];
}

// ---------------- tiled GEMM conv, k=2, stride 1 (conv2 & dt1) ----------------
__global__ __launch_bounds__(256) void convk2_gemm(
    const float* __restrict__ in, const float* __restrict__ Wc,
    const float* __restrict__ bias, float* __restrict__ out,
    int inH, int inW, int outH, int outW, int pad) {
    int b = blockIdx.y;
    int cg = blockIdx.x >> 6;
    int t  = blockIdx.x & 63;
    int oh0 = (t >> 3) * 8, ow0 = (t & 7) * 8;
    int co0 = cg * 64;
    __shared__ __align__(16) float As[64*68];
    __shared__ __align__(16) float Bs[16*108];   // [16][9][12]
    int it = threadIdx.x >> 4, jt = threadIdx.x & 15;
    int jh = jt >> 2, jw = jt & 3;
    int r0 = jh*2, c0 = jw*2;
    float acc[4][4] = {};
    const float* inb = in + (size_t)b*256*inH*inW;
    for (int cc = 0; cc < 16; ++cc) {
        int ci0 = cc*16;
        __syncthreads();
        for (int tt = threadIdx.x; tt < 16*81; tt += 256) {
            int ci = tt / 81, rc = tt % 81, r = rc / 9, c = rc % 9;
            int gh = oh0 + r - pad, gw = ow0 + c - pad;
            float v = 0.f;
            if (gh >= 0 && gh < inH && gw >= 0 && gw < inW)
                v = inb[((size_t)(ci0+ci)*inH + gh)*inW + gw];
            Bs[ci*108 + r*12 + c] = v;
        }
        #pragma unroll
        for (int k = 0; k < 16; ++k) {
            int t2 = k*256 + threadIdx.x;
            int co = t2 >> 6, l = t2 & 63;
            As[co*68 + l] = Wc[(size_t)(co0+co)*1024 + ci0*4 + l];
        }
        __syncthreads();
        #pragma unroll 4
        for (int ci = 0; ci < 16; ++ci) {
            float patch[3][4];
            #pragma unroll
            for (int r = 0; r < 3; ++r) {
                float2 u = *(const float2*)&Bs[ci*108 + (r0+r)*12 + c0];
                float2 v = *(const float2*)&Bs[ci*108 + (r0+r)*12 + c0 + 2];
                patch[r][0]=u.x; patch[r][1]=u.y; patch[r][2]=v.x; patch[r][3]=v.y;
            }
            float4 A0 = *(const float4*)&As[(it+ 0)*68 + ci*4];
            float4 A1 = *(const float4*)&As[(it+16)*68 + ci*4];
            float4 A2 = *(const float4*)&As[(it+32)*68 + ci*4];
            float4 A3 = *(const float4*)&As[(it+48)*68 + ci*4];
            float av[4][4] = {{A0.x,A0.y,A0.z,A0.w},{A1.x,A1.y,A1.z,A1.w},
                              {A2.x,A2.y,A2.z,A2.w},{A3.x,A3.y,A3.z,A3.w}};
            #pragma unroll
            for (int tap = 0; tap < 4; ++tap) {
                int kh = tap >> 1, kw = tap & 1;
                float bv[4] = { patch[kh][kw],   patch[kh][kw+1],
                                patch[kh+1][kw], patch[kh+1][kw+1] };
                #pragma unroll
                for (int m = 0; m < 4; ++m)
                    #pragma unroll
                    for (int n = 0; n < 4; ++n)
                        acc[m][n] = fmaf(av[m][tap], bv[n], acc[m][n]);
            }
        }
    }
    #pragma unroll
    for (int m = 0; m < 4; ++m) {
        int co = co0 + it + 16*m;
        float bz = bias[co];
        #pragma unroll
        for (int n = 0; n < 4; ++n) {
            int oh = oh0 + r0 + (n >> 1), ow = ow0 + c0 + (n & 1);
            if (oh < outH && ow < outW)
                out[((size_t)(b*256+co)*outH + oh)*outW + ow] = fmaxf(acc[m][n] + bz, 0.f);
        }
    }
}

// ---------------- repack dt1 weights -> canonical [co][ci][kh][kw] ----------------
__global__ __launch_bounds__(256) void repack_dt1(
    const float* __restrict__ w, float* __restrict__ Wc) {
    int t = blockIdx.x*256 + threadIdx.x;
    if (t >= 256*256*4) return;
    int kw = t & 1, kh = (t >> 1) & 1, ci = (t >> 2) & 255, co = t >> 10;
    Wc[t] = w[((size_t)ci*256 + co)*4 + (1-kh)*2 + (1-kw)];
}

// ---------------- codebook norms ----------------
__global__ __launch_bounds__(256) void cb_norm(
    const float* __restrict__ cb, float* __restrict__ cbn) {
    for (int n = threadIdx.x; n < KCB; n += 256) {
        float s = 0.f;
        for (int k = 0; k < 256; ++k) { float v = cb[(size_t)n*256+k]; s = fmaf(v,v,s); }
        cbn[n] = s;
    }
}

// ---------------- VQ assign: argmin_n (cbn[n] - 2*z.cb[n]) ----------------
__global__ __launch_bounds__(256) void vq_assign(
    const float* __restrict__ z, const float* __restrict__ cb,
    const float* __restrict__ cbn, int* __restrict__ idx) {
    __shared__ __align__(16) float zs[16*260];
    __shared__ __align__(16) float cbs[16*260];
    int r0 = blockIdx.x * 16;
    for (int t = threadIdx.x; t < 4096; t += 256) {
        int r = t >> 8, k = t & 255;
        zs[r*260 + k] = z[(size_t)(r0+r)*256 + k];
    }
    int rl = threadIdx.x >> 4, nl = threadIdx.x & 15;
    float bd = 3.0e38f; int bi = 0;
    for (int nc = 0; nc < 32; ++nc) {
        __syncthreads();
        for (int t = threadIdx.x; t < 4096; t += 256) {
            int n = t >> 8, k = t & 255;
            cbs[n*260 + k] = cb[(size_t)(nc*16+n)*256 + k];
        }
        __syncthreads();
        float acc = 0.f;
        #pragma unroll 8
        for (int k = 0; k < 256; k += 4) {
            float4 zv = *(const float4*)&zs[rl*260 + k];
            float4 cv = *(const float4*)&cbs[nl*260 + k];
            acc = fmaf(zv.x, cv.x, acc); acc = fmaf(zv.y, cv.y, acc);
            acc = fmaf(zv.z, cv.z, acc); acc = fmaf(zv.w, cv.w, acc);
        }
        int n = nc*16 + nl;
        float dist = cbn[n] - 2.f*acc;
        if (dist < bd) { bd = dist; bi = n; }
    }
    for (int off = 8; off; off >>= 1) {
        float od = __shfl_xor(bd, off, 64);
        int   oi = __shfl_xor(bi, off, 64);
        if (od < bd || (od == bd && oi < bi)) { bd = od; bi = oi; }
    }
    if (nl == 0) idx[r0 + rl] = bi;
}

// ---------------- IN-PLACE VQ gather: persistent blocks, LDS-privatized hist,
// ---------------- one SSE atomic per block (fixes 123k same-address atomics) ----------------
__global__ __launch_bounds__(256) void vq_gather(
    float* zq, const float* __restrict__ cb,
    const int* __restrict__ idx, float* __restrict__ sse, int* __restrict__ counts) {
    __shared__ int hist[KCB];
    for (int i = threadIdx.x; i < KCB; i += 256) hist[i] = 0;
    __syncthreads();
    float local = 0.f;
    for (int r = blockIdx.x; r < NROWS; r += GATHER_BLOCKS) {
        int id = idx[r];
        if (threadIdx.x == 0) atomicAdd(&hist[id], 1);
        float qv = cb[(size_t)id*256 + threadIdx.x];
        float* pz = zq + (size_t)r*256 + threadIdx.x;
        float zv = *pz;
        *pz = qv;
        float d = qv - zv;
        local = fmaf(d, d, local);
    }
    __shared__ float lds[4];
    for (int off = 32; off; off >>= 1) local += __shfl_down(local, off, 64);
    if ((threadIdx.x & 63) == 0) lds[threadIdx.x >> 6] = local;
    __syncthreads();
    if (threadIdx.x == 0) atomicAdd(sse, lds[0]+lds[1]+lds[2]+lds[3]);
    for (int i = threadIdx.x; i < KCB; i += 256) {
        int h = hist[i];
        if (h) atomicAdd(counts + i, h);
    }
}

// ---------------- loss + perplexity ----------------
__global__ __launch_bounds__(256) void vq_finalize(
    const float* __restrict__ sse, const int* __restrict__ counts,
    float* __restrict__ out) {
    __shared__ float lds[4];
    float h = 0.f;
    for (int n = threadIdx.x; n < KCB; n += 256) {
        float p = (float)counts[n] * (1.f/123008.f);
        h += p * logf(p + 1e-10f);
    }
    for (int off = 32; off; off >>= 1) h += __shfl_down(h, off, 64);
    if ((threadIdx.x & 63) == 0) lds[threadIdx.x >> 6] = h;
    __syncthreads();
    if (threadIdx.x == 0) {
        out[1572864] = 1.25f * sse[0] / 31490048.f;
        out[1572865] = expf(-(lds[0]+lds[1]+lds[2]+lds[3]));
    }
}

// ---------------- dt2: convT 256->3, k4, s2 ----------------
__global__ __launch_bounds__(256) void dt2_kernel(
    const float* __restrict__ d, const float* __restrict__ w,
    const float* __restrict__ bias, float* __restrict__ out) {
    int b = blockIdx.y;
    int co = blockIdx.x / 64;
    int h = (blockIdx.x % 64)*2 + (threadIdx.x >> 7);
    int wpos = threadIdx.x & 127;
    __shared__ float ws[4096];
    for (int t = threadIdx.x; t < 4096; t += 256) {
        int ci = t >> 4, k = t & 15;
        ws[t] = w[(size_t)ci*48 + co*16 + k];
    }
    __syncthreads();
    int kh0 = h & 1, kw0 = wpos & 1;
    int ih0 = (h - kh0) >> 1, iw0 = (wpos - kw0) >> 1;
    bool vh0 = (ih0 < 63), vh1 = (ih0 >= 1);
    bool vw0 = (iw0 < 63), vw1 = (iw0 >= 1);
    float acc = bias[co];
    const float* db = d + (size_t)b*256*HW1;
    for (int ci = 0; ci < 256; ++ci) {
        const float* dc = db + (size_t)ci*HW1;
        const float* wc = ws + ci*16;
        float v00 = (vh0 && vw0) ? dc[ih0*63 + iw0]       : 0.f;
        float v01 = (vh0 && vw1) ? dc[ih0*63 + iw0 - 1]   : 0.f;
        float v10 = (vh1 && vw0) ? dc[(ih0-1)*63 + iw0]   : 0.f;
        float v11 = (vh1 && vw1) ? dc[(ih0-1)*63 + iw0-1] : 0.f;
        acc = fmaf(v00, wc[kh0*4 + kw0],         acc);
        acc = fmaf(v01, wc[kh0*4 + kw0 + 2],     acc);
        acc = fmaf(v10, wc[(kh0+2)*4 + kw0],     acc);
        acc = fmaf(v11, wc[(kh0+2)*4 + kw0 + 2], acc);
    }
    out[((size_t)(b*3+co)*128 + h)*128 + wpos] = acc;
}

// ---------------- launch ----------------
extern "C" void kernel_launch(void* const* d_in, const int* in_sizes, int n_in,
                              void* d_out, int out_size, void* d_ws, size_t ws_size,
                              hipStream_t stream) {
    const float* x      = (const float*)d_in[0];
    const float* ec1_w  = (const float*)d_in[1];
    const float* ec1_b  = (const float*)d_in[2];
    const float* ec2_w  = (const float*)d_in[3];
    const float* ec2_b  = (const float*)d_in[4];
    const float* se1_w1 = (const float*)d_in[5];
    const float* se1_b1 = (const float*)d_in[6];
    const float* se1_w2 = (const float*)d_in[7];
    const float* se1_b2 = (const float*)d_in[8];
    const float* sa1_w  = (const float*)d_in[9];
    const float* se2_w1 = (const float*)d_in[10];
    const float* se2_b1 = (const float*)d_in[11];
    const float* se2_w2 = (const float*)d_in[12];
    const float* se2_b2 = (const float*)d_in[13];
    const float* sa2_w  = (const float*)d_in[14];
    const float* cbk    = (const float*)d_in[15];
    const float* dt1_w  = (const float*)d_in[16];
    const float* dt1_b  = (const float*)d_in[17];
    const float* dt2_w  = (const float*)d_in[18];
    const float* dt2_b  = (const float*)d_in[19];
    const float* dse_w1 = (const float*)d_in[20];
    const float* dse_b1 = (const float*)d_in[21];
    const float* dse_w2 = (const float*)d_in[22];
    const float* dse_b2 = (const float*)d_in[23];
    const float* dsa_w  = (const float*)d_in[24];
    float* out = (float*)d_out;

    // Two big buffers only (~259 MB total): A=T63, C=T62; CBAM + VQ-gather in-place.
    float* A      = (float*)d_ws;
    float* C      = A + T63;
    float* pooled = C + T62;
    float* g      = pooled + 8192;
    float* am     = g + 8192;
    float* ssmap  = am + (size_t)NB*2*HW1;
    float* cbn    = ssmap + (size_t)NB*HW1;
    float* Wc     = cbn + 512;
    float* sse    = Wc + 262144;
    int*   counts = (int*)(sse + 1);
    int*   idx    = counts + 512;

    // prep
    zero_small<<<1, 256, 0, stream>>>(sse, counts);
    repack_dt1<<<1024, 256, 0, stream>>>(dt1_w, Wc);
    cb_norm<<<1, 256, 0, stream>>>(cbk, cbn);

    // encoder conv1 + cbam1 (in-place on A)
    conv1_relu<<<dim3(NB*256, 16), 256, 0, stream>>>(x, ec1_w, ec1_b, A);
    gap_kernel<<<NB*256, 256, 0, stream>>>(A, pooled, HW1);
    se_mlp<<<NB, 256, 0, stream>>>(pooled, se1_w1, se1_b1, se1_w2, se1_b2, g);
    chanpool<<<dim3(16, NB), 256, 0, stream>>>(A, g, am, HW1);
    spatial_conv<<<dim3(16, NB), 256, 0, stream>>>(am, sa1_w, ssmap, 63, 63, 0);
    cbam_final<<<dim3(HW1, NB), 256, 0, stream>>>(A, g, ssmap, HW1);

    // conv2 (A -> C) + cbam2 (in-place on C)  => z in C
    convk2_gemm<<<dim3(256, NB), 256, 0, stream>>>(A, ec2_w, ec2_b, C, 63, 63, 62, 62, 0);
    gap_kernel<<<NB*256, 256, 0, stream>>>(C, pooled, HW2);
    se_mlp<<<NB, 256, 0, stream>>>(pooled, se2_w1, se2_b1, se2_w2, se2_b2, g);
    chanpool<<<dim3(16, NB), 256, 0, stream>>>(C, g, am, HW2);
    spatial_conv<<<dim3(16, NB), 256, 0, stream>>>(am, sa2_w, ssmap, 62, 62, 0);
    cbam_final<<<dim3(HW2, NB), 256, 0, stream>>>(C, g, ssmap, HW2);

    // VQ: z in C -> q in C (in-place)
    vq_assign<<<NROWS/16, 256, 0, stream>>>(C, cbk, cbn, idx);
    vq_gather<<<GATHER_BLOCKS, 256, 0, stream>>>(C, cbk, idx, sse, counts);
    vq_finalize<<<1, 256, 0, stream>>>(sse, counts, out);

    // decoder dt1 (C -> A) + cbam3 (in-place on A)
    convk2_gemm<<<dim3(256, NB), 256, 0, stream>>>(C, Wc, dt1_b, A, 62, 62, 63, 63, 1);
    gap_kernel<<<NB*256, 256, 0, stream>>>(A, pooled, HW1);
    se_mlp<<<NB, 256, 0, stream>>>(pooled, dse_w1, dse_b1, dse_w2, dse_b2, g);
    chanpool<<<dim3(16, NB), 256, 0, stream>>>(A, g, am, HW1);
    spatial_conv<<<dim3(16, NB), 256, 0, stream>>>(am, dsa_w, ssmap, 63, 63, 1);
    cbam_final<<<dim3(HW1, NB), 256, 0, stream>>>(A, g, ssmap, HW1);

    // final convT -> out
    dt2_kernel<<<dim3(192, NB), 256, 0, stream>>>(A, dt2_w, dt2_b, out);
}

// Round 4
// 2734.339 us; speedup vs baseline: 2.2281x; 1.6221x over previous
//
#include <hip/hip_runtime.h>
#include <math.h>

// ---------------- sizes ----------------
// x: [32,3,128,128]; conv1 (k4 s2) -> [32,256,63,63]; conv2 (k2 s1) -> [32,256,62,62]
// dt1 (convT k2 s1) -> [32,256,63,63]; dt2 (convT k4 s2) -> [32,3,128,128]
#define NB 32
#define HID 256
#define HW1 (63*63)      // 3969
#define HW2 (62*62)      // 3844
#define T63 ((size_t)NB*HID*HW1)   // 32,514,048
#define T62 ((size_t)NB*HID*HW2)   // 31,490,048
#define NROWS 123008               // T62 / 256
#define KCB 512
#define GATHER_BLOCKS 1024

typedef __attribute__((ext_vector_type(8))) short short8;
typedef __attribute__((ext_vector_type(4))) float f32x4;

__device__ __forceinline__ unsigned short f2bf(float f) {
    union { float f; unsigned int u; } v; v.f = f;
    unsigned int u = v.u;
    return (unsigned short)((u + 0x7FFFu + ((u >> 16) & 1u)) >> 16);
}

// ---------------- zero small scratch (sse + counts) ----------------
__global__ __launch_bounds__(256) void zero_small(float* __restrict__ sse, int* __restrict__ counts) {
    if (threadIdx.x == 0) sse[0] = 0.f;
    for (int i = threadIdx.x; i < KCB; i += 256) counts[i] = 0;
}

// ---------------- conv1: 3->256, k4, s2, bias, relu ----------------
__global__ __launch_bounds__(256) void conv1_relu(
    const float* __restrict__ x, const float* __restrict__ w,
    const float* __restrict__ bias, float* __restrict__ out) {
    int b = blockIdx.x >> 8, co = blockIdx.x & 255;
    int ow = threadIdx.x & 63, oh = (blockIdx.y << 2) + (threadIdx.x >> 6);
    __shared__ float ws[48];
    if (threadIdx.x < 48) ws[threadIdx.x] = w[co*48 + threadIdx.x];
    __syncthreads();
    if (ow >= 63 || oh >= 63) return;
    float acc = bias[co];
    const float* xb = x + (size_t)b*3*128*128;
    int ih0 = oh*2, iw0 = ow*2;
    #pragma unroll
    for (int ci = 0; ci < 3; ++ci)
      #pragma unroll
      for (int kh = 0; kh < 4; ++kh) {
        const float* row = xb + ((size_t)ci*128 + ih0+kh)*128 + iw0;
        #pragma unroll
        for (int kw = 0; kw < 4; ++kw)
            acc = fmaf(row[kw], ws[ci*16+kh*4+kw], acc);
      }
    out[((size_t)(b*HID+co)*63 + oh)*63 + ow] = fmaxf(acc, 0.f);
}

// ---------------- global average pool over spatial ----------------
__global__ __launch_bounds__(256) void gap_kernel(
    const float* __restrict__ x, float* __restrict__ pooled, int HW) {
    int bc = blockIdx.x;
    const float* p = x + (size_t)bc*HW;
    float s = 0.f;
    for (int i = threadIdx.x; i < HW; i += 256) s += p[i];
    __shared__ float lds[4];
    for (int off = 32; off; off >>= 1) s += __shfl_down(s, off, 64);
    if ((threadIdx.x & 63) == 0) lds[threadIdx.x >> 6] = s;
    __syncthreads();
    if (threadIdx.x == 0) pooled[bc] = (lds[0]+lds[1]+lds[2]+lds[3]) / (float)HW;
}

// ---------------- SE MLP: g = sigmoid(relu(s@w1.T+b1)@w2.T+b2) ----------------
__global__ __launch_bounds__(256) void se_mlp(
    const float* __restrict__ pooled, const float* __restrict__ w1,
    const float* __restrict__ b1, const float* __restrict__ w2,
    const float* __restrict__ b2, float* __restrict__ g) {
    int b = blockIdx.x;
    __shared__ float ps[256], hs[16];
    ps[threadIdx.x] = pooled[b*256 + threadIdx.x];
    __syncthreads();
    if (threadIdx.x < 16) {
        float a = b1[threadIdx.x];
        const float* wr = w1 + threadIdx.x*256;
        for (int k = 0; k < 256; ++k) a = fmaf(ps[k], wr[k], a);
        hs[threadIdx.x] = fmaxf(a, 0.f);
    }
    __syncthreads();
    float a = b2[threadIdx.x];
    const float* wr = w2 + threadIdx.x*16;
    #pragma unroll
    for (int j = 0; j < 16; ++j) a = fmaf(hs[j], wr[j], a);
    g[b*256 + threadIdx.x] = 1.f / (1.f + expf(-a));
}

// ---------------- channel mean/max of x*g ----------------
__global__ __launch_bounds__(256) void chanpool(
    const float* __restrict__ x, const float* __restrict__ g,
    float* __restrict__ am, int HW) {
    int b = blockIdx.y;
    int p = blockIdx.x*256 + threadIdx.x;
    if (p >= HW) return;
    const float* xb = x + (size_t)b*256*HW + p;
    const float* gb = g + b*256;
    float s = 0.f, mx = -3.0e38f;
    for (int c = 0; c < 256; ++c) {
        float v = xb[(size_t)c*HW] * gb[c];
        s += v; mx = fmaxf(mx, v);
    }
    am[((size_t)b*2)*HW + p]   = s * (1.f/256.f);
    am[((size_t)b*2+1)*HW + p] = mx;
}

// ---------------- 7x7 spatial conv on [mean,max], sigmoid ----------------
__global__ __launch_bounds__(256) void spatial_conv(
    const float* __restrict__ am, const float* __restrict__ sw,
    float* __restrict__ ss, int H, int W, int transpose) {
    int b = blockIdx.y;
    int p = blockIdx.x*256 + threadIdx.x;
    __shared__ float ws[98];
    if (threadIdx.x < 98) {
        int c = threadIdx.x / 49, k = threadIdx.x % 49;
        int kh = k / 7, kw = k % 7;
        ws[threadIdx.x] = transpose ? sw[c*49 + (6-kh)*7 + (6-kw)]
                                    : sw[c*49 + kh*7 + kw];
    }
    __syncthreads();
    if (p >= H*W) return;
    int oh = p / W, ow = p % W;
    float acc = 0.f;
    #pragma unroll
    for (int c = 0; c < 2; ++c) {
        const float* ab = am + ((size_t)b*2 + c)*H*W;
        for (int kh = 0; kh < 7; ++kh) {
            int ih = oh + kh - 3;
            if (ih < 0 || ih >= H) continue;
            for (int kw = 0; kw < 7; ++kw) {
                int iw = ow + kw - 3;
                if (iw < 0 || iw >= W) continue;
                acc = fmaf(ab[(size_t)ih*W + iw], ws[c*49 + kh*7 + kw], acc);
            }
        }
    }
    ss[(size_t)b*H*W + p] = 1.f / (1.f + expf(-acc));
}

// ---------------- IN-PLACE: x = x*x*g*sig(s) ----------------
__global__ __launch_bounds__(256) void cbam_final(
    float* x, const float* __restrict__ g,
    const float* __restrict__ ss, int HW) {
    int b = blockIdx.y;
    size_t e = (size_t)blockIdx.x*256 + threadIdx.x;
    if (e >= (size_t)256*HW) return;
    int c = (int)(e / HW), p = (int)(e % HW);
    float* px = x + (size_t)b*256*HW + e;
    float xv = *px;
    *px = xv * xv * g[b*256+c] * ss[(size_t)b*HW + p];
}

// ---------------- weight prepack into MFMA-fragment layout (bf16) ----------------
// pack[t]: t = cc*32768 + tap*8192 + co*32 + koct*8 + j ; ci = cc*32+koct*8+j
__global__ __launch_bounds__(256) void prepack_w(
    const float* __restrict__ w, unsigned short* __restrict__ pack, int transpose_flip) {
    int t = blockIdx.x*256 + threadIdx.x;
    int j = t & 7, koct = (t >> 3) & 3, co = (t >> 5) & 255, tap = (t >> 13) & 3, cc = t >> 15;
    int ci = cc*32 + koct*8 + j;
    int kh = tap >> 1, kw = tap & 1;
    float v;
    if (transpose_flip) v = w[((size_t)ci*256 + co)*4 + (1-kh)*2 + (1-kw)];
    else                v = w[((size_t)co*256 + ci)*4 + kh*2 + kw];
    pack[t] = f2bf(v);
}

// ---------------- MFMA conv k=2 s=1 (conv2: pad=0; dt1: pad=1) ----------------
// block: 64co x 64px (8x8 spatial), 4 waves of 16co x 64px; K=1024 as 8 ci-chunks x 4 taps.
__global__ __launch_bounds__(256) void convk2_mfma(
    const float* __restrict__ in, const unsigned short* __restrict__ apack,
    const float* __restrict__ bias, float* __restrict__ out,
    int inH, int inW, int outH, int outW, int pad) {
    __shared__ __align__(16) unsigned short Iraw[81*40];  // [sp=9x9][ci=32], stride 40 (16B-aligned, bank-spread)
    int b = blockIdx.y;
    int cog = blockIdx.x >> 6;
    int t   = blockIdx.x & 63;
    int oh0 = (t >> 3) * 8, ow0 = (t & 7) * 8;
    int w = threadIdx.x >> 6, l = threadIdx.x & 63;
    int co0w = cog*64 + w*16;
    int lr = l & 15, lk = l >> 4;
    f32x4 acc0 = {0.f,0.f,0.f,0.f}, acc1 = {0.f,0.f,0.f,0.f};
    f32x4 acc2 = {0.f,0.f,0.f,0.f}, acc3 = {0.f,0.f,0.f,0.f};
    int sci = threadIdx.x >> 3, sc = threadIdx.x & 7;
    const float* inb = in + (size_t)b*256*inH*inW;
    for (int cc = 0; cc < 8; ++cc) {
        __syncthreads();
        const float* cbase = inb + (size_t)(cc*32 + sci)*inH*inW;
        #pragma unroll
        for (int r = 0; r < 9; ++r) {
            int gh = oh0 + r - pad;
            bool vh = (gh >= 0) && (gh < inH);
            int gw = ow0 + sc - pad;
            float v = (vh && gw >= 0 && gw < inW) ? cbase[(size_t)gh*inW + gw] : 0.f;
            Iraw[(r*9 + sc)*40 + sci] = f2bf(v);
            if (sc == 0) {
                int gw8 = ow0 + 8 - pad;
                float v8 = (vh && gw8 >= 0 && gw8 < inW) ? cbase[(size_t)gh*inW + gw8] : 0.f;
                Iraw[(r*9 + 8)*40 + sci] = f2bf(v8);
            }
        }
        __syncthreads();
        #pragma unroll
        for (int tap = 0; tap < 4; ++tap) {
            int kh = tap >> 1, kw = tap & 1;
            short8 af = *(const short8*)(apack +
                ((((size_t)cc*4 + tap)*256 + co0w + lr)*4 + (size_t)lk)*8);
            int spb = kh*9 + kw;
            {
                int px = lr;
                short8 bf = *(const short8*)&Iraw[(spb + (px>>3)*9 + (px&7))*40 + lk*8];
                acc0 = __builtin_amdgcn_mfma_f32_16x16x32_bf16(af, bf, acc0, 0, 0, 0);
            }
            {
                int px = 16 + lr;
                short8 bf = *(const short8*)&Iraw[(spb + (px>>3)*9 + (px&7))*40 + lk*8];
                acc1 = __builtin_amdgcn_mfma_f32_16x16x32_bf16(af, bf, acc1, 0, 0, 0);
            }
            {
                int px = 32 + lr;
                short8 bf = *(const short8*)&Iraw[(spb + (px>>3)*9 + (px&7))*40 + lk*8];
                acc2 = __builtin_amdgcn_mfma_f32_16x16x32_bf16(af, bf, acc2, 0, 0, 0);
            }
            {
                int px = 48 + lr;
                short8 bf = *(const short8*)&Iraw[(spb + (px>>3)*9 + (px&7))*40 + lk*8];
                acc3 = __builtin_amdgcn_mfma_f32_16x16x32_bf16(af, bf, acc3, 0, 0, 0);
            }
        }
    }
    float4 bz = *(const float4*)&bias[co0w + lk*4];
    #pragma unroll
    for (int nf = 0; nf < 4; ++nf) {
        f32x4 a = (nf == 0) ? acc0 : (nf == 1) ? acc1 : (nf == 2) ? acc2 : acc3;
        int px = nf*16 + lr;
        int oh = oh0 + (px >> 3), ow = ow0 + (px & 7);
        if (oh < outH && ow < outW) {
            size_t base = ((size_t)(b*256 + co0w + lk*4)*outH + oh)*outW + ow;
            out[base]                       = fmaxf(a.x + bz.x, 0.f);
            out[base + (size_t)outH*outW]   = fmaxf(a.y + bz.y, 0.f);
            out[base + (size_t)2*outH*outW] = fmaxf(a.z + bz.z, 0.f);
            out[base + (size_t)3*outH*outW] = fmaxf(a.w + bz.w, 0.f);
        }
    }
}

// ---------------- codebook norms ----------------
__global__ __launch_bounds__(256) void cb_norm(
    const float* __restrict__ cb, float* __restrict__ cbn) {
    for (int n = threadIdx.x; n < KCB; n += 256) {
        float s = 0.f;
        for (int k = 0; k < 256; ++k) { float v = cb[(size_t)n*256+k]; s = fmaf(v,v,s); }
        cbn[n] = s;
    }
}

// ---------------- VQ assign: argmin_n (cbn[n] - 2*z.cb[n]) ----------------
__global__ __launch_bounds__(256) void vq_assign(
    const float* __restrict__ z, const float* __restrict__ cb,
    const float* __restrict__ cbn, int* __restrict__ idx) {
    __shared__ __align__(16) float zs[16*260];
    __shared__ __align__(16) float cbs[16*260];
    int r0 = blockIdx.x * 16;
    for (int t = threadIdx.x; t < 4096; t += 256) {
        int r = t >> 8, k = t & 255;
        zs[r*260 + k] = z[(size_t)(r0+r)*256 + k];
    }
    int rl = threadIdx.x >> 4, nl = threadIdx.x & 15;
    float bd = 3.0e38f; int bi = 0;
    for (int nc = 0; nc < 32; ++nc) {
        __syncthreads();
        for (int t = threadIdx.x; t < 4096; t += 256) {
            int n = t >> 8, k = t & 255;
            cbs[n*260 + k] = cb[(size_t)(nc*16+n)*256 + k];
        }
        __syncthreads();
        float acc = 0.f;
        #pragma unroll 8
        for (int k = 0; k < 256; k += 4) {
            float4 zv = *(const float4*)&zs[rl*260 + k];
            float4 cv = *(const float4*)&cbs[nl*260 + k];
            acc = fmaf(zv.x, cv.x, acc); acc = fmaf(zv.y, cv.y, acc);
            acc = fmaf(zv.z, cv.z, acc); acc = fmaf(zv.w, cv.w, acc);
        }
        int n = nc*16 + nl;
        float dist = cbn[n] - 2.f*acc;
        if (dist < bd) { bd = dist; bi = n; }
    }
    for (int off = 8; off; off >>= 1) {
        float od = __shfl_xor(bd, off, 64);
        int   oi = __shfl_xor(bi, off, 64);
        if (od < bd || (od == bd && oi < bi)) { bd = od; bi = oi; }
    }
    if (nl == 0) idx[r0 + rl] = bi;
}

// ---------------- IN-PLACE VQ gather: persistent blocks, LDS hist, 1 SSE atomic/block ----------------
__global__ __launch_bounds__(256) void vq_gather(
    float* zq, const float* __restrict__ cb,
    const int* __restrict__ idx, float* __restrict__ sse, int* __restrict__ counts) {
    __shared__ int hist[KCB];
    for (int i = threadIdx.x; i < KCB; i += 256) hist[i] = 0;
    __syncthreads();
    float local = 0.f;
    for (int r = blockIdx.x; r < NROWS; r += GATHER_BLOCKS) {
        int id = idx[r];
        if (threadIdx.x == 0) atomicAdd(&hist[id], 1);
        float qv = cb[(size_t)id*256 + threadIdx.x];
        float* pz = zq + (size_t)r*256 + threadIdx.x;
        float zv = *pz;
        *pz = qv;
        float d = qv - zv;
        local = fmaf(d, d, local);
    }
    __shared__ float lds[4];
    for (int off = 32; off; off >>= 1) local += __shfl_down(local, off, 64);
    if ((threadIdx.x & 63) == 0) lds[threadIdx.x >> 6] = local;
    __syncthreads();
    if (threadIdx.x == 0) atomicAdd(sse, lds[0]+lds[1]+lds[2]+lds[3]);
    for (int i = threadIdx.x; i < KCB; i += 256) {
        int h = hist[i];
        if (h) atomicAdd(counts + i, h);
    }
}

// ---------------- loss + perplexity ----------------
__global__ __launch_bounds__(256) void vq_finalize(
    const float* __restrict__ sse, const int* __restrict__ counts,
    float* __restrict__ out) {
    __shared__ float lds[4];
    float h = 0.f;
    for (int n = threadIdx.x; n < KCB; n += 256) {
        float p = (float)counts[n] * (1.f/123008.f);
        h += p * logf(p + 1e-10f);
    }
    for (int off = 32; off; off >>= 1) h += __shfl_down(h, off, 64);
    if ((threadIdx.x & 63) == 0) lds[threadIdx.x >> 6] = h;
    __syncthreads();
    if (threadIdx.x == 0) {
        out[1572864] = 1.25f * sse[0] / 31490048.f;
        out[1572865] = expf(-(lds[0]+lds[1]+lds[2]+lds[3]));
    }
}

// ---------------- dt2: convT 256->3, k4, s2 ----------------
__global__ __launch_bounds__(256) void dt2_kernel(
    const float* __restrict__ d, const float* __restrict__ w,
    const float* __restrict__ bias, float* __restrict__ out) {
    int b = blockIdx.y;
    int co = blockIdx.x / 64;
    int h = (blockIdx.x % 64)*2 + (threadIdx.x >> 7);
    int wpos = threadIdx.x & 127;
    __shared__ float ws[4096];
    for (int t = threadIdx.x; t < 4096; t += 256) {
        int ci = t >> 4, k = t & 15;
        ws[t] = w[(size_t)ci*48 + co*16 + k];
    }
    __syncthreads();
    int kh0 = h & 1, kw0 = wpos & 1;
    int ih0 = (h - kh0) >> 1, iw0 = (wpos - kw0) >> 1;
    bool vh0 = (ih0 < 63), vh1 = (ih0 >= 1);
    bool vw0 = (iw0 < 63), vw1 = (iw0 >= 1);
    float acc = bias[co];
    const float* db = d + (size_t)b*256*HW1;
    for (int ci = 0; ci < 256; ++ci) {
        const float* dc = db + (size_t)ci*HW1;
        const float* wc = ws + ci*16;
        float v00 = (vh0 && vw0) ? dc[ih0*63 + iw0]       : 0.f;
        float v01 = (vh0 && vw1) ? dc[ih0*63 + iw0 - 1]   : 0.f;
        float v10 = (vh1 && vw0) ? dc[(ih0-1)*63 + iw0]   : 0.f;
        float v11 = (vh1 && vw1) ? dc[(ih0-1)*63 + iw0-1] : 0.f;
        acc = fmaf(v00, wc[kh0*4 + kw0],         acc);
        acc = fmaf(v01, wc[kh0*4 + kw0 + 2],     acc);
        acc = fmaf(v10, wc[(kh0+2)*4 + kw0],     acc);
        acc = fmaf(v11, wc[(kh0+2)*4 + kw0 + 2], acc);
    }
    out[((size_t)(b*3+co)*128 + h)*128 + wpos] = acc;
}

// ---------------- launch ----------------
extern "C" void kernel_launch(void* const* d_in, const int* in_sizes, int n_in,
                              void* d_out, int out_size, void* d_ws, size_t ws_size,
                              hipStream_t stream) {
    const float* x      = (const float*)d_in[0];
    const float* ec1_w  = (const float*)d_in[1];
    const float* ec1_b  = (const float*)d_in[2];
    const float* ec2_w  = (const float*)d_in[3];
    const float* ec2_b  = (const float*)d_in[4];
    const float* se1_w1 = (const float*)d_in[5];
    const float* se1_b1 = (const float*)d_in[6];
    const float* se1_w2 = (const float*)d_in[7];
    const float* se1_b2 = (const float*)d_in[8];
    const float* sa1_w  = (const float*)d_in[9];
    const float* se2_w1 = (const float*)d_in[10];
    const float* se2_b1 = (const float*)d_in[11];
    const float* se2_w2 = (const float*)d_in[12];
    const float* se2_b2 = (const float*)d_in[13];
    const float* sa2_w  = (const float*)d_in[14];
    const float* cbk    = (const float*)d_in[15];
    const float* dt1_w  = (const float*)d_in[16];
    const float* dt1_b  = (const float*)d_in[17];
    const float* dt2_w  = (const float*)d_in[18];
    const float* dt2_b  = (const float*)d_in[19];
    const float* dse_w1 = (const float*)d_in[20];
    const float* dse_b1 = (const float*)d_in[21];
    const float* dse_w2 = (const float*)d_in[22];
    const float* dse_b2 = (const float*)d_in[23];
    const float* dsa_w  = (const float*)d_in[24];
    float* out = (float*)d_out;

    float* A      = (float*)d_ws;
    float* C      = A + T63;
    float* pooled = C + T62;
    float* g      = pooled + 8192;
    float* am     = g + 8192;
    float* ssmap  = am + (size_t)NB*2*HW1;
    float* cbn    = ssmap + (size_t)NB*HW1;
    unsigned short* apackE = (unsigned short*)(cbn + 512);   // 262144 ushort (conv2)
    unsigned short* apackD = apackE + 262144;                 // 262144 ushort (dt1)
    float* sse    = (float*)(apackD + 262144);
    int*   counts = (int*)(sse + 1);
    int*   idx    = counts + 512;

    // prep
    zero_small<<<1, 256, 0, stream>>>(sse, counts);
    prepack_w<<<1024, 256, 0, stream>>>(ec2_w, apackE, 0);
    prepack_w<<<1024, 256, 0, stream>>>(dt1_w, apackD, 1);
    cb_norm<<<1, 256, 0, stream>>>(cbk, cbn);

    // encoder conv1 + cbam1 (in-place on A)
    conv1_relu<<<dim3(NB*256, 16), 256, 0, stream>>>(x, ec1_w, ec1_b, A);
    gap_kernel<<<NB*256, 256, 0, stream>>>(A, pooled, HW1);
    se_mlp<<<NB, 256, 0, stream>>>(pooled, se1_w1, se1_b1, se1_w2, se1_b2, g);
    chanpool<<<dim3(16, NB), 256, 0, stream>>>(A, g, am, HW1);
    spatial_conv<<<dim3(16, NB), 256, 0, stream>>>(am, sa1_w, ssmap, 63, 63, 0);
    cbam_final<<<dim3(HW1, NB), 256, 0, stream>>>(A, g, ssmap, HW1);

    // conv2 (A -> C, MFMA) + cbam2 (in-place on C)  => z in C
    convk2_mfma<<<dim3(256, NB), 256, 0, stream>>>(A, apackE, ec2_b, C, 63, 63, 62, 62, 0);
    gap_kernel<<<NB*256, 256, 0, stream>>>(C, pooled, HW2);
    se_mlp<<<NB, 256, 0, stream>>>(pooled, se2_w1, se2_b1, se2_w2, se2_b2, g);
    chanpool<<<dim3(16, NB), 256, 0, stream>>>(C, g, am, HW2);
    spatial_conv<<<dim3(16, NB), 256, 0, stream>>>(am, sa2_w, ssmap, 62, 62, 0);
    cbam_final<<<dim3(HW2, NB), 256, 0, stream>>>(C, g, ssmap, HW2);

    // VQ: z in C -> q in C (in-place)
    vq_assign<<<NROWS/16, 256, 0, stream>>>(C, cbk, cbn, idx);
    vq_gather<<<GATHER_BLOCKS, 256, 0, stream>>>(C, cbk, idx, sse, counts);
    vq_finalize<<<1, 256, 0, stream>>>(sse, counts, out);

    // decoder dt1 (C -> A, MFMA) + cbam3 (in-place on A)
    convk2_mfma<<<dim3(256, NB), 256, 0, stream>>>(C, apackD, dt1_b, A, 62, 62, 63, 63, 1);
    gap_kernel<<<NB*256, 256, 0, stream>>>(A, pooled, HW1);
    se_mlp<<<NB, 256, 0, stream>>>(pooled, dse_w1, dse_b1, dse_w2, dse_b2, g);
    chanpool<<<dim3(16, NB), 256, 0, stream>>>(A, g, am, HW1);
    spatial_conv<<<dim3(16, NB), 256, 0, stream>>>(am, dsa_w, ssmap, 63, 63, 1);
    cbam_final<<<dim3(HW1, NB), 256, 0, stream>>>(A, g, ssmap, HW1);

    // final convT -> out
    dt2_kernel<<<dim3(192, NB), 256, 0, stream>>>(A, dt2_w, dt2_b, out);
}

// Round 5
// 1887.660 us; speedup vs baseline: 3.2275x; 1.4485x over previous
//
#include <hip/hip_runtime.h>
#include <math.h>

// ---------------- sizes ----------------
#define NB 32
#define HID 256
#define HW1 (63*63)      // 3969
#define HW2 (62*62)      // 3844
#define T63 ((size_t)NB*HID*HW1)   // 32,514,048
#define T62 ((size_t)NB*HID*HW2)   // 31,490,048
#define NROWS 123008               // T62 / 256
#define KCB 512
#define GATHER_BLOCKS 1024

typedef __attribute__((ext_vector_type(8))) short short8;
typedef __attribute__((ext_vector_type(4))) float f32x4;
typedef __attribute__((ext_vector_type(4))) unsigned short us4;

__device__ __forceinline__ unsigned short f2bf(float f) {
    union { float f; unsigned int u; } v; v.f = f;
    unsigned int u = v.u;
    return (unsigned short)((u + 0x7FFFu + ((u >> 16) & 1u)) >> 16);
}

// ---------------- zero small scratch (sse + counts) ----------------
__global__ __launch_bounds__(256) void zero_small(float* __restrict__ sse, int* __restrict__ counts) {
    if (threadIdx.x == 0) sse[0] = 0.f;
    for (int i = threadIdx.x; i < KCB; i += 256) counts[i] = 0;
}

// ---------------- conv1: 3->256, k4, s2, bias, relu ----------------
__global__ __launch_bounds__(256) void conv1_relu(
    const float* __restrict__ x, const float* __restrict__ w,
    const float* __restrict__ bias, float* __restrict__ out) {
    int b = blockIdx.x >> 8, co = blockIdx.x & 255;
    int ow = threadIdx.x & 63, oh = (blockIdx.y << 2) + (threadIdx.x >> 6);
    __shared__ float ws[48];
    if (threadIdx.x < 48) ws[threadIdx.x] = w[co*48 + threadIdx.x];
    __syncthreads();
    if (ow >= 63 || oh >= 63) return;
    float acc = bias[co];
    const float* xb = x + (size_t)b*3*128*128;
    int ih0 = oh*2, iw0 = ow*2;
    #pragma unroll
    for (int ci = 0; ci < 3; ++ci)
      #pragma unroll
      for (int kh = 0; kh < 4; ++kh) {
        const float* row = xb + ((size_t)ci*128 + ih0+kh)*128 + iw0;
        #pragma unroll
        for (int kw = 0; kw < 4; ++kw)
            acc = fmaf(row[kw], ws[ci*16+kh*4+kw], acc);
      }
    out[((size_t)(b*HID+co)*63 + oh)*63 + ow] = fmaxf(acc, 0.f);
}

// ---------------- global average pool over spatial ----------------
__global__ __launch_bounds__(256) void gap_kernel(
    const float* __restrict__ x, float* __restrict__ pooled, int HW) {
    int bc = blockIdx.x;
    const float* p = x + (size_t)bc*HW;
    float s = 0.f;
    for (int i = threadIdx.x; i < HW; i += 256) s += p[i];
    __shared__ float lds[4];
    for (int off = 32; off; off >>= 1) s += __shfl_down(s, off, 64);
    if ((threadIdx.x & 63) == 0) lds[threadIdx.x >> 6] = s;
    __syncthreads();
    if (threadIdx.x == 0) pooled[bc] = (lds[0]+lds[1]+lds[2]+lds[3]) / (float)HW;
}

// ---------------- SE MLP ----------------
__global__ __launch_bounds__(256) void se_mlp(
    const float* __restrict__ pooled, const float* __restrict__ w1,
    const float* __restrict__ b1, const float* __restrict__ w2,
    const float* __restrict__ b2, float* __restrict__ g) {
    int b = blockIdx.x;
    __shared__ float ps[256], hs[16];
    ps[threadIdx.x] = pooled[b*256 + threadIdx.x];
    __syncthreads();
    if (threadIdx.x < 16) {
        float a = b1[threadIdx.x];
        const float* wr = w1 + threadIdx.x*256;
        for (int k = 0; k < 256; ++k) a = fmaf(ps[k], wr[k], a);
        hs[threadIdx.x] = fmaxf(a, 0.f);
    }
    __syncthreads();
    float a = b2[threadIdx.x];
    const float* wr = w2 + threadIdx.x*16;
    #pragma unroll
    for (int j = 0; j < 16; ++j) a = fmaf(hs[j], wr[j], a);
    g[b*256 + threadIdx.x] = 1.f / (1.f + expf(-a));
}

// ---------------- channel mean/max of x*g ----------------
__global__ __launch_bounds__(256) void chanpool(
    const float* __restrict__ x, const float* __restrict__ g,
    float* __restrict__ am, int HW) {
    int b = blockIdx.y;
    int p = blockIdx.x*256 + threadIdx.x;
    if (p >= HW) return;
    const float* xb = x + (size_t)b*256*HW + p;
    const float* gb = g + b*256;
    float s = 0.f, mx = -3.0e38f;
    for (int c = 0; c < 256; ++c) {
        float v = xb[(size_t)c*HW] * gb[c];
        s += v; mx = fmaxf(mx, v);
    }
    am[((size_t)b*2)*HW + p]   = s * (1.f/256.f);
    am[((size_t)b*2+1)*HW + p] = mx;
}

// ---------------- 7x7 spatial conv on [mean,max], sigmoid ----------------
__global__ __launch_bounds__(256) void spatial_conv(
    const float* __restrict__ am, const float* __restrict__ sw,
    float* __restrict__ ss, int H, int W, int transpose) {
    int b = blockIdx.y;
    int p = blockIdx.x*256 + threadIdx.x;
    __shared__ float ws[98];
    if (threadIdx.x < 98) {
        int c = threadIdx.x / 49, k = threadIdx.x % 49;
        int kh = k / 7, kw = k % 7;
        ws[threadIdx.x] = transpose ? sw[c*49 + (6-kh)*7 + (6-kw)]
                                    : sw[c*49 + kh*7 + kw];
    }
    __syncthreads();
    if (p >= H*W) return;
    int oh = p / W, ow = p % W;
    float acc = 0.f;
    #pragma unroll
    for (int c = 0; c < 2; ++c) {
        const float* ab = am + ((size_t)b*2 + c)*H*W;
        for (int kh = 0; kh < 7; ++kh) {
            int ih = oh + kh - 3;
            if (ih < 0 || ih >= H) continue;
            for (int kw = 0; kw < 7; ++kw) {
                int iw = ow + kw - 3;
                if (iw < 0 || iw >= W) continue;
                acc = fmaf(ab[(size_t)ih*W + iw], ws[c*49 + kh*7 + kw], acc);
            }
        }
    }
    ss[(size_t)b*H*W + p] = 1.f / (1.f + expf(-acc));
}

// ---------------- IN-PLACE: x = x*x*g*sig(s) ----------------
__global__ __launch_bounds__(256) void cbam_final(
    float* x, const float* __restrict__ g,
    const float* __restrict__ ss, int HW) {
    int b = blockIdx.y;
    size_t e = (size_t)blockIdx.x*256 + threadIdx.x;
    if (e >= (size_t)256*HW) return;
    int c = (int)(e / HW), p = (int)(e % HW);
    float* px = x + (size_t)b*256*HW + e;
    float xv = *px;
    *px = xv * xv * g[b*256+c] * ss[(size_t)b*HW + p];
}

// ---------------- weight prepack into MFMA-fragment layout (bf16) ----------------
__global__ __launch_bounds__(256) void prepack_w(
    const float* __restrict__ w, unsigned short* __restrict__ pack, int transpose_flip) {
    int t = blockIdx.x*256 + threadIdx.x;
    int j = t & 7, koct = (t >> 3) & 3, co = (t >> 5) & 255, tap = (t >> 13) & 3, cc = t >> 15;
    int ci = cc*32 + koct*8 + j;
    int kh = tap >> 1, kw = tap & 1;
    float v;
    if (transpose_flip) v = w[((size_t)ci*256 + co)*4 + (1-kh)*2 + (1-kw)];
    else                v = w[((size_t)co*256 + ci)*4 + kh*2 + kw];
    pack[t] = f2bf(v);
}

// ---------------- MFMA conv k=2 s=1 (conv2: pad=0; dt1: pad=1) ----------------
__global__ __launch_bounds__(256) void convk2_mfma(
    const float* __restrict__ in, const unsigned short* __restrict__ apack,
    const float* __restrict__ bias, float* __restrict__ out,
    int inH, int inW, int outH, int outW, int pad) {
    __shared__ __align__(16) unsigned short Iraw[81*40];
    int b = blockIdx.y;
    int cog = blockIdx.x >> 6;
    int t   = blockIdx.x & 63;
    int oh0 = (t >> 3) * 8, ow0 = (t & 7) * 8;
    int w = threadIdx.x >> 6, l = threadIdx.x & 63;
    int co0w = cog*64 + w*16;
    int lr = l & 15, lk = l >> 4;
    f32x4 acc0 = {0.f,0.f,0.f,0.f}, acc1 = {0.f,0.f,0.f,0.f};
    f32x4 acc2 = {0.f,0.f,0.f,0.f}, acc3 = {0.f,0.f,0.f,0.f};
    int sci = threadIdx.x >> 3, sc = threadIdx.x & 7;
    const float* inb = in + (size_t)b*256*inH*inW;
    for (int cc = 0; cc < 8; ++cc) {
        __syncthreads();
        const float* cbase = inb + (size_t)(cc*32 + sci)*inH*inW;
        #pragma unroll
        for (int r = 0; r < 9; ++r) {
            int gh = oh0 + r - pad;
            bool vh = (gh >= 0) && (gh < inH);
            int gw = ow0 + sc - pad;
            float v = (vh && gw >= 0 && gw < inW) ? cbase[(size_t)gh*inW + gw] : 0.f;
            Iraw[(r*9 + sc)*40 + sci] = f2bf(v);
            if (sc == 0) {
                int gw8 = ow0 + 8 - pad;
                float v8 = (vh && gw8 >= 0 && gw8 < inW) ? cbase[(size_t)gh*inW + gw8] : 0.f;
                Iraw[(r*9 + 8)*40 + sci] = f2bf(v8);
            }
        }
        __syncthreads();
        #pragma unroll
        for (int tap = 0; tap < 4; ++tap) {
            int kh = tap >> 1, kw = tap & 1;
            short8 af = *(const short8*)(apack +
                ((((size_t)cc*4 + tap)*256 + co0w + lr)*4 + (size_t)lk)*8);
            int spb = kh*9 + kw;
            {
                int px = lr;
                short8 bf = *(const short8*)&Iraw[(spb + (px>>3)*9 + (px&7))*40 + lk*8];
                acc0 = __builtin_amdgcn_mfma_f32_16x16x32_bf16(af, bf, acc0, 0, 0, 0);
            }
            {
                int px = 16 + lr;
                short8 bf = *(const short8*)&Iraw[(spb + (px>>3)*9 + (px&7))*40 + lk*8];
                acc1 = __builtin_amdgcn_mfma_f32_16x16x32_bf16(af, bf, acc1, 0, 0, 0);
            }
            {
                int px = 32 + lr;
                short8 bf = *(const short8*)&Iraw[(spb + (px>>3)*9 + (px&7))*40 + lk*8];
                acc2 = __builtin_amdgcn_mfma_f32_16x16x32_bf16(af, bf, acc2, 0, 0, 0);
            }
            {
                int px = 48 + lr;
                short8 bf = *(const short8*)&Iraw[(spb + (px>>3)*9 + (px&7))*40 + lk*8];
                acc3 = __builtin_amdgcn_mfma_f32_16x16x32_bf16(af, bf, acc3, 0, 0, 0);
            }
        }
    }
    float4 bz = *(const float4*)&bias[co0w + lk*4];
    #pragma unroll
    for (int nf = 0; nf < 4; ++nf) {
        f32x4 a = (nf == 0) ? acc0 : (nf == 1) ? acc1 : (nf == 2) ? acc2 : acc3;
        int px = nf*16 + lr;
        int oh = oh0 + (px >> 3), ow = ow0 + (px & 7);
        if (oh < outH && ow < outW) {
            size_t base = ((size_t)(b*256 + co0w + lk*4)*outH + oh)*outW + ow;
            out[base]                       = fmaxf(a.x + bz.x, 0.f);
            out[base + (size_t)outH*outW]   = fmaxf(a.y + bz.y, 0.f);
            out[base + (size_t)2*outH*outW] = fmaxf(a.z + bz.z, 0.f);
            out[base + (size_t)3*outH*outW] = fmaxf(a.w + bz.w, 0.f);
        }
    }
}

// ---------------- codebook norms (fp32, exact) ----------------
__global__ __launch_bounds__(256) void cb_norm(
    const float* __restrict__ cb, float* __restrict__ cbn) {
    for (int n = threadIdx.x; n < KCB; n += 256) {
        float s = 0.f;
        for (int k = 0; k < 256; ++k) { float v = cb[(size_t)n*256+k]; s = fmaf(v,v,s); }
        cbn[n] = s;
    }
}

// ---------------- codebook bf16 pack [n][k] ----------------
__global__ __launch_bounds__(256) void cb_pack(
    const float* __restrict__ cb, unsigned short* __restrict__ cbp) {
    int t = blockIdx.x*256 + threadIdx.x;   // grid 512 -> 131072
    cbp[t] = f2bf(cb[t]);
}

// ---------------- MFMA VQ assign: S = Z@CB^T, dist = cbn - 2S, argmin ----------------
// block: 32 rows x 512 codes; 4 waves as 2x2 (wm: row half, wn: code half).
__global__ __launch_bounds__(256) void vq_assign_mfma(
    const float* __restrict__ z, const unsigned short* __restrict__ cbp,
    const float* __restrict__ cbn, int* __restrict__ idx) {
    __shared__ __align__(16) unsigned short zb[32*264];  // stride 264 bf16 (2-way b128 alias = free)
    __shared__ float red_d[2][32];
    __shared__ int   red_i[2][32];
    int r0 = blockIdx.x * 32;
    // stage Z: 32 rows x 256 k, fp32 -> bf16 (vectorized)
    for (int v = threadIdx.x; v < 2048; v += 256) {
        int row = v >> 6, col4 = v & 63;
        float4 u = *(const float4*)&z[(size_t)(r0+row)*256 + col4*4];
        us4 pk = { f2bf(u.x), f2bf(u.y), f2bf(u.z), f2bf(u.w) };
        *(us4*)&zb[row*264 + col4*4] = pk;
    }
    __syncthreads();
    int w = threadIdx.x >> 6, l = threadIdx.x & 63;
    int wm = w >> 1, wn = w & 1;
    int lr = l & 15, lk = l >> 4;
    // A fragments: 16 rows (wm half) x K=256
    short8 afr[8];
    #pragma unroll
    for (int ks = 0; ks < 8; ++ks)
        afr[ks] = *(const short8*)&zb[(wm*16 + lr)*264 + ks*32 + lk*8];
    // accumulate S for 16 n-frags (256 codes in wn half)
    f32x4 acc[16];
    #pragma unroll
    for (int nf = 0; nf < 16; ++nf) acc[nf] = (f32x4){0.f,0.f,0.f,0.f};
    #pragma unroll
    for (int nf = 0; nf < 16; ++nf) {
        const unsigned short* cbase = cbp + ((size_t)(wn*256 + nf*16 + lr))*256 + lk*8;
        #pragma unroll
        for (int ks = 0; ks < 8; ++ks) {
            short8 bfr = *(const short8*)(cbase + ks*32);
            acc[nf] = __builtin_amdgcn_mfma_f32_16x16x32_bf16(afr[ks], bfr, acc[nf], 0, 0, 0);
        }
    }
    // per-lane argmin over its 16 codes, for its 4 rows
    float bd[4]; int bi[4];
    #pragma unroll
    for (int r = 0; r < 4; ++r) { bd[r] = 3.0e38f; bi[r] = 0; }
    #pragma unroll
    for (int nf = 0; nf < 16; ++nf) {
        int n = wn*256 + nf*16 + lr;
        float cn = cbn[n];
        #pragma unroll
        for (int r = 0; r < 4; ++r) {
            float dist = fmaf(-2.f, acc[nf][r], cn);
            if (dist < bd[r]) { bd[r] = dist; bi[r] = n; }   // ascending n: ties keep lowest
        }
    }
    // reduce across the 16 lanes (lr) holding different codes, same rows
    #pragma unroll
    for (int r = 0; r < 4; ++r) {
        #pragma unroll
        for (int off = 1; off < 16; off <<= 1) {
            float od = __shfl_xor(bd[r], off, 64);
            int   oi = __shfl_xor(bi[r], off, 64);
            if (od < bd[r] || (od == bd[r] && oi < bi[r])) { bd[r] = od; bi[r] = oi; }
        }
    }
    if (lr == 0) {
        #pragma unroll
        for (int r = 0; r < 4; ++r) {
            int row = wm*16 + lk*4 + r;
            red_d[wn][row] = bd[r];
            red_i[wn][row] = bi[r];
        }
    }
    __syncthreads();
    if (threadIdx.x < 32) {
        int row = threadIdx.x;
        float d0 = red_d[0][row], d1 = red_d[1][row];
        int   i0 = red_i[0][row], i1 = red_i[1][row];
        // wn=0 codes are lower-indexed: take wn=1 only on strict less
        idx[r0 + row] = (d1 < d0) ? i1 : i0;
    }
}

// ---------------- IN-PLACE VQ gather: persistent blocks, LDS hist, 1 SSE atomic/block ----------------
__global__ __launch_bounds__(256) void vq_gather(
    float* zq, const float* __restrict__ cb,
    const int* __restrict__ idx, float* __restrict__ sse, int* __restrict__ counts) {
    __shared__ int hist[KCB];
    for (int i = threadIdx.x; i < KCB; i += 256) hist[i] = 0;
    __syncthreads();
    float local = 0.f;
    for (int r = blockIdx.x; r < NROWS; r += GATHER_BLOCKS) {
        int id = idx[r];
        if (threadIdx.x == 0) atomicAdd(&hist[id], 1);
        float qv = cb[(size_t)id*256 + threadIdx.x];
        float* pz = zq + (size_t)r*256 + threadIdx.x;
        float zv = *pz;
        *pz = qv;
        float d = qv - zv;
        local = fmaf(d, d, local);
    }
    __shared__ float lds[4];
    for (int off = 32; off; off >>= 1) local += __shfl_down(local, off, 64);
    if ((threadIdx.x & 63) == 0) lds[threadIdx.x >> 6] = local;
    __syncthreads();
    if (threadIdx.x == 0) atomicAdd(sse, lds[0]+lds[1]+lds[2]+lds[3]);
    for (int i = threadIdx.x; i < KCB; i += 256) {
        int h = hist[i];
        if (h) atomicAdd(counts + i, h);
    }
}

// ---------------- loss + perplexity ----------------
__global__ __launch_bounds__(256) void vq_finalize(
    const float* __restrict__ sse, const int* __restrict__ counts,
    float* __restrict__ out) {
    __shared__ float lds[4];
    float h = 0.f;
    for (int n = threadIdx.x; n < KCB; n += 256) {
        float p = (float)counts[n] * (1.f/123008.f);
        h += p * logf(p + 1e-10f);
    }
    for (int off = 32; off; off >>= 1) h += __shfl_down(h, off, 64);
    if ((threadIdx.x & 63) == 0) lds[threadIdx.x >> 6] = h;
    __syncthreads();
    if (threadIdx.x == 0) {
        out[1572864] = 1.25f * sse[0] / 31490048.f;
        out[1572865] = expf(-(lds[0]+lds[1]+lds[2]+lds[3]));
    }
}

// ---------------- dt2: convT 256->3, k4, s2 ----------------
__global__ __launch_bounds__(256) void dt2_kernel(
    const float* __restrict__ d, const float* __restrict__ w,
    const float* __restrict__ bias, float* __restrict__ out) {
    int b = blockIdx.y;
    int co = blockIdx.x / 64;
    int h = (blockIdx.x % 64)*2 + (threadIdx.x >> 7);
    int wpos = threadIdx.x & 127;
    __shared__ float ws[4096];
    for (int t = threadIdx.x; t < 4096; t += 256) {
        int ci = t >> 4, k = t & 15;
        ws[t] = w[(size_t)ci*48 + co*16 + k];
    }
    __syncthreads();
    int kh0 = h & 1, kw0 = wpos & 1;
    int ih0 = (h - kh0) >> 1, iw0 = (wpos - kw0) >> 1;
    bool vh0 = (ih0 < 63), vh1 = (ih0 >= 1);
    bool vw0 = (iw0 < 63), vw1 = (iw0 >= 1);
    float acc = bias[co];
    const float* db = d + (size_t)b*256*HW1;
    for (int ci = 0; ci < 256; ++ci) {
        const float* dc = db + (size_t)ci*HW1;
        const float* wc = ws + ci*16;
        float v00 = (vh0 && vw0) ? dc[ih0*63 + iw0]       : 0.f;
        float v01 = (vh0 && vw1) ? dc[ih0*63 + iw0 - 1]   : 0.f;
        float v10 = (vh1 && vw0) ? dc[(ih0-1)*63 + iw0]   : 0.f;
        float v11 = (vh1 && vw1) ? dc[(ih0-1)*63 + iw0-1] : 0.f;
        acc = fmaf(v00, wc[kh0*4 + kw0],         acc);
        acc = fmaf(v01, wc[kh0*4 + kw0 + 2],     acc);
        acc = fmaf(v10, wc[(kh0+2)*4 + kw0],     acc);
        acc = fmaf(v11, wc[(kh0+2)*4 + kw0 + 2], acc);
    }
    out[((size_t)(b*3+co)*128 + h)*128 + wpos] = acc;
}

// ---------------- launch ----------------
extern "C" void kernel_launch(void* const* d_in, const int* in_sizes, int n_in,
                              void* d_out, int out_size, void* d_ws, size_t ws_size,
                              hipStream_t stream) {
    const float* x      = (const float*)d_in[0];
    const float* ec1_w  = (const float*)d_in[1];
    const float* ec1_b  = (const float*)d_in[2];
    const float* ec2_w  = (const float*)d_in[3];
    const float* ec2_b  = (const float*)d_in[4];
    const float* se1_w1 = (const float*)d_in[5];
    const float* se1_b1 = (const float*)d_in[6];
    const float* se1_w2 = (const float*)d_in[7];
    const float* se1_b2 = (const float*)d_in[8];
    const float* sa1_w  = (const float*)d_in[9];
    const float* se2_w1 = (const float*)d_in[10];
    const float* se2_b1 = (const float*)d_in[11];
    const float* se2_w2 = (const float*)d_in[12];
    const float* se2_b2 = (const float*)d_in[13];
    const float* sa2_w  = (const float*)d_in[14];
    const float* cbk    = (const float*)d_in[15];
    const float* dt1_w  = (const float*)d_in[16];
    const float* dt1_b  = (const float*)d_in[17];
    const float* dt2_w  = (const float*)d_in[18];
    const float* dt2_b  = (const float*)d_in[19];
    const float* dse_w1 = (const float*)d_in[20];
    const float* dse_b1 = (const float*)d_in[21];
    const float* dse_w2 = (const float*)d_in[22];
    const float* dse_b2 = (const float*)d_in[23];
    const float* dsa_w  = (const float*)d_in[24];
    float* out = (float*)d_out;

    float* A      = (float*)d_ws;
    float* C      = A + T63;
    float* pooled = C + T62;
    float* g      = pooled + 8192;
    float* am     = g + 8192;
    float* ssmap  = am + (size_t)NB*2*HW1;
    float* cbn    = ssmap + (size_t)NB*HW1;
    unsigned short* apackE = (unsigned short*)(cbn + 512);   // 262144 ushort (conv2)
    unsigned short* apackD = apackE + 262144;                 // 262144 ushort (dt1)
    unsigned short* cbp    = apackD + 262144;                 // 131072 ushort (codebook bf16)
    float* sse    = (float*)(cbp + 131072);
    int*   counts = (int*)(sse + 1);
    int*   idx    = counts + 512;

    // prep
    zero_small<<<1, 256, 0, stream>>>(sse, counts);
    prepack_w<<<1024, 256, 0, stream>>>(ec2_w, apackE, 0);
    prepack_w<<<1024, 256, 0, stream>>>(dt1_w, apackD, 1);
    cb_norm<<<1, 256, 0, stream>>>(cbk, cbn);
    cb_pack<<<512, 256, 0, stream>>>(cbk, cbp);

    // encoder conv1 + cbam1 (in-place on A)
    conv1_relu<<<dim3(NB*256, 16), 256, 0, stream>>>(x, ec1_w, ec1_b, A);
    gap_kernel<<<NB*256, 256, 0, stream>>>(A, pooled, HW1);
    se_mlp<<<NB, 256, 0, stream>>>(pooled, se1_w1, se1_b1, se1_w2, se1_b2, g);
    chanpool<<<dim3(16, NB), 256, 0, stream>>>(A, g, am, HW1);
    spatial_conv<<<dim3(16, NB), 256, 0, stream>>>(am, sa1_w, ssmap, 63, 63, 0);
    cbam_final<<<dim3(HW1, NB), 256, 0, stream>>>(A, g, ssmap, HW1);

    // conv2 (A -> C, MFMA) + cbam2 (in-place on C)  => z in C
    convk2_mfma<<<dim3(256, NB), 256, 0, stream>>>(A, apackE, ec2_b, C, 63, 63, 62, 62, 0);
    gap_kernel<<<NB*256, 256, 0, stream>>>(C, pooled, HW2);
    se_mlp<<<NB, 256, 0, stream>>>(pooled, se2_w1, se2_b1, se2_w2, se2_b2, g);
    chanpool<<<dim3(16, NB), 256, 0, stream>>>(C, g, am, HW2);
    spatial_conv<<<dim3(16, NB), 256, 0, stream>>>(am, sa2_w, ssmap, 62, 62, 0);
    cbam_final<<<dim3(HW2, NB), 256, 0, stream>>>(C, g, ssmap, HW2);

    // VQ: z in C -> q in C (in-place)
    vq_assign_mfma<<<NROWS/32, 256, 0, stream>>>(C, cbp, cbn, idx);
    vq_gather<<<GATHER_BLOCKS, 256, 0, stream>>>(C, cbk, idx, sse, counts);
    vq_finalize<<<1, 256, 0, stream>>>(sse, counts, out);

    // decoder dt1 (C -> A, MFMA) + cbam3 (in-place on A)
    convk2_mfma<<<dim3(256, NB), 256, 0, stream>>>(C, apackD, dt1_b, A, 62, 62, 63, 63, 1);
    gap_kernel<<<NB*256, 256, 0, stream>>>(A, pooled, HW1);
    se_mlp<<<NB, 256, 0, stream>>>(pooled, dse_w1, dse_b1, dse_w2, dse_b2, g);
    chanpool<<<dim3(16, NB), 256, 0, stream>>>(A, g, am, HW1);
    spatial_conv<<<dim3(16, NB), 256, 0, stream>>>(am, dsa_w, ssmap, 63, 63, 1);
    cbam_final<<<dim3(HW1, NB), 256, 0, stream>>>(A, g, ssmap, HW1);

    // final convT -> out
    dt2_kernel<<<dim3(192, NB), 256, 0, stream>>>(A, dt2_w, dt2_b, out);
}

// Round 6
// 1621.542 us; speedup vs baseline: 3.7572x; 1.1641x over previous
//
#include <hip/hip_runtime.h>
#include <math.h>

// ---------------- sizes ----------------
#define NB 32
#define HID 256
#define HW1 (63*63)      // 3969
#define HW2 (62*62)      // 3844
#define T63 ((size_t)NB*HID*HW1)   // 32,514,048
#define T62 ((size_t)NB*HID*HW2)   // 31,490,048
#define NROWS 123008               // T62 / 256
#define KCB 512
#define GATHER_BLOCKS 1024

typedef __attribute__((ext_vector_type(8))) short short8;
typedef __attribute__((ext_vector_type(4))) float f32x4;
typedef __attribute__((ext_vector_type(4))) unsigned short us4;

__device__ __forceinline__ unsigned short f2bf(float f) {
    union { float f; unsigned int u; } v; v.f = f;
    unsigned int u = v.u;
    return (unsigned short)((u + 0x7FFFu + ((u >> 16) & 1u)) >> 16);
}

// ---------------- zero small scratch (sse + counts) ----------------
__global__ __launch_bounds__(256) void zero_small(float* __restrict__ sse, int* __restrict__ counts) {
    if (threadIdx.x == 0) sse[0] = 0.f;
    for (int i = threadIdx.x; i < KCB; i += 256) counts[i] = 0;
}

// ---------------- conv1: 3->256, k4, s2, bias, relu ----------------
__global__ __launch_bounds__(256) void conv1_relu(
    const float* __restrict__ x, const float* __restrict__ w,
    const float* __restrict__ bias, float* __restrict__ out) {
    int b = blockIdx.x >> 8, co = blockIdx.x & 255;
    int ow = threadIdx.x & 63, oh = (blockIdx.y << 2) + (threadIdx.x >> 6);
    __shared__ float ws[48];
    if (threadIdx.x < 48) ws[threadIdx.x] = w[co*48 + threadIdx.x];
    __syncthreads();
    if (ow >= 63 || oh >= 63) return;
    float acc = bias[co];
    const float* xb = x + (size_t)b*3*128*128;
    int ih0 = oh*2, iw0 = ow*2;
    #pragma unroll
    for (int ci = 0; ci < 3; ++ci)
      #pragma unroll
      for (int kh = 0; kh < 4; ++kh) {
        const float* row = xb + ((size_t)ci*128 + ih0+kh)*128 + iw0;
        #pragma unroll
        for (int kw = 0; kw < 4; ++kw)
            acc = fmaf(row[kw], ws[ci*16+kh*4+kw], acc);
      }
    out[((size_t)(b*HID+co)*63 + oh)*63 + ow] = fmaxf(acc, 0.f);
}

// ---------------- global average pool over spatial ----------------
__global__ __launch_bounds__(256) void gap_kernel(
    const float* __restrict__ x, float* __restrict__ pooled, int HW) {
    int bc = blockIdx.x;
    const float* p = x + (size_t)bc*HW;
    float s = 0.f;
    for (int i = threadIdx.x; i < HW; i += 256) s += p[i];
    __shared__ float lds[4];
    for (int off = 32; off; off >>= 1) s += __shfl_down(s, off, 64);
    if ((threadIdx.x & 63) == 0) lds[threadIdx.x >> 6] = s;
    __syncthreads();
    if (threadIdx.x == 0) pooled[bc] = (lds[0]+lds[1]+lds[2]+lds[3]) / (float)HW;
}

// ---------------- SE MLP ----------------
__global__ __launch_bounds__(256) void se_mlp(
    const float* __restrict__ pooled, const float* __restrict__ w1,
    const float* __restrict__ b1, const float* __restrict__ w2,
    const float* __restrict__ b2, float* __restrict__ g) {
    int b = blockIdx.x;
    __shared__ float ps[256], hs[16];
    ps[threadIdx.x] = pooled[b*256 + threadIdx.x];
    __syncthreads();
    if (threadIdx.x < 16) {
        float a = b1[threadIdx.x];
        const float* wr = w1 + threadIdx.x*256;
        for (int k = 0; k < 256; ++k) a = fmaf(ps[k], wr[k], a);
        hs[threadIdx.x] = fmaxf(a, 0.f);
    }
    __syncthreads();
    float a = b2[threadIdx.x];
    const float* wr = w2 + threadIdx.x*16;
    #pragma unroll
    for (int j = 0; j < 16; ++j) a = fmaf(hs[j], wr[j], a);
    g[b*256 + threadIdx.x] = 1.f / (1.f + expf(-a));
}

// ---------------- channel mean/max of x*g ----------------
__global__ __launch_bounds__(256) void chanpool(
    const float* __restrict__ x, const float* __restrict__ g,
    float* __restrict__ am, int HW) {
    int b = blockIdx.y;
    int p = blockIdx.x*256 + threadIdx.x;
    if (p >= HW) return;
    const float* xb = x + (size_t)b*256*HW + p;
    const float* gb = g + b*256;
    float s = 0.f, mx = -3.0e38f;
    for (int c = 0; c < 256; ++c) {
        float v = xb[(size_t)c*HW] * gb[c];
        s += v; mx = fmaxf(mx, v);
    }
    am[((size_t)b*2)*HW + p]   = s * (1.f/256.f);
    am[((size_t)b*2+1)*HW + p] = mx;
}

// ---------------- 7x7 spatial conv on [mean,max], sigmoid ----------------
__global__ __launch_bounds__(256) void spatial_conv(
    const float* __restrict__ am, const float* __restrict__ sw,
    float* __restrict__ ss, int H, int W, int transpose) {
    int b = blockIdx.y;
    int p = blockIdx.x*256 + threadIdx.x;
    __shared__ float ws[98];
    if (threadIdx.x < 98) {
        int c = threadIdx.x / 49, k = threadIdx.x % 49;
        int kh = k / 7, kw = k % 7;
        ws[threadIdx.x] = transpose ? sw[c*49 + (6-kh)*7 + (6-kw)]
                                    : sw[c*49 + kh*7 + kw];
    }
    __syncthreads();
    if (p >= H*W) return;
    int oh = p / W, ow = p % W;
    float acc = 0.f;
    #pragma unroll
    for (int c = 0; c < 2; ++c) {
        const float* ab = am + ((size_t)b*2 + c)*H*W;
        for (int kh = 0; kh < 7; ++kh) {
            int ih = oh + kh - 3;
            if (ih < 0 || ih >= H) continue;
            for (int kw = 0; kw < 7; ++kw) {
                int iw = ow + kw - 3;
                if (iw < 0 || iw >= W) continue;
                acc = fmaf(ab[(size_t)ih*W + iw], ws[c*49 + kh*7 + kw], acc);
            }
        }
    }
    ss[(size_t)b*H*W + p] = 1.f / (1.f + expf(-acc));
}

// ---------------- IN-PLACE: x = x*x*g*sig(s) ----------------
__global__ __launch_bounds__(256) void cbam_final(
    float* x, const float* __restrict__ g,
    const float* __restrict__ ss, int HW) {
    int b = blockIdx.y;
    size_t e = (size_t)blockIdx.x*256 + threadIdx.x;
    if (e >= (size_t)256*HW) return;
    int c = (int)(e / HW), p = (int)(e % HW);
    float* px = x + (size_t)b*256*HW + e;
    float xv = *px;
    *px = xv * xv * g[b*256+c] * ss[(size_t)b*HW + p];
}

// ---------------- weight prepack into MFMA-fragment layout (bf16) ----------------
__global__ __launch_bounds__(256) void prepack_w(
    const float* __restrict__ w, unsigned short* __restrict__ pack, int transpose_flip) {
    int t = blockIdx.x*256 + threadIdx.x;
    int j = t & 7, koct = (t >> 3) & 3, co = (t >> 5) & 255, tap = (t >> 13) & 3, cc = t >> 15;
    int ci = cc*32 + koct*8 + j;
    int kh = tap >> 1, kw = tap & 1;
    float v;
    if (transpose_flip) v = w[((size_t)ci*256 + co)*4 + (1-kh)*2 + (1-kw)];
    else                v = w[((size_t)co*256 + ci)*4 + kh*2 + kw];
    pack[t] = f2bf(v);
}

// ---------------- MFMA conv k=2 s=1, co=256 per block, double-buffered LDS ----------------
// block: 256co x 64px (8x8 spatial); 4 waves, each 64co (4 co-frags) x 64px (4 px-frags).
// K=1024 as 8 ci-chunks x 4 taps; one barrier per chunk; staging amortized over all 256 co.
__global__ __launch_bounds__(256) void convk2_mfma(
    const float* __restrict__ in, const unsigned short* __restrict__ apack,
    const float* __restrict__ bias, float* __restrict__ out,
    int inH, int inW, int outH, int outW, int pad) {
    __shared__ __align__(16) unsigned short Iraw[2][81*40];  // [buf][sp=9x9][ci=32]
    int b = blockIdx.y;
    int t = blockIdx.x;                       // 64 spatial tiles
    int oh0 = (t >> 3) * 8, ow0 = (t & 7) * 8;
    int w = threadIdx.x >> 6, l = threadIdx.x & 63;
    int lr = l & 15, lk = l >> 4;
    // staging mapping: cp = ci-pair (0..15 -> ci {2cp,2cp+1}), scc = sp stripe
    int cp = threadIdx.x >> 4, scc = threadIdx.x & 15;
    const float* inb = in + ((size_t)b*256 + 2*cp)*inH*inW;
    size_t chstride = (size_t)inH*inW;

    f32x4 acc[4][4];
    #pragma unroll
    for (int i = 0; i < 4; ++i)
        #pragma unroll
        for (int j = 0; j < 4; ++j) acc[i][j] = (f32x4){0.f,0.f,0.f,0.f};

    auto STAGE = [&](int cc, int bufi) {
        const float* c0 = inb + (size_t)cc*32*chstride;
        const float* c1 = c0 + chstride;
        #pragma unroll
        for (int it = 0; it < 6; ++it) {
            int sp = scc + it*16;
            if (sp < 81) {
                int r = (sp*456) >> 12, c = sp - 9*r;
                int gh = oh0 + r - pad, gw = ow0 + c - pad;
                bool v = (gh >= 0) && (gh < inH) && (gw >= 0) && (gw < inW);
                size_t off = (size_t)gh*inW + gw;
                float f0 = v ? c0[off] : 0.f;
                float f1 = v ? c1[off] : 0.f;
                unsigned int pk = (unsigned int)f2bf(f0) | ((unsigned int)f2bf(f1) << 16);
                *(unsigned int*)&Iraw[bufi][sp*40 + 2*cp] = pk;
            }
        }
    };

    STAGE(0, 0);
    int spb_lane = (lr >> 3)*9 + (lr & 7);    // lane's base spatial slot within tile
    for (int cc = 0; cc < 8; ++cc) {
        __syncthreads();
        if (cc < 7) STAGE(cc+1, (cc+1)&1);
        const unsigned short* Ib = Iraw[cc & 1];
        #pragma unroll
        for (int tap = 0; tap < 4; ++tap) {
            int spb = (tap >> 1)*9 + (tap & 1) + spb_lane;
            short8 b0 = *(const short8*)&Ib[(spb      )*40 + lk*8];
            short8 b1 = *(const short8*)&Ib[(spb + 18 )*40 + lk*8];
            short8 b2 = *(const short8*)&Ib[(spb + 36 )*40 + lk*8];
            short8 b3 = *(const short8*)&Ib[(spb + 54 )*40 + lk*8];
            const unsigned short* abase = apack + (((size_t)(cc*4 + tap)*256)*4 + (size_t)lk)*8;
            #pragma unroll
            for (int cof = 0; cof < 4; ++cof) {
                int co = w*64 + cof*16 + lr;
                short8 af = *(const short8*)(abase + (size_t)co*32);
                acc[cof][0] = __builtin_amdgcn_mfma_f32_16x16x32_bf16(af, b0, acc[cof][0], 0, 0, 0);
                acc[cof][1] = __builtin_amdgcn_mfma_f32_16x16x32_bf16(af, b1, acc[cof][1], 0, 0, 0);
                acc[cof][2] = __builtin_amdgcn_mfma_f32_16x16x32_bf16(af, b2, acc[cof][2], 0, 0, 0);
                acc[cof][3] = __builtin_amdgcn_mfma_f32_16x16x32_bf16(af, b3, acc[cof][3], 0, 0, 0);
            }
        }
    }
    #pragma unroll
    for (int cof = 0; cof < 4; ++cof) {
        int cob = w*64 + cof*16 + lk*4;
        float4 bz = *(const float4*)&bias[cob];
        #pragma unroll
        for (int pxf = 0; pxf < 4; ++pxf) {
            f32x4 a = acc[cof][pxf];
            int px = pxf*16 + lr;
            int oh = oh0 + (px >> 3), ow = ow0 + (px & 7);
            if (oh < outH && ow < outW) {
                size_t base = ((size_t)(b*256 + cob)*outH + oh)*outW + ow;
                size_t st = (size_t)outH*outW;
                out[base]        = fmaxf(a.x + bz.x, 0.f);
                out[base +   st] = fmaxf(a.y + bz.y, 0.f);
                out[base + 2*st] = fmaxf(a.z + bz.z, 0.f);
                out[base + 3*st] = fmaxf(a.w + bz.w, 0.f);
            }
        }
    }
}

// ---------------- codebook norms (fp32, exact) ----------------
__global__ __launch_bounds__(256) void cb_norm(
    const float* __restrict__ cb, float* __restrict__ cbn) {
    for (int n = threadIdx.x; n < KCB; n += 256) {
        float s = 0.f;
        for (int k = 0; k < 256; ++k) { float v = cb[(size_t)n*256+k]; s = fmaf(v,v,s); }
        cbn[n] = s;
    }
}

// ---------------- codebook bf16 pack [n][k] ----------------
__global__ __launch_bounds__(256) void cb_pack(
    const float* __restrict__ cb, unsigned short* __restrict__ cbp) {
    int t = blockIdx.x*256 + threadIdx.x;
    cbp[t] = f2bf(cb[t]);
}

// ---------------- MFMA VQ assign ----------------
__global__ __launch_bounds__(256) void vq_assign_mfma(
    const float* __restrict__ z, const unsigned short* __restrict__ cbp,
    const float* __restrict__ cbn, int* __restrict__ idx) {
    __shared__ __align__(16) unsigned short zb[32*264];
    __shared__ float red_d[2][32];
    __shared__ int   red_i[2][32];
    int r0 = blockIdx.x * 32;
    for (int v = threadIdx.x; v < 2048; v += 256) {
        int row = v >> 6, col4 = v & 63;
        float4 u = *(const float4*)&z[(size_t)(r0+row)*256 + col4*4];
        us4 pk = { f2bf(u.x), f2bf(u.y), f2bf(u.z), f2bf(u.w) };
        *(us4*)&zb[row*264 + col4*4] = pk;
    }
    __syncthreads();
    int w = threadIdx.x >> 6, l = threadIdx.x & 63;
    int wm = w >> 1, wn = w & 1;
    int lr = l & 15, lk = l >> 4;
    short8 afr[8];
    #pragma unroll
    for (int ks = 0; ks < 8; ++ks)
        afr[ks] = *(const short8*)&zb[(wm*16 + lr)*264 + ks*32 + lk*8];
    f32x4 acc[16];
    #pragma unroll
    for (int nf = 0; nf < 16; ++nf) acc[nf] = (f32x4){0.f,0.f,0.f,0.f};
    #pragma unroll
    for (int nf = 0; nf < 16; ++nf) {
        const unsigned short* cbase = cbp + ((size_t)(wn*256 + nf*16 + lr))*256 + lk*8;
        #pragma unroll
        for (int ks = 0; ks < 8; ++ks) {
            short8 bfr = *(const short8*)(cbase + ks*32);
            acc[nf] = __builtin_amdgcn_mfma_f32_16x16x32_bf16(afr[ks], bfr, acc[nf], 0, 0, 0);
        }
    }
    float bd[4]; int bi[4];
    #pragma unroll
    for (int r = 0; r < 4; ++r) { bd[r] = 3.0e38f; bi[r] = 0; }
    #pragma unroll
    for (int nf = 0; nf < 16; ++nf) {
        int n = wn*256 + nf*16 + lr;
        float cn = cbn[n];
        #pragma unroll
        for (int r = 0; r < 4; ++r) {
            float dist = fmaf(-2.f, acc[nf][r], cn);
            if (dist < bd[r]) { bd[r] = dist; bi[r] = n; }
        }
    }
    #pragma unroll
    for (int r = 0; r < 4; ++r) {
        #pragma unroll
        for (int off = 1; off < 16; off <<= 1) {
            float od = __shfl_xor(bd[r], off, 64);
            int   oi = __shfl_xor(bi[r], off, 64);
            if (od < bd[r] || (od == bd[r] && oi < bi[r])) { bd[r] = od; bi[r] = oi; }
        }
    }
    if (lr == 0) {
        #pragma unroll
        for (int r = 0; r < 4; ++r) {
            int row = wm*16 + lk*4 + r;
            red_d[wn][row] = bd[r];
            red_i[wn][row] = bi[r];
        }
    }
    __syncthreads();
    if (threadIdx.x < 32) {
        int row = threadIdx.x;
        float d0 = red_d[0][row], d1 = red_d[1][row];
        int   i0 = red_i[0][row], i1 = red_i[1][row];
        idx[r0 + row] = (d1 < d0) ? i1 : i0;
    }
}

// ---------------- IN-PLACE VQ gather ----------------
__global__ __launch_bounds__(256) void vq_gather(
    float* zq, const float* __restrict__ cb,
    const int* __restrict__ idx, float* __restrict__ sse, int* __restrict__ counts) {
    __shared__ int hist[KCB];
    for (int i = threadIdx.x; i < KCB; i += 256) hist[i] = 0;
    __syncthreads();
    float local = 0.f;
    for (int r = blockIdx.x; r < NROWS; r += GATHER_BLOCKS) {
        int id = idx[r];
        if (threadIdx.x == 0) atomicAdd(&hist[id], 1);
        float qv = cb[(size_t)id*256 + threadIdx.x];
        float* pz = zq + (size_t)r*256 + threadIdx.x;
        float zv = *pz;
        *pz = qv;
        float d = qv - zv;
        local = fmaf(d, d, local);
    }
    __shared__ float lds[4];
    for (int off = 32; off; off >>= 1) local += __shfl_down(local, off, 64);
    if ((threadIdx.x & 63) == 0) lds[threadIdx.x >> 6] = local;
    __syncthreads();
    if (threadIdx.x == 0) atomicAdd(sse, lds[0]+lds[1]+lds[2]+lds[3]);
    for (int i = threadIdx.x; i < KCB; i += 256) {
        int h = hist[i];
        if (h) atomicAdd(counts + i, h);
    }
}

// ---------------- loss + perplexity ----------------
__global__ __launch_bounds__(256) void vq_finalize(
    const float* __restrict__ sse, const int* __restrict__ counts,
    float* __restrict__ out) {
    __shared__ float lds[4];
    float h = 0.f;
    for (int n = threadIdx.x; n < KCB; n += 256) {
        float p = (float)counts[n] * (1.f/123008.f);
        h += p * logf(p + 1e-10f);
    }
    for (int off = 32; off; off >>= 1) h += __shfl_down(h, off, 64);
    if ((threadIdx.x & 63) == 0) lds[threadIdx.x >> 6] = h;
    __syncthreads();
    if (threadIdx.x == 0) {
        out[1572864] = 1.25f * sse[0] / 31490048.f;
        out[1572865] = expf(-(lds[0]+lds[1]+lds[2]+lds[3]));
    }
}

// ---------------- dt2: convT 256->3, k4, s2 ----------------
__global__ __launch_bounds__(256) void dt2_kernel(
    const float* __restrict__ d, const float* __restrict__ w,
    const float* __restrict__ bias, float* __restrict__ out) {
    int b = blockIdx.y;
    int co = blockIdx.x / 64;
    int h = (blockIdx.x % 64)*2 + (threadIdx.x >> 7);
    int wpos = threadIdx.x & 127;
    __shared__ float ws[4096];
    for (int t = threadIdx.x; t < 4096; t += 256) {
        int ci = t >> 4, k = t & 15;
        ws[t] = w[(size_t)ci*48 + co*16 + k];
    }
    __syncthreads();
    int kh0 = h & 1, kw0 = wpos & 1;
    int ih0 = (h - kh0) >> 1, iw0 = (wpos - kw0) >> 1;
    bool vh0 = (ih0 < 63), vh1 = (ih0 >= 1);
    bool vw0 = (iw0 < 63), vw1 = (iw0 >= 1);
    float acc = bias[co];
    const float* db = d + (size_t)b*256*HW1;
    for (int ci = 0; ci < 256; ++ci) {
        const float* dc = db + (size_t)ci*HW1;
        const float* wc = ws + ci*16;
        float v00 = (vh0 && vw0) ? dc[ih0*63 + iw0]       : 0.f;
        float v01 = (vh0 && vw1) ? dc[ih0*63 + iw0 - 1]   : 0.f;
        float v10 = (vh1 && vw0) ? dc[(ih0-1)*63 + iw0]   : 0.f;
        float v11 = (vh1 && vw1) ? dc[(ih0-1)*63 + iw0-1] : 0.f;
        acc = fmaf(v00, wc[kh0*4 + kw0],         acc);
        acc = fmaf(v01, wc[kh0*4 + kw0 + 2],     acc);
        acc = fmaf(v10, wc[(kh0+2)*4 + kw0],     acc);
        acc = fmaf(v11, wc[(kh0+2)*4 + kw0 + 2], acc);
    }
    out[((size_t)(b*3+co)*128 + h)*128 + wpos] = acc;
}

// ---------------- launch ----------------
extern "C" void kernel_launch(void* const* d_in, const int* in_sizes, int n_in,
                              void* d_out, int out_size, void* d_ws, size_t ws_size,
                              hipStream_t stream) {
    const float* x      = (const float*)d_in[0];
    const float* ec1_w  = (const float*)d_in[1];
    const float* ec1_b  = (const float*)d_in[2];
    const float* ec2_w  = (const float*)d_in[3];
    const float* ec2_b  = (const float*)d_in[4];
    const float* se1_w1 = (const float*)d_in[5];
    const float* se1_b1 = (const float*)d_in[6];
    const float* se1_w2 = (const float*)d_in[7];
    const float* se1_b2 = (const float*)d_in[8];
    const float* sa1_w  = (const float*)d_in[9];
    const float* se2_w1 = (const float*)d_in[10];
    const float* se2_b1 = (const float*)d_in[11];
    const float* se2_w2 = (const float*)d_in[12];
    const float* se2_b2 = (const float*)d_in[13];
    const float* sa2_w  = (const float*)d_in[14];
    const float* cbk    = (const float*)d_in[15];
    const float* dt1_w  = (const float*)d_in[16];
    const float* dt1_b  = (const float*)d_in[17];
    const float* dt2_w  = (const float*)d_in[18];
    const float* dt2_b  = (const float*)d_in[19];
    const float* dse_w1 = (const float*)d_in[20];
    const float* dse_b1 = (const float*)d_in[21];
    const float* dse_w2 = (const float*)d_in[22];
    const float* dse_b2 = (const float*)d_in[23];
    const float* dsa_w  = (const float*)d_in[24];
    float* out = (float*)d_out;

    float* A      = (float*)d_ws;
    float* C      = A + T63;
    float* pooled = C + T62;
    float* g      = pooled + 8192;
    float* am     = g + 8192;
    float* ssmap  = am + (size_t)NB*2*HW1;
    float* cbn    = ssmap + (size_t)NB*HW1;
    unsigned short* apackE = (unsigned short*)(cbn + 512);
    unsigned short* apackD = apackE + 262144;
    unsigned short* cbp    = apackD + 262144;
    float* sse    = (float*)(cbp + 131072);
    int*   counts = (int*)(sse + 1);
    int*   idx    = counts + 512;

    // prep
    zero_small<<<1, 256, 0, stream>>>(sse, counts);
    prepack_w<<<1024, 256, 0, stream>>>(ec2_w, apackE, 0);
    prepack_w<<<1024, 256, 0, stream>>>(dt1_w, apackD, 1);
    cb_norm<<<1, 256, 0, stream>>>(cbk, cbn);
    cb_pack<<<512, 256, 0, stream>>>(cbk, cbp);

    // encoder conv1 + cbam1 (in-place on A)
    conv1_relu<<<dim3(NB*256, 16), 256, 0, stream>>>(x, ec1_w, ec1_b, A);
    gap_kernel<<<NB*256, 256, 0, stream>>>(A, pooled, HW1);
    se_mlp<<<NB, 256, 0, stream>>>(pooled, se1_w1, se1_b1, se1_w2, se1_b2, g);
    chanpool<<<dim3(16, NB), 256, 0, stream>>>(A, g, am, HW1);
    spatial_conv<<<dim3(16, NB), 256, 0, stream>>>(am, sa1_w, ssmap, 63, 63, 0);
    cbam_final<<<dim3(HW1, NB), 256, 0, stream>>>(A, g, ssmap, HW1);

    // conv2 (A -> C, MFMA co=256) + cbam2 (in-place on C)  => z in C
    convk2_mfma<<<dim3(64, NB), 256, 0, stream>>>(A, apackE, ec2_b, C, 63, 63, 62, 62, 0);
    gap_kernel<<<NB*256, 256, 0, stream>>>(C, pooled, HW2);
    se_mlp<<<NB, 256, 0, stream>>>(pooled, se2_w1, se2_b1, se2_w2, se2_b2, g);
    chanpool<<<dim3(16, NB), 256, 0, stream>>>(C, g, am, HW2);
    spatial_conv<<<dim3(16, NB), 256, 0, stream>>>(am, sa2_w, ssmap, 62, 62, 0);
    cbam_final<<<dim3(HW2, NB), 256, 0, stream>>>(C, g, ssmap, HW2);

    // VQ: z in C -> q in C (in-place)
    vq_assign_mfma<<<NROWS/32, 256, 0, stream>>>(C, cbp, cbn, idx);
    vq_gather<<<GATHER_BLOCKS, 256, 0, stream>>>(C, cbk, idx, sse, counts);
    vq_finalize<<<1, 256, 0, stream>>>(sse, counts, out);

    // decoder dt1 (C -> A, MFMA co=256) + cbam3 (in-place on A)
    convk2_mfma<<<dim3(64, NB), 256, 0, stream>>>(C, apackD, dt1_b, A, 62, 62, 63, 63, 1);
    gap_kernel<<<NB*256, 256, 0, stream>>>(A, pooled, HW1);
    se_mlp<<<NB, 256, 0, stream>>>(pooled, dse_w1, dse_b1, dse_w2, dse_b2, g);
    chanpool<<<dim3(16, NB), 256, 0, stream>>>(A, g, am, HW1);
    spatial_conv<<<dim3(16, NB), 256, 0, stream>>>(am, dsa_w, ssmap, 63, 63, 1);
    cbam_final<<<dim3(HW1, NB), 256, 0, stream>>>(A, g, ssmap, HW1);

    // final convT -> out
    dt2_kernel<<<dim3(192, NB), 256, 0, stream>>>(A, dt2_w, dt2_b, out);
}

// Round 7
// 1449.430 us; speedup vs baseline: 4.2033x; 1.1187x over previous
//
#include <hip/hip_runtime.h>
#include <math.h>

// ---------------- sizes ----------------
#define NB 32
#define HID 256
#define HW1 (63*63)      // 3969
#define HW2 (62*62)      // 3844
#define T63 ((size_t)NB*HID*HW1)   // 32,514,048
#define T62 ((size_t)NB*HID*HW2)   // 31,490,048
#define NROWS 123008               // T62 / 256
#define KCB 512
#define GATHER_BLOCKS 1024

typedef __attribute__((ext_vector_type(8))) short short8;
typedef __attribute__((ext_vector_type(4))) float f32x4;
typedef __attribute__((ext_vector_type(4))) unsigned short us4;

__device__ __forceinline__ unsigned short f2bf(float f) {
    union { float f; unsigned int u; } v; v.f = f;
    unsigned int u = v.u;
    return (unsigned short)((u + 0x7FFFu + ((u >> 16) & 1u)) >> 16);
}

// ---------------- zero small scratch (sse + counts) ----------------
__global__ __launch_bounds__(256) void zero_small(float* __restrict__ sse, int* __restrict__ counts) {
    if (threadIdx.x == 0) sse[0] = 0.f;
    for (int i = threadIdx.x; i < KCB; i += 256) counts[i] = 0;
}

// ---------------- conv1: 3->256, k4, s2, bias, relu ----------------
__global__ __launch_bounds__(256) void conv1_relu(
    const float* __restrict__ x, const float* __restrict__ w,
    const float* __restrict__ bias, float* __restrict__ out) {
    int b = blockIdx.x >> 8, co = blockIdx.x & 255;
    int ow = threadIdx.x & 63, oh = (blockIdx.y << 2) + (threadIdx.x >> 6);
    __shared__ float ws[48];
    if (threadIdx.x < 48) ws[threadIdx.x] = w[co*48 + threadIdx.x];
    __syncthreads();
    if (ow >= 63 || oh >= 63) return;
    float acc = bias[co];
    const float* xb = x + (size_t)b*3*128*128;
    int ih0 = oh*2, iw0 = ow*2;
    #pragma unroll
    for (int ci = 0; ci < 3; ++ci)
      #pragma unroll
      for (int kh = 0; kh < 4; ++kh) {
        const float* row = xb + ((size_t)ci*128 + ih0+kh)*128 + iw0;
        #pragma unroll
        for (int kw = 0; kw < 4; ++kw)
            acc = fmaf(row[kw], ws[ci*16+kh*4+kw], acc);
      }
    out[((size_t)(b*HID+co)*63 + oh)*63 + ow] = fmaxf(acc, 0.f);
}

// ---------------- global average pool over spatial ----------------
__global__ __launch_bounds__(256) void gap_kernel(
    const float* __restrict__ x, float* __restrict__ pooled, int HW) {
    int bc = blockIdx.x;
    const float* p = x + (size_t)bc*HW;
    float s = 0.f;
    for (int i = threadIdx.x; i < HW; i += 256) s += p[i];
    __shared__ float lds[4];
    for (int off = 32; off; off >>= 1) s += __shfl_down(s, off, 64);
    if ((threadIdx.x & 63) == 0) lds[threadIdx.x >> 6] = s;
    __syncthreads();
    if (threadIdx.x == 0) pooled[bc] = (lds[0]+lds[1]+lds[2]+lds[3]) / (float)HW;
}

// ---------------- SE MLP ----------------
__global__ __launch_bounds__(256) void se_mlp(
    const float* __restrict__ pooled, const float* __restrict__ w1,
    const float* __restrict__ b1, const float* __restrict__ w2,
    const float* __restrict__ b2, float* __restrict__ g) {
    int b = blockIdx.x;
    __shared__ float ps[256], hs[16];
    ps[threadIdx.x] = pooled[b*256 + threadIdx.x];
    __syncthreads();
    if (threadIdx.x < 16) {
        float a = b1[threadIdx.x];
        const float* wr = w1 + threadIdx.x*256;
        for (int k = 0; k < 256; ++k) a = fmaf(ps[k], wr[k], a);
        hs[threadIdx.x] = fmaxf(a, 0.f);
    }
    __syncthreads();
    float a = b2[threadIdx.x];
    const float* wr = w2 + threadIdx.x*16;
    #pragma unroll
    for (int j = 0; j < 16; ++j) a = fmaf(hs[j], wr[j], a);
    g[b*256 + threadIdx.x] = 1.f / (1.f + expf(-a));
}

// ---------------- channel mean/max of x*g ----------------
__global__ __launch_bounds__(256) void chanpool(
    const float* __restrict__ x, const float* __restrict__ g,
    float* __restrict__ am, int HW) {
    int b = blockIdx.y;
    int p = blockIdx.x*256 + threadIdx.x;
    if (p >= HW) return;
    const float* xb = x + (size_t)b*256*HW + p;
    const float* gb = g + b*256;
    float s = 0.f, mx = -3.0e38f;
    for (int c = 0; c < 256; ++c) {
        float v = xb[(size_t)c*HW] * gb[c];
        s += v; mx = fmaxf(mx, v);
    }
    am[((size_t)b*2)*HW + p]   = s * (1.f/256.f);
    am[((size_t)b*2+1)*HW + p] = mx;
}

// ---------------- 7x7 spatial conv on [mean,max], sigmoid ----------------
__global__ __launch_bounds__(256) void spatial_conv(
    const float* __restrict__ am, const float* __restrict__ sw,
    float* __restrict__ ss, int H, int W, int transpose) {
    int b = blockIdx.y;
    int p = blockIdx.x*256 + threadIdx.x;
    __shared__ float ws[98];
    if (threadIdx.x < 98) {
        int c = threadIdx.x / 49, k = threadIdx.x % 49;
        int kh = k / 7, kw = k % 7;
        ws[threadIdx.x] = transpose ? sw[c*49 + (6-kh)*7 + (6-kw)]
                                    : sw[c*49 + kh*7 + kw];
    }
    __syncthreads();
    if (p >= H*W) return;
    int oh = p / W, ow = p % W;
    float acc = 0.f;
    #pragma unroll
    for (int c = 0; c < 2; ++c) {
        const float* ab = am + ((size_t)b*2 + c)*H*W;
        for (int kh = 0; kh < 7; ++kh) {
            int ih = oh + kh - 3;
            if (ih < 0 || ih >= H) continue;
            for (int kw = 0; kw < 7; ++kw) {
                int iw = ow + kw - 3;
                if (iw < 0 || iw >= W) continue;
                acc = fmaf(ab[(size_t)ih*W + iw], ws[c*49 + kh*7 + kw], acc);
            }
        }
    }
    ss[(size_t)b*H*W + p] = 1.f / (1.f + expf(-acc));
}

// ---------------- IN-PLACE: x = x*x*g*sig(s) ----------------
__global__ __launch_bounds__(256) void cbam_final(
    float* x, const float* __restrict__ g,
    const float* __restrict__ ss, int HW) {
    int b = blockIdx.y;
    size_t e = (size_t)blockIdx.x*256 + threadIdx.x;
    if (e >= (size_t)256*HW) return;
    int c = (int)(e / HW), p = (int)(e % HW);
    float* px = x + (size_t)b*256*HW + e;
    float xv = *px;
    *px = xv * xv * g[b*256+c] * ss[(size_t)b*HW + p];
}

// ---------------- weight prepack into MFMA-fragment layout (bf16) ----------------
__global__ __launch_bounds__(256) void prepack_w(
    const float* __restrict__ w, unsigned short* __restrict__ pack, int transpose_flip) {
    int t = blockIdx.x*256 + threadIdx.x;
    int j = t & 7, koct = (t >> 3) & 3, co = (t >> 5) & 255, tap = (t >> 13) & 3, cc = t >> 15;
    int ci = cc*32 + koct*8 + j;
    int kh = tap >> 1, kw = tap & 1;
    float v;
    if (transpose_flip) v = w[((size_t)ci*256 + co)*4 + (1-kh)*2 + (1-kw)];
    else                v = w[((size_t)co*256 + ci)*4 + kh*2 + kw];
    pack[t] = f2bf(v);
}

// ---------------- MFMA conv k=2 s=1, co=256 per block, double-buffered LDS ----------------
__global__ __launch_bounds__(256) void convk2_mfma(
    const float* __restrict__ in, const unsigned short* __restrict__ apack,
    const float* __restrict__ bias, float* __restrict__ out,
    int inH, int inW, int outH, int outW, int pad) {
    __shared__ __align__(16) unsigned short Iraw[2][81*40];
    int b = blockIdx.y;
    int t = blockIdx.x;
    int oh0 = (t >> 3) * 8, ow0 = (t & 7) * 8;
    int w = threadIdx.x >> 6, l = threadIdx.x & 63;
    int lr = l & 15, lk = l >> 4;
    int cp = threadIdx.x >> 4, scc = threadIdx.x & 15;
    const float* inb = in + ((size_t)b*256 + 2*cp)*inH*inW;
    size_t chstride = (size_t)inH*inW;

    f32x4 acc[4][4];
    #pragma unroll
    for (int i = 0; i < 4; ++i)
        #pragma unroll
        for (int j = 0; j < 4; ++j) acc[i][j] = (f32x4){0.f,0.f,0.f,0.f};

    auto STAGE = [&](int cc, int bufi) {
        const float* c0 = inb + (size_t)cc*32*chstride;
        const float* c1 = c0 + chstride;
        #pragma unroll
        for (int it = 0; it < 6; ++it) {
            int sp = scc + it*16;
            if (sp < 81) {
                int r = (sp*456) >> 12, c = sp - 9*r;
                int gh = oh0 + r - pad, gw = ow0 + c - pad;
                bool v = (gh >= 0) && (gh < inH) && (gw >= 0) && (gw < inW);
                size_t off = (size_t)gh*inW + gw;
                float f0 = v ? c0[off] : 0.f;
                float f1 = v ? c1[off] : 0.f;
                unsigned int pk = (unsigned int)f2bf(f0) | ((unsigned int)f2bf(f1) << 16);
                *(unsigned int*)&Iraw[bufi][sp*40 + 2*cp] = pk;
            }
        }
    };

    STAGE(0, 0);
    int spb_lane = (lr >> 3)*9 + (lr & 7);
    for (int cc = 0; cc < 8; ++cc) {
        __syncthreads();
        if (cc < 7) STAGE(cc+1, (cc+1)&1);
        const unsigned short* Ib = Iraw[cc & 1];
        #pragma unroll
        for (int tap = 0; tap < 4; ++tap) {
            int spb = (tap >> 1)*9 + (tap & 1) + spb_lane;
            short8 b0 = *(const short8*)&Ib[(spb      )*40 + lk*8];
            short8 b1 = *(const short8*)&Ib[(spb + 18 )*40 + lk*8];
            short8 b2 = *(const short8*)&Ib[(spb + 36 )*40 + lk*8];
            short8 b3 = *(const short8*)&Ib[(spb + 54 )*40 + lk*8];
            const unsigned short* abase = apack + (((size_t)(cc*4 + tap)*256)*4 + (size_t)lk)*8;
            #pragma unroll
            for (int cof = 0; cof < 4; ++cof) {
                int co = w*64 + cof*16 + lr;
                short8 af = *(const short8*)(abase + (size_t)co*32);
                acc[cof][0] = __builtin_amdgcn_mfma_f32_16x16x32_bf16(af, b0, acc[cof][0], 0, 0, 0);
                acc[cof][1] = __builtin_amdgcn_mfma_f32_16x16x32_bf16(af, b1, acc[cof][1], 0, 0, 0);
                acc[cof][2] = __builtin_amdgcn_mfma_f32_16x16x32_bf16(af, b2, acc[cof][2], 0, 0, 0);
                acc[cof][3] = __builtin_amdgcn_mfma_f32_16x16x32_bf16(af, b3, acc[cof][3], 0, 0, 0);
            }
        }
    }
    #pragma unroll
    for (int cof = 0; cof < 4; ++cof) {
        int cob = w*64 + cof*16 + lk*4;
        float4 bz = *(const float4*)&bias[cob];
        #pragma unroll
        for (int pxf = 0; pxf < 4; ++pxf) {
            f32x4 a = acc[cof][pxf];
            int px = pxf*16 + lr;
            int oh = oh0 + (px >> 3), ow = ow0 + (px & 7);
            if (oh < outH && ow < outW) {
                size_t base = ((size_t)(b*256 + cob)*outH + oh)*outW + ow;
                size_t st = (size_t)outH*outW;
                out[base]        = fmaxf(a.x + bz.x, 0.f);
                out[base +   st] = fmaxf(a.y + bz.y, 0.f);
                out[base + 2*st] = fmaxf(a.z + bz.z, 0.f);
                out[base + 3*st] = fmaxf(a.w + bz.w, 0.f);
            }
        }
    }
}

// ---------------- codebook norms (fp32, exact) ----------------
__global__ __launch_bounds__(256) void cb_norm(
    const float* __restrict__ cb, float* __restrict__ cbn) {
    for (int n = threadIdx.x; n < KCB; n += 256) {
        float s = 0.f;
        for (int k = 0; k < 256; ++k) { float v = cb[(size_t)n*256+k]; s = fmaf(v,v,s); }
        cbn[n] = s;
    }
}

// ---------------- codebook bf16 pack [n][k] ----------------
__global__ __launch_bounds__(256) void cb_pack(
    const float* __restrict__ cb, unsigned short* __restrict__ cbp) {
    int t = blockIdx.x*256 + threadIdx.x;
    cbp[t] = f2bf(cb[t]);
}

// ---------------- MFMA VQ assign v2: LDS-staged codebook, 64 rows/block ----------------
// 4 waves, each owns 16 rows x all 512 codes; codebook streamed via double-buffered
// 32-code LDS tiles (ds_read B-frags ~12cyc vs ~200cyc L2); acc folded per chunk.
__global__ __launch_bounds__(256) void vq_assign_mfma(
    const float* __restrict__ z, const unsigned short* __restrict__ cbp,
    const float* __restrict__ cbn, int* __restrict__ idx) {
    __shared__ __align__(16) unsigned short zb[64*264];      // 33,792 B
    __shared__ __align__(16) unsigned short cbs[2][32*264];  // 2 x 16,896 B
    __shared__ float cbl[KCB];                               // 2 KB
    int r0 = blockIdx.x * 64;
    // stage Z: 64 rows x 256 k, fp32 -> bf16
    for (int v = threadIdx.x; v < 4096; v += 256) {
        int row = v >> 6, col4 = v & 63;
        float4 u = *(const float4*)&z[(size_t)(r0+row)*256 + col4*4];
        us4 pk = { f2bf(u.x), f2bf(u.y), f2bf(u.z), f2bf(u.w) };
        *(us4*)&zb[row*264 + col4*4] = pk;
    }
    for (int i = threadIdx.x; i < KCB; i += 256) cbl[i] = cbn[i];
    // codebook chunk staging: 32 codes x 256 k, 8 threads/code, 4x16B each
    int tcode = threadIdx.x >> 3, tk = threadIdx.x & 7;
    auto STAGE_CB = [&](int c, int bufi) {
        const unsigned short* src = cbp + ((size_t)(c*32 + tcode))*256 + tk*8;
        unsigned short* dst = &cbs[bufi][tcode*264 + tk*8];
        #pragma unroll
        for (int j = 0; j < 4; ++j)
            *(short8*)(dst + j*64) = *(const short8*)(src + j*64);
    };
    STAGE_CB(0, 0);
    __syncthreads();

    int w = threadIdx.x >> 6, l = threadIdx.x & 63;
    int lr = l & 15, lk = l >> 4;
    short8 afr[8];
    #pragma unroll
    for (int ks = 0; ks < 8; ++ks)
        afr[ks] = *(const short8*)&zb[(w*16 + lr)*264 + ks*32 + lk*8];

    float bd[4]; int bi[4];
    #pragma unroll
    for (int r = 0; r < 4; ++r) { bd[r] = 3.0e38f; bi[r] = 0; }

    for (int c = 0; c < 16; ++c) {
        if (c < 15) STAGE_CB(c+1, (c+1)&1);
        const unsigned short* Cb = cbs[c & 1];
        #pragma unroll
        for (int f = 0; f < 2; ++f) {
            f32x4 acc = (f32x4){0.f,0.f,0.f,0.f};
            #pragma unroll
            for (int ks = 0; ks < 8; ++ks) {
                short8 bfr = *(const short8*)&Cb[(f*16 + lr)*264 + ks*32 + lk*8];
                acc = __builtin_amdgcn_mfma_f32_16x16x32_bf16(afr[ks], bfr, acc, 0, 0, 0);
            }
            int n = c*32 + f*16 + lr;
            float cn = cbl[n];
            #pragma unroll
            for (int r = 0; r < 4; ++r) {
                float dist = fmaf(-2.f, acc[r], cn);
                if (dist < bd[r]) { bd[r] = dist; bi[r] = n; }  // ascending n: ties keep lowest
            }
        }
        __syncthreads();
    }
    // reduce across the 16 lr lanes (codes), per row
    #pragma unroll
    for (int r = 0; r < 4; ++r) {
        #pragma unroll
        for (int off = 1; off < 16; off <<= 1) {
            float od = __shfl_xor(bd[r], off, 64);
            int   oi = __shfl_xor(bi[r], off, 64);
            if (od < bd[r] || (od == bd[r] && oi < bi[r])) { bd[r] = od; bi[r] = oi; }
        }
    }
    if (lr == 0) {
        #pragma unroll
        for (int r = 0; r < 4; ++r)
            idx[r0 + w*16 + lk*4 + r] = bi[r];
    }
}

// ---------------- IN-PLACE VQ gather ----------------
__global__ __launch_bounds__(256) void vq_gather(
    float* zq, const float* __restrict__ cb,
    const int* __restrict__ idx, float* __restrict__ sse, int* __restrict__ counts) {
    __shared__ int hist[KCB];
    for (int i = threadIdx.x; i < KCB; i += 256) hist[i] = 0;
    __syncthreads();
    float local = 0.f;
    for (int r = blockIdx.x; r < NROWS; r += GATHER_BLOCKS) {
        int id = idx[r];
        if (threadIdx.x == 0) atomicAdd(&hist[id], 1);
        float qv = cb[(size_t)id*256 + threadIdx.x];
        float* pz = zq + (size_t)r*256 + threadIdx.x;
        float zv = *pz;
        *pz = qv;
        float d = qv - zv;
        local = fmaf(d, d, local);
    }
    __shared__ float lds[4];
    for (int off = 32; off; off >>= 1) local += __shfl_down(local, off, 64);
    if ((threadIdx.x & 63) == 0) lds[threadIdx.x >> 6] = local;
    __syncthreads();
    if (threadIdx.x == 0) atomicAdd(sse, lds[0]+lds[1]+lds[2]+lds[3]);
    for (int i = threadIdx.x; i < KCB; i += 256) {
        int h = hist[i];
        if (h) atomicAdd(counts + i, h);
    }
}

// ---------------- loss + perplexity ----------------
__global__ __launch_bounds__(256) void vq_finalize(
    const float* __restrict__ sse, const int* __restrict__ counts,
    float* __restrict__ out) {
    __shared__ float lds[4];
    float h = 0.f;
    for (int n = threadIdx.x; n < KCB; n += 256) {
        float p = (float)counts[n] * (1.f/123008.f);
        h += p * logf(p + 1e-10f);
    }
    for (int off = 32; off; off >>= 1) h += __shfl_down(h, off, 64);
    if ((threadIdx.x & 63) == 0) lds[threadIdx.x >> 6] = h;
    __syncthreads();
    if (threadIdx.x == 0) {
        out[1572864] = 1.25f * sse[0] / 31490048.f;
        out[1572865] = expf(-(lds[0]+lds[1]+lds[2]+lds[3]));
    }
}

// ---------------- dt2: convT 256->3, k4, s2 ----------------
__global__ __launch_bounds__(256) void dt2_kernel(
    const float* __restrict__ d, const float* __restrict__ w,
    const float* __restrict__ bias, float* __restrict__ out) {
    int b = blockIdx.y;
    int co = blockIdx.x / 64;
    int h = (blockIdx.x % 64)*2 + (threadIdx.x >> 7);
    int wpos = threadIdx.x & 127;
    __shared__ float ws[4096];
    for (int t = threadIdx.x; t < 4096; t += 256) {
        int ci = t >> 4, k = t & 15;
        ws[t] = w[(size_t)ci*48 + co*16 + k];
    }
    __syncthreads();
    int kh0 = h & 1, kw0 = wpos & 1;
    int ih0 = (h - kh0) >> 1, iw0 = (wpos - kw0) >> 1;
    bool vh0 = (ih0 < 63), vh1 = (ih0 >= 1);
    bool vw0 = (iw0 < 63), vw1 = (iw0 >= 1);
    float acc = bias[co];
    const float* db = d + (size_t)b*256*HW1;
    for (int ci = 0; ci < 256; ++ci) {
        const float* dc = db + (size_t)ci*HW1;
        const float* wc = ws + ci*16;
        float v00 = (vh0 && vw0) ? dc[ih0*63 + iw0]       : 0.f;
        float v01 = (vh0 && vw1) ? dc[ih0*63 + iw0 - 1]   : 0.f;
        float v10 = (vh1 && vw0) ? dc[(ih0-1)*63 + iw0]   : 0.f;
        float v11 = (vh1 && vw1) ? dc[(ih0-1)*63 + iw0-1] : 0.f;
        acc = fmaf(v00, wc[kh0*4 + kw0],         acc);
        acc = fmaf(v01, wc[kh0*4 + kw0 + 2],     acc);
        acc = fmaf(v10, wc[(kh0+2)*4 + kw0],     acc);
        acc = fmaf(v11, wc[(kh0+2)*4 + kw0 + 2], acc);
    }
    out[((size_t)(b*3+co)*128 + h)*128 + wpos] = acc;
}

// ---------------- launch ----------------
extern "C" void kernel_launch(void* const* d_in, const int* in_sizes, int n_in,
                              void* d_out, int out_size, void* d_ws, size_t ws_size,
                              hipStream_t stream) {
    const float* x      = (const float*)d_in[0];
    const float* ec1_w  = (const float*)d_in[1];
    const float* ec1_b  = (const float*)d_in[2];
    const float* ec2_w  = (const float*)d_in[3];
    const float* ec2_b  = (const float*)d_in[4];
    const float* se1_w1 = (const float*)d_in[5];
    const float* se1_b1 = (const float*)d_in[6];
    const float* se1_w2 = (const float*)d_in[7];
    const float* se1_b2 = (const float*)d_in[8];
    const float* sa1_w  = (const float*)d_in[9];
    const float* se2_w1 = (const float*)d_in[10];
    const float* se2_b1 = (const float*)d_in[11];
    const float* se2_w2 = (const float*)d_in[12];
    const float* se2_b2 = (const float*)d_in[13];
    const float* sa2_w  = (const float*)d_in[14];
    const float* cbk    = (const float*)d_in[15];
    const float* dt1_w  = (const float*)d_in[16];
    const float* dt1_b  = (const float*)d_in[17];
    const float* dt2_w  = (const float*)d_in[18];
    const float* dt2_b  = (const float*)d_in[19];
    const float* dse_w1 = (const float*)d_in[20];
    const float* dse_b1 = (const float*)d_in[21];
    const float* dse_w2 = (const float*)d_in[22];
    const float* dse_b2 = (const float*)d_in[23];
    const float* dsa_w  = (const float*)d_in[24];
    float* out = (float*)d_out;

    float* A      = (float*)d_ws;
    float* C      = A + T63;
    float* pooled = C + T62;
    float* g      = pooled + 8192;
    float* am     = g + 8192;
    float* ssmap  = am + (size_t)NB*2*HW1;
    float* cbn    = ssmap + (size_t)NB*HW1;
    unsigned short* apackE = (unsigned short*)(cbn + 512);
    unsigned short* apackD = apackE + 262144;
    unsigned short* cbp    = apackD + 262144;
    float* sse    = (float*)(cbp + 131072);
    int*   counts = (int*)(sse + 1);
    int*   idx    = counts + 512;

    // prep
    zero_small<<<1, 256, 0, stream>>>(sse, counts);
    prepack_w<<<1024, 256, 0, stream>>>(ec2_w, apackE, 0);
    prepack_w<<<1024, 256, 0, stream>>>(dt1_w, apackD, 1);
    cb_norm<<<1, 256, 0, stream>>>(cbk, cbn);
    cb_pack<<<512, 256, 0, stream>>>(cbk, cbp);

    // encoder conv1 + cbam1 (in-place on A)
    conv1_relu<<<dim3(NB*256, 16), 256, 0, stream>>>(x, ec1_w, ec1_b, A);
    gap_kernel<<<NB*256, 256, 0, stream>>>(A, pooled, HW1);
    se_mlp<<<NB, 256, 0, stream>>>(pooled, se1_w1, se1_b1, se1_w2, se1_b2, g);
    chanpool<<<dim3(16, NB), 256, 0, stream>>>(A, g, am, HW1);
    spatial_conv<<<dim3(16, NB), 256, 0, stream>>>(am, sa1_w, ssmap, 63, 63, 0);
    cbam_final<<<dim3(HW1, NB), 256, 0, stream>>>(A, g, ssmap, HW1);

    // conv2 (A -> C, MFMA co=256) + cbam2 (in-place on C)  => z in C
    convk2_mfma<<<dim3(64, NB), 256, 0, stream>>>(A, apackE, ec2_b, C, 63, 63, 62, 62, 0);
    gap_kernel<<<NB*256, 256, 0, stream>>>(C, pooled, HW2);
    se_mlp<<<NB, 256, 0, stream>>>(pooled, se2_w1, se2_b1, se2_w2, se2_b2, g);
    chanpool<<<dim3(16, NB), 256, 0, stream>>>(C, g, am, HW2);
    spatial_conv<<<dim3(16, NB), 256, 0, stream>>>(am, sa2_w, ssmap, 62, 62, 0);
    cbam_final<<<dim3(HW2, NB), 256, 0, stream>>>(C, g, ssmap, HW2);

    // VQ: z in C -> q in C (in-place)
    vq_assign_mfma<<<NROWS/64, 256, 0, stream>>>(C, cbp, cbn, idx);
    vq_gather<<<GATHER_BLOCKS, 256, 0, stream>>>(C, cbk, idx, sse, counts);
    vq_finalize<<<1, 256, 0, stream>>>(sse, counts, out);

    // decoder dt1 (C -> A, MFMA co=256) + cbam3 (in-place on A)
    convk2_mfma<<<dim3(64, NB), 256, 0, stream>>>(C, apackD, dt1_b, A, 62, 62, 63, 63, 1);
    gap_kernel<<<NB*256, 256, 0, stream>>>(A, pooled, HW1);
    se_mlp<<<NB, 256, 0, stream>>>(pooled, dse_w1, dse_b1, dse_w2, dse_b2, g);
    chanpool<<<dim3(16, NB), 256, 0, stream>>>(A, g, am, HW1);
    spatial_conv<<<dim3(16, NB), 256, 0, stream>>>(am, dsa_w, ssmap, 63, 63, 1);
    cbam_final<<<dim3(HW1, NB), 256, 0, stream>>>(A, g, ssmap, HW1);

    // final convT -> out
    dt2_kernel<<<dim3(192, NB), 256, 0, stream>>>(A, dt2_w, dt2_b, out);
}

// Round 8
// 1289.353 us; speedup vs baseline: 4.7251x; 1.1242x over previous
//
#include <hip/hip_runtime.h>
#include <math.h>

// ---------------- sizes ----------------
#define NB 32
#define HID 256
#define HW1 (63*63)      // 3969
#define HW2 (62*62)      // 3844
#define T63 ((size_t)NB*HID*HW1)   // 32,514,048
#define T62 ((size_t)NB*HID*HW2)   // 31,490,048
#define NROWS 123008               // T62 / 256
#define KCB 512
#define GATHER_BLOCKS 1024

typedef __attribute__((ext_vector_type(8))) short short8;
typedef __attribute__((ext_vector_type(4))) float f32x4;
typedef __attribute__((ext_vector_type(4))) unsigned short us4;

__device__ __forceinline__ unsigned short f2bf(float f) {
    union { float f; unsigned int u; } v; v.f = f;
    unsigned int u = v.u;
    return (unsigned short)((u + 0x7FFFu + ((u >> 16) & 1u)) >> 16);
}

// ---------------- zero small scratch (sse + counts) ----------------
__global__ __launch_bounds__(256) void zero_small(float* __restrict__ sse, int* __restrict__ counts) {
    if (threadIdx.x == 0) sse[0] = 0.f;
    for (int i = threadIdx.x; i < KCB; i += 256) counts[i] = 0;
}

// ---------------- conv1: 3->256, k4, s2, bias, relu ----------------
__global__ __launch_bounds__(256) void conv1_relu(
    const float* __restrict__ x, const float* __restrict__ w,
    const float* __restrict__ bias, float* __restrict__ out) {
    int b = blockIdx.x >> 8, co = blockIdx.x & 255;
    int ow = threadIdx.x & 63, oh = (blockIdx.y << 2) + (threadIdx.x >> 6);
    __shared__ float ws[48];
    if (threadIdx.x < 48) ws[threadIdx.x] = w[co*48 + threadIdx.x];
    __syncthreads();
    if (ow >= 63 || oh >= 63) return;
    float acc = bias[co];
    const float* xb = x + (size_t)b*3*128*128;
    int ih0 = oh*2, iw0 = ow*2;
    #pragma unroll
    for (int ci = 0; ci < 3; ++ci)
      #pragma unroll
      for (int kh = 0; kh < 4; ++kh) {
        const float* row = xb + ((size_t)ci*128 + ih0+kh)*128 + iw0;
        #pragma unroll
        for (int kw = 0; kw < 4; ++kw)
            acc = fmaf(row[kw], ws[ci*16+kh*4+kw], acc);
      }
    out[((size_t)(b*HID+co)*63 + oh)*63 + ow] = fmaxf(acc, 0.f);
}

// ---------------- global average pool over spatial ----------------
__global__ __launch_bounds__(256) void gap_kernel(
    const float* __restrict__ x, float* __restrict__ pooled, int HW) {
    int bc = blockIdx.x;
    const float* p = x + (size_t)bc*HW;
    float s = 0.f;
    for (int i = threadIdx.x; i < HW; i += 256) s += p[i];
    __shared__ float lds[4];
    for (int off = 32; off; off >>= 1) s += __shfl_down(s, off, 64);
    if ((threadIdx.x & 63) == 0) lds[threadIdx.x >> 6] = s;
    __syncthreads();
    if (threadIdx.x == 0) pooled[bc] = (lds[0]+lds[1]+lds[2]+lds[3]) / (float)HW;
}

// ---------------- SE MLP ----------------
__global__ __launch_bounds__(256) void se_mlp(
    const float* __restrict__ pooled, const float* __restrict__ w1,
    const float* __restrict__ b1, const float* __restrict__ w2,
    const float* __restrict__ b2, float* __restrict__ g) {
    int b = blockIdx.x;
    __shared__ float ps[256], hs[16];
    ps[threadIdx.x] = pooled[b*256 + threadIdx.x];
    __syncthreads();
    if (threadIdx.x < 16) {
        float a = b1[threadIdx.x];
        const float* wr = w1 + threadIdx.x*256;
        for (int k = 0; k < 256; ++k) a = fmaf(ps[k], wr[k], a);
        hs[threadIdx.x] = fmaxf(a, 0.f);
    }
    __syncthreads();
    float a = b2[threadIdx.x];
    const float* wr = w2 + threadIdx.x*16;
    #pragma unroll
    for (int j = 0; j < 16; ++j) a = fmaf(hs[j], wr[j], a);
    g[b*256 + threadIdx.x] = 1.f / (1.f + expf(-a));
}

// ---------------- channel mean/max of x*g ----------------
__global__ __launch_bounds__(256) void chanpool(
    const float* __restrict__ x, const float* __restrict__ g,
    float* __restrict__ am, int HW) {
    int b = blockIdx.y;
    int p = blockIdx.x*256 + threadIdx.x;
    if (p >= HW) return;
    const float* xb = x + (size_t)b*256*HW + p;
    const float* gb = g + b*256;
    float s = 0.f, mx = -3.0e38f;
    for (int c = 0; c < 256; ++c) {
        float v = xb[(size_t)c*HW] * gb[c];
        s += v; mx = fmaxf(mx, v);
    }
    am[((size_t)b*2)*HW + p]   = s * (1.f/256.f);
    am[((size_t)b*2+1)*HW + p] = mx;
}

// ---------------- 7x7 spatial conv on [mean,max], sigmoid ----------------
__global__ __launch_bounds__(256) void spatial_conv(
    const float* __restrict__ am, const float* __restrict__ sw,
    float* __restrict__ ss, int H, int W, int transpose) {
    int b = blockIdx.y;
    int p = blockIdx.x*256 + threadIdx.x;
    __shared__ float ws[98];
    if (threadIdx.x < 98) {
        int c = threadIdx.x / 49, k = threadIdx.x % 49;
        int kh = k / 7, kw = k % 7;
        ws[threadIdx.x] = transpose ? sw[c*49 + (6-kh)*7 + (6-kw)]
                                    : sw[c*49 + kh*7 + kw];
    }
    __syncthreads();
    if (p >= H*W) return;
    int oh = p / W, ow = p % W;
    float acc = 0.f;
    #pragma unroll
    for (int c = 0; c < 2; ++c) {
        const float* ab = am + ((size_t)b*2 + c)*H*W;
        for (int kh = 0; kh < 7; ++kh) {
            int ih = oh + kh - 3;
            if (ih < 0 || ih >= H) continue;
            for (int kw = 0; kw < 7; ++kw) {
                int iw = ow + kw - 3;
                if (iw < 0 || iw >= W) continue;
                acc = fmaf(ab[(size_t)ih*W + iw], ws[c*49 + kh*7 + kw], acc);
            }
        }
    }
    ss[(size_t)b*H*W + p] = 1.f / (1.f + expf(-acc));
}

// ---------------- IN-PLACE: x = x*x*g*sig(s) (used by cbam2, cbam3) ----------------
__global__ __launch_bounds__(256) void cbam_final(
    float* x, const float* __restrict__ g,
    const float* __restrict__ ss, int HW) {
    int b = blockIdx.y;
    size_t e = (size_t)blockIdx.x*256 + threadIdx.x;
    if (e >= (size_t)256*HW) return;
    int c = (int)(e / HW), p = (int)(e % HW);
    float* px = x + (size_t)b*256*HW + e;
    float xv = *px;
    *px = xv * xv * g[b*256+c] * ss[(size_t)b*HW + p];
}

// ---------------- NCHW fp32 -> NHWC bf16 register transpose ----------------
// applycbam=1: also applies x*x*g[c]*ss[p] (replaces cbam_final for cbam1).
// Thread owns one pixel p: reads 256 channels (coalesced along p within wave),
// packs bf16 pairs, writes 128B contiguous per 64-ch chunk.
__global__ __launch_bounds__(256) void to_nhwc_bf16(
    const float* __restrict__ in, const float* __restrict__ g,
    const float* __restrict__ ss, unsigned short* __restrict__ X,
    int HW, int applycbam) {
    int b = blockIdx.y;
    int p = blockIdx.x*256 + threadIdx.x;
    bool valid = p < HW;
    float sv = 0.f;
    if (applycbam && valid) sv = ss[(size_t)b*HW + p];
    const float* inb = in + (size_t)b*256*HW + p;
    const float* gb = g + b*256;
    unsigned short* dst = X + ((size_t)b*HW + p)*256;
    #pragma unroll
    for (int ch = 0; ch < 4; ++ch) {
        unsigned int pk[32];
        #pragma unroll
        for (int j = 0; j < 32; ++j) {
            int c0 = ch*64 + j*2;
            float v0 = valid ? inb[(size_t)c0*HW] : 0.f;
            float v1 = valid ? inb[(size_t)(c0+1)*HW] : 0.f;
            if (applycbam) {
                v0 = v0*v0*gb[c0]*sv;
                v1 = v1*v1*gb[c0+1]*sv;
            }
            pk[j] = (unsigned int)f2bf(v0) | ((unsigned int)f2bf(v1) << 16);
        }
        if (valid) {
            #pragma unroll
            for (int j2 = 0; j2 < 8; ++j2)
                *(short8*)(dst + ch*64 + j2*8) = *(const short8*)&pk[j2*4];
        }
    }
}

// ---------------- weight prepack into MFMA-fragment layout (bf16) ----------------
__global__ __launch_bounds__(256) void prepack_w(
    const float* __restrict__ w, unsigned short* __restrict__ pack, int transpose_flip) {
    int t = blockIdx.x*256 + threadIdx.x;
    int j = t & 7, koct = (t >> 3) & 3, co = (t >> 5) & 255, tap = (t >> 13) & 3, cc = t >> 15;
    int ci = cc*32 + koct*8 + j;
    int kh = tap >> 1, kw = tap & 1;
    float v;
    if (transpose_flip) v = w[((size_t)ci*256 + co)*4 + (1-kh)*2 + (1-kw)];
    else                v = w[((size_t)co*256 + ci)*4 + kh*2 + kw];
    pack[t] = f2bf(v);
}

// ---------------- MFMA conv k=2 s=1, NHWC bf16 input, 16x4 output tiles ----------------
// block: 256co x 64px (16w x 4h); 4 waves, each 64co (4 co-frags) x 64px (4 row-frags).
// Staging: 85-sp halo (5x17) per 32-ci chunk, coalesced 16B loads, double-buffered.
__global__ __launch_bounds__(256) void convk2_mfma_nhwc(
    const unsigned short* __restrict__ Xin, const unsigned short* __restrict__ apack,
    const float* __restrict__ bias, float* __restrict__ out,
    int inH, int inW, int outH, int outW, int pad) {
    __shared__ __align__(16) unsigned short Iraw[2][85*40];   // [buf][sp=5x17][ci=32]
    int b = blockIdx.y;
    int t = blockIdx.x;                       // 16 th x 4 tw = 64 tiles
    int oh0 = (t >> 2) * 4, ow0 = (t & 3) * 16;
    int w = threadIdx.x >> 6, l = threadIdx.x & 63;
    int lr = l & 15, lk = l >> 4;
    const unsigned short* src = Xin + (size_t)b*inH*inW*256;

    f32x4 acc[4][4];
    #pragma unroll
    for (int i = 0; i < 4; ++i)
        #pragma unroll
        for (int j = 0; j < 4; ++j) acc[i][j] = (f32x4){0.f,0.f,0.f,0.f};

    auto STAGE = [&](int cc, int bufi) {
        #pragma unroll
        for (int pass = 0; pass < 2; ++pass) {
            int u = pass*256 + threadIdx.x;
            if (u < 340) {                    // 85 sp x 4 quads of 16B
                int sp = u >> 2, q = u & 3;
                int r = (sp*241) >> 12, c = sp - r*17;
                int gh = oh0 + r - pad, gw = ow0 + c - pad;
                short8 v = (short8){0,0,0,0,0,0,0,0};
                if (gh >= 0 && gh < inH && gw >= 0 && gw < inW)
                    v = *(const short8*)(src + ((size_t)gh*inW + gw)*256 + cc*32 + q*8);
                *(short8*)&Iraw[bufi][sp*40 + q*8] = v;
            }
        }
    };

    STAGE(0, 0);
    for (int cc = 0; cc < 8; ++cc) {
        __syncthreads();
        if (cc < 7) STAGE(cc+1, (cc+1)&1);
        const unsigned short* Ib = Iraw[cc & 1];
        #pragma unroll
        for (int tap = 0; tap < 4; ++tap) {
            int kh = tap >> 1, kw = tap & 1;
            int spb = kh*17 + kw + lr;        // + pxf*17 per row-fragment
            short8 b0 = *(const short8*)&Ib[(spb     )*40 + lk*8];
            short8 b1 = *(const short8*)&Ib[(spb + 17)*40 + lk*8];
            short8 b2 = *(const short8*)&Ib[(spb + 34)*40 + lk*8];
            short8 b3 = *(const short8*)&Ib[(spb + 51)*40 + lk*8];
            const unsigned short* abase = apack + (((size_t)(cc*4 + tap)*256)*4 + (size_t)lk)*8;
            #pragma unroll
            for (int cof = 0; cof < 4; ++cof) {
                int co = w*64 + cof*16 + lr;
                short8 af = *(const short8*)(abase + (size_t)co*32);
                acc[cof][0] = __builtin_amdgcn_mfma_f32_16x16x32_bf16(af, b0, acc[cof][0], 0, 0, 0);
                acc[cof][1] = __builtin_amdgcn_mfma_f32_16x16x32_bf16(af, b1, acc[cof][1], 0, 0, 0);
                acc[cof][2] = __builtin_amdgcn_mfma_f32_16x16x32_bf16(af, b2, acc[cof][2], 0, 0, 0);
                acc[cof][3] = __builtin_amdgcn_mfma_f32_16x16x32_bf16(af, b3, acc[cof][3], 0, 0, 0);
            }
        }
    }
    int ow = ow0 + lr;
    #pragma unroll
    for (int cof = 0; cof < 4; ++cof) {
        int cob = w*64 + cof*16 + lk*4;
        float4 bz = *(const float4*)&bias[cob];
        #pragma unroll
        for (int pxf = 0; pxf < 4; ++pxf) {
            int oh = oh0 + pxf;
            if (oh < outH && ow < outW) {
                f32x4 a = acc[cof][pxf];
                size_t base = ((size_t)(b*256 + cob)*outH + oh)*outW + ow;
                size_t st = (size_t)outH*outW;
                out[base]        = fmaxf(a.x + bz.x, 0.f);
                out[base +   st] = fmaxf(a.y + bz.y, 0.f);
                out[base + 2*st] = fmaxf(a.z + bz.z, 0.f);
                out[base + 3*st] = fmaxf(a.w + bz.w, 0.f);
            }
        }
    }
}

// ---------------- codebook norms (fp32, exact) ----------------
__global__ __launch_bounds__(256) void cb_norm(
    const float* __restrict__ cb, float* __restrict__ cbn) {
    for (int n = threadIdx.x; n < KCB; n += 256) {
        float s = 0.f;
        for (int k = 0; k < 256; ++k) { float v = cb[(size_t)n*256+k]; s = fmaf(v,v,s); }
        cbn[n] = s;
    }
}

// ---------------- codebook bf16 pack [n][k] ----------------
__global__ __launch_bounds__(256) void cb_pack(
    const float* __restrict__ cb, unsigned short* __restrict__ cbp) {
    int t = blockIdx.x*256 + threadIdx.x;
    cbp[t] = f2bf(cb[t]);
}

// ---------------- MFMA VQ assign: LDS-staged codebook, 64 rows/block ----------------
__global__ __launch_bounds__(256) void vq_assign_mfma(
    const float* __restrict__ z, const unsigned short* __restrict__ cbp,
    const float* __restrict__ cbn, int* __restrict__ idx) {
    __shared__ __align__(16) unsigned short zb[64*264];
    __shared__ __align__(16) unsigned short cbs[2][32*264];
    __shared__ float cbl[KCB];
    int r0 = blockIdx.x * 64;
    for (int v = threadIdx.x; v < 4096; v += 256) {
        int row = v >> 6, col4 = v & 63;
        float4 u = *(const float4*)&z[(size_t)(r0+row)*256 + col4*4];
        us4 pk = { f2bf(u.x), f2bf(u.y), f2bf(u.z), f2bf(u.w) };
        *(us4*)&zb[row*264 + col4*4] = pk;
    }
    for (int i = threadIdx.x; i < KCB; i += 256) cbl[i] = cbn[i];
    int tcode = threadIdx.x >> 3, tk = threadIdx.x & 7;
    auto STAGE_CB = [&](int c, int bufi) {
        const unsigned short* src = cbp + ((size_t)(c*32 + tcode))*256 + tk*8;
        unsigned short* dst = &cbs[bufi][tcode*264 + tk*8];
        #pragma unroll
        for (int j = 0; j < 4; ++j)
            *(short8*)(dst + j*64) = *(const short8*)(src + j*64);
    };
    STAGE_CB(0, 0);
    __syncthreads();

    int w = threadIdx.x >> 6, l = threadIdx.x & 63;
    int lr = l & 15, lk = l >> 4;
    short8 afr[8];
    #pragma unroll
    for (int ks = 0; ks < 8; ++ks)
        afr[ks] = *(const short8*)&zb[(w*16 + lr)*264 + ks*32 + lk*8];

    float bd[4]; int bi[4];
    #pragma unroll
    for (int r = 0; r < 4; ++r) { bd[r] = 3.0e38f; bi[r] = 0; }

    for (int c = 0; c < 16; ++c) {
        if (c < 15) STAGE_CB(c+1, (c+1)&1);
        const unsigned short* Cb = cbs[c & 1];
        #pragma unroll
        for (int f = 0; f < 2; ++f) {
            f32x4 acc = (f32x4){0.f,0.f,0.f,0.f};
            #pragma unroll
            for (int ks = 0; ks < 8; ++ks) {
                short8 bfr = *(const short8*)&Cb[(f*16 + lr)*264 + ks*32 + lk*8];
                acc = __builtin_amdgcn_mfma_f32_16x16x32_bf16(afr[ks], bfr, acc, 0, 0, 0);
            }
            int n = c*32 + f*16 + lr;
            float cn = cbl[n];
            #pragma unroll
            for (int r = 0; r < 4; ++r) {
                float dist = fmaf(-2.f, acc[r], cn);
                if (dist < bd[r]) { bd[r] = dist; bi[r] = n; }
            }
        }
        __syncthreads();
    }
    #pragma unroll
    for (int r = 0; r < 4; ++r) {
        #pragma unroll
        for (int off = 1; off < 16; off <<= 1) {
            float od = __shfl_xor(bd[r], off, 64);
            int   oi = __shfl_xor(bi[r], off, 64);
            if (od < bd[r] || (od == bd[r] && oi < bi[r])) { bd[r] = od; bi[r] = oi; }
        }
    }
    if (lr == 0) {
        #pragma unroll
        for (int r = 0; r < 4; ++r)
            idx[r0 + w*16 + lk*4 + r] = bi[r];
    }
}

// ---------------- IN-PLACE VQ gather ----------------
__global__ __launch_bounds__(256) void vq_gather(
    float* zq, const float* __restrict__ cb,
    const int* __restrict__ idx, float* __restrict__ sse, int* __restrict__ counts) {
    __shared__ int hist[KCB];
    for (int i = threadIdx.x; i < KCB; i += 256) hist[i] = 0;
    __syncthreads();
    float local = 0.f;
    for (int r = blockIdx.x; r < NROWS; r += GATHER_BLOCKS) {
        int id = idx[r];
        if (threadIdx.x == 0) atomicAdd(&hist[id], 1);
        float qv = cb[(size_t)id*256 + threadIdx.x];
        float* pz = zq + (size_t)r*256 + threadIdx.x;
        float zv = *pz;
        *pz = qv;
        float d = qv - zv;
        local = fmaf(d, d, local);
    }
    __shared__ float lds[4];
    for (int off = 32; off; off >>= 1) local += __shfl_down(local, off, 64);
    if ((threadIdx.x & 63) == 0) lds[threadIdx.x >> 6] = local;
    __syncthreads();
    if (threadIdx.x == 0) atomicAdd(sse, lds[0]+lds[1]+lds[2]+lds[3]);
    for (int i = threadIdx.x; i < KCB; i += 256) {
        int h = hist[i];
        if (h) atomicAdd(counts + i, h);
    }
}

// ---------------- loss + perplexity ----------------
__global__ __launch_bounds__(256) void vq_finalize(
    const float* __restrict__ sse, const int* __restrict__ counts,
    float* __restrict__ out) {
    __shared__ float lds[4];
    float h = 0.f;
    for (int n = threadIdx.x; n < KCB; n += 256) {
        float p = (float)counts[n] * (1.f/123008.f);
        h += p * logf(p + 1e-10f);
    }
    for (int off = 32; off; off >>= 1) h += __shfl_down(h, off, 64);
    if ((threadIdx.x & 63) == 0) lds[threadIdx.x >> 6] = h;
    __syncthreads();
    if (threadIdx.x == 0) {
        out[1572864] = 1.25f * sse[0] / 31490048.f;
        out[1572865] = expf(-(lds[0]+lds[1]+lds[2]+lds[3]));
    }
}

// ---------------- dt2: convT 256->3, k4, s2 ----------------
__global__ __launch_bounds__(256) void dt2_kernel(
    const float* __restrict__ d, const float* __restrict__ w,
    const float* __restrict__ bias, float* __restrict__ out) {
    int b = blockIdx.y;
    int co = blockIdx.x / 64;
    int h = (blockIdx.x % 64)*2 + (threadIdx.x >> 7);
    int wpos = threadIdx.x & 127;
    __shared__ float ws[4096];
    for (int t = threadIdx.x; t < 4096; t += 256) {
        int ci = t >> 4, k = t & 15;
        ws[t] = w[(size_t)ci*48 + co*16 + k];
    }
    __syncthreads();
    int kh0 = h & 1, kw0 = wpos & 1;
    int ih0 = (h - kh0) >> 1, iw0 = (wpos - kw0) >> 1;
    bool vh0 = (ih0 < 63), vh1 = (ih0 >= 1);
    bool vw0 = (iw0 < 63), vw1 = (iw0 >= 1);
    float acc = bias[co];
    const float* db = d + (size_t)b*256*HW1;
    for (int ci = 0; ci < 256; ++ci) {
        const float* dc = db + (size_t)ci*HW1;
        const float* wc = ws + ci*16;
        float v00 = (vh0 && vw0) ? dc[ih0*63 + iw0]       : 0.f;
        float v01 = (vh0 && vw1) ? dc[ih0*63 + iw0 - 1]   : 0.f;
        float v10 = (vh1 && vw0) ? dc[(ih0-1)*63 + iw0]   : 0.f;
        float v11 = (vh1 && vw1) ? dc[(ih0-1)*63 + iw0-1] : 0.f;
        acc = fmaf(v00, wc[kh0*4 + kw0],         acc);
        acc = fmaf(v01, wc[kh0*4 + kw0 + 2],     acc);
        acc = fmaf(v10, wc[(kh0+2)*4 + kw0],     acc);
        acc = fmaf(v11, wc[(kh0+2)*4 + kw0 + 2], acc);
    }
    out[((size_t)(b*3+co)*128 + h)*128 + wpos] = acc;
}

// ---------------- launch ----------------
extern "C" void kernel_launch(void* const* d_in, const int* in_sizes, int n_in,
                              void* d_out, int out_size, void* d_ws, size_t ws_size,
                              hipStream_t stream) {
    const float* x      = (const float*)d_in[0];
    const float* ec1_w  = (const float*)d_in[1];
    const float* ec1_b  = (const float*)d_in[2];
    const float* ec2_w  = (const float*)d_in[3];
    const float* ec2_b  = (const float*)d_in[4];
    const float* se1_w1 = (const float*)d_in[5];
    const float* se1_b1 = (const float*)d_in[6];
    const float* se1_w2 = (const float*)d_in[7];
    const float* se1_b2 = (const float*)d_in[8];
    const float* sa1_w  = (const float*)d_in[9];
    const float* se2_w1 = (const float*)d_in[10];
    const float* se2_b1 = (const float*)d_in[11];
    const float* se2_w2 = (const float*)d_in[12];
    const float* se2_b2 = (const float*)d_in[13];
    const float* sa2_w  = (const float*)d_in[14];
    const float* cbk    = (const float*)d_in[15];
    const float* dt1_w  = (const float*)d_in[16];
    const float* dt1_b  = (const float*)d_in[17];
    const float* dt2_w  = (const float*)d_in[18];
    const float* dt2_b  = (const float*)d_in[19];
    const float* dse_w1 = (const float*)d_in[20];
    const float* dse_b1 = (const float*)d_in[21];
    const float* dse_w2 = (const float*)d_in[22];
    const float* dse_b2 = (const float*)d_in[23];
    const float* dsa_w  = (const float*)d_in[24];
    float* out = (float*)d_out;

    // Single big fp32 buffer (reused encoder->decoder) + one bf16 NHWC buffer.
    float* BIG    = (float*)d_ws;                           // T63 floats (130 MB)
    unsigned short* X = (unsigned short*)(BIG + T63);       // T63 ushorts (65 MB)
    float* pooled = (float*)(X + T63);
    float* g      = pooled + 8192;
    float* am     = g + 8192;
    float* ssmap  = am + (size_t)NB*2*HW1;
    float* cbn    = ssmap + (size_t)NB*HW1;
    unsigned short* apackE = (unsigned short*)(cbn + 512);
    unsigned short* apackD = apackE + 262144;
    unsigned short* cbp    = apackD + 262144;
    float* sse    = (float*)(cbp + 131072);
    int*   counts = (int*)(sse + 1);
    int*   idx    = counts + 512;

    // prep
    zero_small<<<1, 256, 0, stream>>>(sse, counts);
    prepack_w<<<1024, 256, 0, stream>>>(ec2_w, apackE, 0);
    prepack_w<<<1024, 256, 0, stream>>>(dt1_w, apackD, 1);
    cb_norm<<<1, 256, 0, stream>>>(cbk, cbn);
    cb_pack<<<512, 256, 0, stream>>>(cbk, cbp);

    // encoder conv1 -> BIG; cbam1 (final fused into NHWC transpose -> X)
    conv1_relu<<<dim3(NB*256, 16), 256, 0, stream>>>(x, ec1_w, ec1_b, BIG);
    gap_kernel<<<NB*256, 256, 0, stream>>>(BIG, pooled, HW1);
    se_mlp<<<NB, 256, 0, stream>>>(pooled, se1_w1, se1_b1, se1_w2, se1_b2, g);
    chanpool<<<dim3(16, NB), 256, 0, stream>>>(BIG, g, am, HW1);
    spatial_conv<<<dim3(16, NB), 256, 0, stream>>>(am, sa1_w, ssmap, 63, 63, 0);
    to_nhwc_bf16<<<dim3(16, NB), 256, 0, stream>>>(BIG, g, ssmap, X, HW1, 1);

    // conv2 (X -> BIG, NHWC MFMA) + cbam2 (in-place BIG) => z in BIG
    convk2_mfma_nhwc<<<dim3(64, NB), 256, 0, stream>>>(X, apackE, ec2_b, BIG, 63, 63, 62, 62, 0);
    gap_kernel<<<NB*256, 256, 0, stream>>>(BIG, pooled, HW2);
    se_mlp<<<NB, 256, 0, stream>>>(pooled, se2_w1, se2_b1, se2_w2, se2_b2, g);
    chanpool<<<dim3(16, NB), 256, 0, stream>>>(BIG, g, am, HW2);
    spatial_conv<<<dim3(16, NB), 256, 0, stream>>>(am, sa2_w, ssmap, 62, 62, 0);
    cbam_final<<<dim3(HW2, NB), 256, 0, stream>>>(BIG, g, ssmap, HW2);

    // VQ: z in BIG -> q in BIG (in-place), then q -> X (bf16 NHWC)
    vq_assign_mfma<<<NROWS/64, 256, 0, stream>>>(BIG, cbp, cbn, idx);
    vq_gather<<<GATHER_BLOCKS, 256, 0, stream>>>(BIG, cbk, idx, sse, counts);
    vq_finalize<<<1, 256, 0, stream>>>(sse, counts, out);
    to_nhwc_bf16<<<dim3(16, NB), 256, 0, stream>>>(BIG, g, ssmap, X, HW2, 0);

    // decoder dt1 (X -> BIG, NHWC MFMA) + cbam3 (in-place BIG)
    convk2_mfma_nhwc<<<dim3(64, NB), 256, 0, stream>>>(X, apackD, dt1_b, BIG, 62, 62, 63, 63, 1);
    gap_kernel<<<NB*256, 256, 0, stream>>>(BIG, pooled, HW1);
    se_mlp<<<NB, 256, 0, stream>>>(pooled, dse_w1, dse_b1, dse_w2, dse_b2, g);
    chanpool<<<dim3(16, NB), 256, 0, stream>>>(BIG, g, am, HW1);
    spatial_conv<<<dim3(16, NB), 256, 0, stream>>>(am, dsa_w, ssmap, 63, 63, 1);
    cbam_final<<<dim3(HW1, NB), 256, 0, stream>>>(BIG, g, ssmap, HW1);

    // final convT -> out
    dt2_kernel<<<dim3(192, NB), 256, 0, stream>>>(BIG, dt2_w, dt2_b, out);
}

// Round 9
// 1171.780 us; speedup vs baseline: 5.1993x; 1.1003x over previous
//
#include <hip/hip_runtime.h>
#include <math.h>

// ---------------- sizes ----------------
#define NB 32
#define HID 256
#define HW1 (63*63)      // 3969
#define HW2 (62*62)      // 3844
#define T63 ((size_t)NB*HID*HW1)   // 32,514,048
#define T62 ((size_t)NB*HID*HW2)   // 31,490,048
#define NROWS 123008               // T62 / 256
#define KCB 512
#define GATHER_BLOCKS 1024

typedef __attribute__((ext_vector_type(8))) short short8;
typedef __attribute__((ext_vector_type(4))) float f32x4;
typedef __attribute__((ext_vector_type(4))) unsigned short us4;

__device__ __forceinline__ unsigned short f2bf(float f) {
    union { float f; unsigned int u; } v; v.f = f;
    unsigned int u = v.u;
    return (unsigned short)((u + 0x7FFFu + ((u >> 16) & 1u)) >> 16);
}
__device__ __forceinline__ float bf2f(unsigned short u) {
    union { unsigned int i; float f; } v; v.i = ((unsigned int)u) << 16;
    return v.f;
}

// ---------------- zero helpers ----------------
__global__ __launch_bounds__(256) void zero_small(float* __restrict__ sse, int* __restrict__ counts) {
    if (threadIdx.x == 0) sse[0] = 0.f;
    for (int i = threadIdx.x; i < KCB; i += 256) counts[i] = 0;
}
__global__ __launch_bounds__(256) void zero_pooled(float* __restrict__ pooled) {
    pooled[blockIdx.x*256 + threadIdx.x] = 0.f;
}

// ---------------- conv1: 3->256, k4, s2, relu -> bf16 NHWC ----------------
__global__ __launch_bounds__(256) void conv1_nhwc(
    const float* __restrict__ x, const float* __restrict__ w,
    const float* __restrict__ bias, unsigned short* __restrict__ X0) {
    int b = blockIdx.y, s = blockIdx.x;
    int oh0 = s*4;
    int nrow = (oh0 + 4 <= 63) ? 4 : (63 - oh0);
    __shared__ float xs[3][10][128];
    const float* xb = x + (size_t)b*3*128*128;
    for (int i = threadIdx.x; i < 3840; i += 256) {
        int c = i / 1280, rem = i - c*1280, r = rem >> 7, col = rem & 127;
        int ih = oh0*2 + r;
        xs[c][r][col] = (ih < 128) ? xb[((size_t)c*128 + ih)*128 + col] : 0.f;
    }
    __syncthreads();
    int loh = threadIdx.x / 63, ow = threadIdx.x - loh*63;
    bool active = (threadIdx.x < 252) && (loh < nrow);
    float xr[48];
    #pragma unroll
    for (int k = 0; k < 48; ++k) xr[k] = 0.f;
    if (active) {
        #pragma unroll
        for (int c = 0; c < 3; ++c)
            #pragma unroll
            for (int kh = 0; kh < 4; ++kh) {
                float2 a = *(const float2*)&xs[c][loh*2+kh][2*ow];
                float2 d = *(const float2*)&xs[c][loh*2+kh][2*ow+2];
                xr[c*16+kh*4+0] = a.x; xr[c*16+kh*4+1] = a.y;
                xr[c*16+kh*4+2] = d.x; xr[c*16+kh*4+3] = d.y;
            }
    }
    size_t obase = ((size_t)b*HW1 + (size_t)(oh0+loh)*63 + ow)*256;
    for (int co0 = 0; co0 < 256; co0 += 8) {
        float acc[8];
        #pragma unroll
        for (int j = 0; j < 8; ++j) acc[j] = bias[co0+j];
        #pragma unroll
        for (int j = 0; j < 8; ++j) {
            const float* wr = w + (co0+j)*48;
            #pragma unroll
            for (int k = 0; k < 48; ++k) acc[j] = fmaf(xr[k], wr[k], acc[j]);
        }
        if (active) {
            unsigned int pk[4];
            #pragma unroll
            for (int j = 0; j < 4; ++j)
                pk[j] = (unsigned int)f2bf(fmaxf(acc[2*j], 0.f))
                      | ((unsigned int)f2bf(fmaxf(acc[2*j+1], 0.f)) << 16);
            *(short8*)(X0 + obase + co0) = *(const short8*)pk;
        }
    }
}

// ---------------- gap over NHWC bf16 (atomic accumulate; pooled pre-zeroed) ----------------
__global__ __launch_bounds__(256) void gap_nhwc(
    const unsigned short* __restrict__ X, float* __restrict__ pooled,
    int HW, float inv) {
    int b = blockIdx.y;
    int px0 = blockIdx.x * 512;
    int o = threadIdx.x & 31, pg = threadIdx.x >> 5;
    const unsigned short* xb = X + (size_t)b*HW*256 + o*8;
    float acc[8];
    #pragma unroll
    for (int j = 0; j < 8; ++j) acc[j] = 0.f;
    for (int i = 0; i < 64; ++i) {
        int px = px0 + pg + i*8;
        if (px < HW) {
            short8 v = *(const short8*)(xb + (size_t)px*256);
            #pragma unroll
            for (int j = 0; j < 8; ++j) acc[j] += bf2f((unsigned short)v[j]);
        }
    }
    __shared__ float pool2[8][256];
    #pragma unroll
    for (int j = 0; j < 8; ++j) pool2[pg][o*8+j] = acc[j];
    __syncthreads();
    float s = 0.f;
    #pragma unroll
    for (int p = 0; p < 8; ++p) s += pool2[p][threadIdx.x];
    atomicAdd(pooled + b*256 + threadIdx.x, s * inv);
}

// ---------------- gap NCHW (encoder-2) ----------------
__global__ __launch_bounds__(256) void gap_kernel(
    const float* __restrict__ x, float* __restrict__ pooled, int HW) {
    int bc = blockIdx.x;
    const float* p = x + (size_t)bc*HW;
    float s = 0.f;
    for (int i = threadIdx.x; i < HW; i += 256) s += p[i];
    __shared__ float lds[4];
    for (int off = 32; off; off >>= 1) s += __shfl_down(s, off, 64);
    if ((threadIdx.x & 63) == 0) lds[threadIdx.x >> 6] = s;
    __syncthreads();
    if (threadIdx.x == 0) pooled[bc] = (lds[0]+lds[1]+lds[2]+lds[3]) / (float)HW;
}

// ---------------- SE MLP ----------------
__global__ __launch_bounds__(256) void se_mlp(
    const float* __restrict__ pooled, const float* __restrict__ w1,
    const float* __restrict__ b1, const float* __restrict__ w2,
    const float* __restrict__ b2, float* __restrict__ g) {
    int b = blockIdx.x;
    __shared__ float ps[256], hs[16];
    ps[threadIdx.x] = pooled[b*256 + threadIdx.x];
    __syncthreads();
    if (threadIdx.x < 16) {
        float a = b1[threadIdx.x];
        const float* wr = w1 + threadIdx.x*256;
        for (int k = 0; k < 256; ++k) a = fmaf(ps[k], wr[k], a);
        hs[threadIdx.x] = fmaxf(a, 0.f);
    }
    __syncthreads();
    float a = b2[threadIdx.x];
    const float* wr = w2 + threadIdx.x*16;
    #pragma unroll
    for (int j = 0; j < 16; ++j) a = fmaf(hs[j], wr[j], a);
    g[b*256 + threadIdx.x] = 1.f / (1.f + expf(-a));
}

// ---------------- channel mean/max of x*g (NHWC bf16) ----------------
__global__ __launch_bounds__(256) void chanpool_nhwc(
    const unsigned short* __restrict__ X, const float* __restrict__ g,
    float* __restrict__ am, int HW) {
    int b = blockIdx.y;
    __shared__ float gs[256];
    gs[threadIdx.x] = g[b*256 + threadIdx.x];
    __syncthreads();
    int p = blockIdx.x*256 + threadIdx.x;
    if (p >= HW) return;
    const unsigned short* xp = X + ((size_t)b*HW + p)*256;
    float s = 0.f, mx = -3.0e38f;
    for (int o = 0; o < 32; ++o) {
        short8 v = *(const short8*)(xp + o*8);
        #pragma unroll
        for (int j = 0; j < 8; ++j) {
            float f = bf2f((unsigned short)v[j]) * gs[o*8+j];
            s += f; mx = fmaxf(mx, f);
        }
    }
    am[((size_t)b*2)*HW + p]   = s * (1.f/256.f);
    am[((size_t)b*2+1)*HW + p] = mx;
}

// ---------------- channel mean/max of x*g (NCHW fp32, encoder-2) ----------------
__global__ __launch_bounds__(256) void chanpool(
    const float* __restrict__ x, const float* __restrict__ g,
    float* __restrict__ am, int HW) {
    int b = blockIdx.y;
    int p = blockIdx.x*256 + threadIdx.x;
    if (p >= HW) return;
    const float* xb = x + (size_t)b*256*HW + p;
    const float* gb = g + b*256;
    float s = 0.f, mx = -3.0e38f;
    for (int c = 0; c < 256; ++c) {
        float v = xb[(size_t)c*HW] * gb[c];
        s += v; mx = fmaxf(mx, v);
    }
    am[((size_t)b*2)*HW + p]   = s * (1.f/256.f);
    am[((size_t)b*2+1)*HW + p] = mx;
}

// ---------------- 7x7 spatial conv on [mean,max], sigmoid ----------------
__global__ __launch_bounds__(256) void spatial_conv(
    const float* __restrict__ am, const float* __restrict__ sw,
    float* __restrict__ ss, int H, int W, int transpose) {
    int b = blockIdx.y;
    int p = blockIdx.x*256 + threadIdx.x;
    __shared__ float ws[98];
    if (threadIdx.x < 98) {
        int c = threadIdx.x / 49, k = threadIdx.x % 49;
        int kh = k / 7, kw = k % 7;
        ws[threadIdx.x] = transpose ? sw[c*49 + (6-kh)*7 + (6-kw)]
                                    : sw[c*49 + kh*7 + kw];
    }
    __syncthreads();
    if (p >= H*W) return;
    int oh = p / W, ow = p % W;
    float acc = 0.f;
    #pragma unroll
    for (int c = 0; c < 2; ++c) {
        const float* ab = am + ((size_t)b*2 + c)*H*W;
        for (int kh = 0; kh < 7; ++kh) {
            int ih = oh + kh - 3;
            if (ih < 0 || ih >= H) continue;
            for (int kw = 0; kw < 7; ++kw) {
                int iw = ow + kw - 3;
                if (iw < 0 || iw >= W) continue;
                acc = fmaf(ab[(size_t)ih*W + iw], ws[c*49 + kh*7 + kw], acc);
            }
        }
    }
    ss[(size_t)b*H*W + p] = 1.f / (1.f + expf(-acc));
}

// ---------------- IN-PLACE NHWC bf16: x = x*x*g*sig(s) ----------------
__global__ __launch_bounds__(256) void cbam_mul_nhwc(
    unsigned short* X, const float* __restrict__ g,
    const float* __restrict__ ss, int HW) {
    int b = blockIdx.y;
    __shared__ float gs[256];
    gs[threadIdx.x] = g[b*256 + threadIdx.x];
    __syncthreads();
    int p = blockIdx.x*256 + threadIdx.x;
    if (p >= HW) return;
    float sv = ss[(size_t)b*HW + p];
    unsigned short* xp = X + ((size_t)b*HW + p)*256;
    for (int o = 0; o < 32; ++o) {
        short8 v = *(const short8*)(xp + o*8);
        unsigned int pk[4];
        #pragma unroll
        for (int j = 0; j < 4; ++j) {
            float f0 = bf2f((unsigned short)v[2*j]);
            float f1 = bf2f((unsigned short)v[2*j+1]);
            f0 = f0*f0*gs[o*8+2*j]*sv;
            f1 = f1*f1*gs[o*8+2*j+1]*sv;
            pk[j] = (unsigned int)f2bf(f0) | ((unsigned int)f2bf(f1) << 16);
        }
        *(short8*)(xp + o*8) = *(const short8*)pk;
    }
}

// ---------------- IN-PLACE NCHW fp32: x = x*x*g*sig(s) (encoder-2) ----------------
__global__ __launch_bounds__(256) void cbam_final(
    float* x, const float* __restrict__ g,
    const float* __restrict__ ss, int HW) {
    int b = blockIdx.y;
    size_t e = (size_t)blockIdx.x*256 + threadIdx.x;
    if (e >= (size_t)256*HW) return;
    int c = (int)(e / HW), p = (int)(e % HW);
    float* px = x + (size_t)b*256*HW + e;
    float xv = *px;
    *px = xv * xv * g[b*256+c] * ss[(size_t)b*HW + p];
}

// ---------------- NCHW fp32 -> NHWC bf16 (q after VQ) ----------------
__global__ __launch_bounds__(256) void to_nhwc_bf16(
    const float* __restrict__ in, unsigned short* __restrict__ X, int HW) {
    int b = blockIdx.y;
    int p = blockIdx.x*256 + threadIdx.x;
    bool valid = p < HW;
    const float* inb = in + (size_t)b*256*HW + p;
    unsigned short* dst = X + ((size_t)b*HW + p)*256;
    #pragma unroll
    for (int ch = 0; ch < 4; ++ch) {
        unsigned int pk[32];
        #pragma unroll
        for (int j = 0; j < 32; ++j) {
            int c0 = ch*64 + j*2;
            float v0 = valid ? inb[(size_t)c0*HW] : 0.f;
            float v1 = valid ? inb[(size_t)(c0+1)*HW] : 0.f;
            pk[j] = (unsigned int)f2bf(v0) | ((unsigned int)f2bf(v1) << 16);
        }
        if (valid) {
            #pragma unroll
            for (int j2 = 0; j2 < 8; ++j2)
                *(short8*)(dst + ch*64 + j2*8) = *(const short8*)&pk[j2*4];
        }
    }
}

// ---------------- weight prepack into MFMA-fragment layout (bf16) ----------------
__global__ __launch_bounds__(256) void prepack_w(
    const float* __restrict__ w, unsigned short* __restrict__ pack, int transpose_flip) {
    int t = blockIdx.x*256 + threadIdx.x;
    int j = t & 7, koct = (t >> 3) & 3, co = (t >> 5) & 255, tap = (t >> 13) & 3, cc = t >> 15;
    int ci = cc*32 + koct*8 + j;
    int kh = tap >> 1, kw = tap & 1;
    float v;
    if (transpose_flip) v = w[((size_t)ci*256 + co)*4 + (1-kh)*2 + (1-kw)];
    else                v = w[((size_t)co*256 + ci)*4 + kh*2 + kw];
    pack[t] = f2bf(v);
}

// ---------------- dt2 weight prepack: Wd[p][j][ci][co] fp32 ----------------
__global__ __launch_bounds__(256) void prepack_dt2(
    const float* __restrict__ w, float* __restrict__ Wd) {
    int t = blockIdx.x*256 + threadIdx.x;
    if (t >= 12288) return;
    int co = t % 3, ci = (t/3) % 256, j = (t/768) % 4, p = t/3072;
    int kh0 = p >> 1, kw0 = p & 1;
    const int dj[4] = {0, 2, 8, 10};
    Wd[t] = w[(size_t)ci*48 + co*16 + kh0*4 + kw0 + dj[j]];
}

// ---------------- MFMA conv k=2 s=1, NHWC bf16 input; mode 0: fp32 NCHW out, 1: bf16 NHWC out ----------------
__global__ __launch_bounds__(256) void convk2_mfma_nhwc(
    const unsigned short* __restrict__ Xin, const unsigned short* __restrict__ apack,
    const float* __restrict__ bias, float* __restrict__ outF,
    unsigned short* __restrict__ outU,
    int inH, int inW, int outH, int outW, int pad, int mode) {
    __shared__ __align__(16) unsigned short Iraw[2][85*40];
    int b = blockIdx.y;
    int t = blockIdx.x;
    int oh0 = (t >> 2) * 4, ow0 = (t & 3) * 16;
    int w = threadIdx.x >> 6, l = threadIdx.x & 63;
    int lr = l & 15, lk = l >> 4;
    const unsigned short* src = Xin + (size_t)b*inH*inW*256;

    f32x4 acc[4][4];
    #pragma unroll
    for (int i = 0; i < 4; ++i)
        #pragma unroll
        for (int j = 0; j < 4; ++j) acc[i][j] = (f32x4){0.f,0.f,0.f,0.f};

    auto STAGE = [&](int cc, int bufi) {
        #pragma unroll
        for (int pass = 0; pass < 2; ++pass) {
            int u = pass*256 + threadIdx.x;
            if (u < 340) {
                int sp = u >> 2, q = u & 3;
                int r = (sp*241) >> 12, c = sp - r*17;
                int gh = oh0 + r - pad, gw = ow0 + c - pad;
                short8 v = (short8){0,0,0,0,0,0,0,0};
                if (gh >= 0 && gh < inH && gw >= 0 && gw < inW)
                    v = *(const short8*)(src + ((size_t)gh*inW + gw)*256 + cc*32 + q*8);
                *(short8*)&Iraw[bufi][sp*40 + q*8] = v;
            }
        }
    };

    STAGE(0, 0);
    for (int cc = 0; cc < 8; ++cc) {
        __syncthreads();
        if (cc < 7) STAGE(cc+1, (cc+1)&1);
        const unsigned short* Ib = Iraw[cc & 1];
        #pragma unroll
        for (int tap = 0; tap < 4; ++tap) {
            int kh = tap >> 1, kw = tap & 1;
            int spb = kh*17 + kw + lr;
            short8 b0 = *(const short8*)&Ib[(spb     )*40 + lk*8];
            short8 b1 = *(const short8*)&Ib[(spb + 17)*40 + lk*8];
            short8 b2 = *(const short8*)&Ib[(spb + 34)*40 + lk*8];
            short8 b3 = *(const short8*)&Ib[(spb + 51)*40 + lk*8];
            const unsigned short* abase = apack + (((size_t)(cc*4 + tap)*256)*4 + (size_t)lk)*8;
            #pragma unroll
            for (int cof = 0; cof < 4; ++cof) {
                int co = w*64 + cof*16 + lr;
                short8 af = *(const short8*)(abase + (size_t)co*32);
                acc[cof][0] = __builtin_amdgcn_mfma_f32_16x16x32_bf16(af, b0, acc[cof][0], 0, 0, 0);
                acc[cof][1] = __builtin_amdgcn_mfma_f32_16x16x32_bf16(af, b1, acc[cof][1], 0, 0, 0);
                acc[cof][2] = __builtin_amdgcn_mfma_f32_16x16x32_bf16(af, b2, acc[cof][2], 0, 0, 0);
                acc[cof][3] = __builtin_amdgcn_mfma_f32_16x16x32_bf16(af, b3, acc[cof][3], 0, 0, 0);
            }
        }
    }
    int ow = ow0 + lr;
    #pragma unroll
    for (int cof = 0; cof < 4; ++cof) {
        int cob = w*64 + cof*16 + lk*4;
        float4 bz = *(const float4*)&bias[cob];
        #pragma unroll
        for (int pxf = 0; pxf < 4; ++pxf) {
            int oh = oh0 + pxf;
            if (oh < outH && ow < outW) {
                f32x4 a = acc[cof][pxf];
                float r0 = fmaxf(a.x + bz.x, 0.f);
                float r1 = fmaxf(a.y + bz.y, 0.f);
                float r2 = fmaxf(a.z + bz.z, 0.f);
                float r3 = fmaxf(a.w + bz.w, 0.f);
                if (mode == 0) {
                    size_t base = ((size_t)(b*256 + cob)*outH + oh)*outW + ow;
                    size_t st = (size_t)outH*outW;
                    outF[base]        = r0;
                    outF[base +   st] = r1;
                    outF[base + 2*st] = r2;
                    outF[base + 3*st] = r3;
                } else {
                    us4 pk = { f2bf(r0), f2bf(r1), f2bf(r2), f2bf(r3) };
                    *(us4*)(outU + ((size_t)b*outH*outW + (size_t)oh*outW + ow)*256 + cob) = pk;
                }
            }
        }
    }
}

// ---------------- codebook norms ----------------
__global__ __launch_bounds__(256) void cb_norm(
    const float* __restrict__ cb, float* __restrict__ cbn) {
    for (int n = threadIdx.x; n < KCB; n += 256) {
        float s = 0.f;
        for (int k = 0; k < 256; ++k) { float v = cb[(size_t)n*256+k]; s = fmaf(v,v,s); }
        cbn[n] = s;
    }
}

// ---------------- codebook bf16 pack ----------------
__global__ __launch_bounds__(256) void cb_pack(
    const float* __restrict__ cb, unsigned short* __restrict__ cbp) {
    int t = blockIdx.x*256 + threadIdx.x;
    cbp[t] = f2bf(cb[t]);
}

// ---------------- MFMA VQ assign: LDS-staged codebook, 64 rows/block ----------------
__global__ __launch_bounds__(256) void vq_assign_mfma(
    const float* __restrict__ z, const unsigned short* __restrict__ cbp,
    const float* __restrict__ cbn, int* __restrict__ idx) {
    __shared__ __align__(16) unsigned short zb[64*264];
    __shared__ __align__(16) unsigned short cbs[2][32*264];
    __shared__ float cbl[KCB];
    int r0 = blockIdx.x * 64;
    for (int v = threadIdx.x; v < 4096; v += 256) {
        int row = v >> 6, col4 = v & 63;
        float4 u = *(const float4*)&z[(size_t)(r0+row)*256 + col4*4];
        us4 pk = { f2bf(u.x), f2bf(u.y), f2bf(u.z), f2bf(u.w) };
        *(us4*)&zb[row*264 + col4*4] = pk;
    }
    for (int i = threadIdx.x; i < KCB; i += 256) cbl[i] = cbn[i];
    int tcode = threadIdx.x >> 3, tk = threadIdx.x & 7;
    auto STAGE_CB = [&](int c, int bufi) {
        const unsigned short* src = cbp + ((size_t)(c*32 + tcode))*256 + tk*8;
        unsigned short* dst = &cbs[bufi][tcode*264 + tk*8];
        #pragma unroll
        for (int j = 0; j < 4; ++j)
            *(short8*)(dst + j*64) = *(const short8*)(src + j*64);
    };
    STAGE_CB(0, 0);
    __syncthreads();

    int w = threadIdx.x >> 6, l = threadIdx.x & 63;
    int lr = l & 15, lk = l >> 4;
    short8 afr[8];
    #pragma unroll
    for (int ks = 0; ks < 8; ++ks)
        afr[ks] = *(const short8*)&zb[(w*16 + lr)*264 + ks*32 + lk*8];

    float bd[4]; int bi[4];
    #pragma unroll
    for (int r = 0; r < 4; ++r) { bd[r] = 3.0e38f; bi[r] = 0; }

    for (int c = 0; c < 16; ++c) {
        if (c < 15) STAGE_CB(c+1, (c+1)&1);
        const unsigned short* Cb = cbs[c & 1];
        #pragma unroll
        for (int f = 0; f < 2; ++f) {
            f32x4 acc = (f32x4){0.f,0.f,0.f,0.f};
            #pragma unroll
            for (int ks = 0; ks < 8; ++ks) {
                short8 bfr = *(const short8*)&Cb[(f*16 + lr)*264 + ks*32 + lk*8];
                acc = __builtin_amdgcn_mfma_f32_16x16x32_bf16(afr[ks], bfr, acc, 0, 0, 0);
            }
            int n = c*32 + f*16 + lr;
            float cn = cbl[n];
            #pragma unroll
            for (int r = 0; r < 4; ++r) {
                float dist = fmaf(-2.f, acc[r], cn);
                if (dist < bd[r]) { bd[r] = dist; bi[r] = n; }
            }
        }
        __syncthreads();
    }
    #pragma unroll
    for (int r = 0; r < 4; ++r) {
        #pragma unroll
        for (int off = 1; off < 16; off <<= 1) {
            float od = __shfl_xor(bd[r], off, 64);
            int   oi = __shfl_xor(bi[r], off, 64);
            if (od < bd[r] || (od == bd[r] && oi < bi[r])) { bd[r] = od; bi[r] = oi; }
        }
    }
    if (lr == 0) {
        #pragma unroll
        for (int r = 0; r < 4; ++r)
            idx[r0 + w*16 + lk*4 + r] = bi[r];
    }
}

// ---------------- IN-PLACE VQ gather ----------------
__global__ __launch_bounds__(256) void vq_gather(
    float* zq, const float* __restrict__ cb,
    const int* __restrict__ idx, float* __restrict__ sse, int* __restrict__ counts) {
    __shared__ int hist[KCB];
    for (int i = threadIdx.x; i < KCB; i += 256) hist[i] = 0;
    __syncthreads();
    float local = 0.f;
    for (int r = blockIdx.x; r < NROWS; r += GATHER_BLOCKS) {
        int id = idx[r];
        if (threadIdx.x == 0) atomicAdd(&hist[id], 1);
        float qv = cb[(size_t)id*256 + threadIdx.x];
        float* pz = zq + (size_t)r*256 + threadIdx.x;
        float zv = *pz;
        *pz = qv;
        float d = qv - zv;
        local = fmaf(d, d, local);
    }
    __shared__ float lds[4];
    for (int off = 32; off; off >>= 1) local += __shfl_down(local, off, 64);
    if ((threadIdx.x & 63) == 0) lds[threadIdx.x >> 6] = local;
    __syncthreads();
    if (threadIdx.x == 0) atomicAdd(sse, lds[0]+lds[1]+lds[2]+lds[3]);
    for (int i = threadIdx.x; i < KCB; i += 256) {
        int h = hist[i];
        if (h) atomicAdd(counts + i, h);
    }
}

// ---------------- loss + perplexity ----------------
__global__ __launch_bounds__(256) void vq_finalize(
    const float* __restrict__ sse, const int* __restrict__ counts,
    float* __restrict__ out) {
    __shared__ float lds[4];
    float h = 0.f;
    for (int n = threadIdx.x; n < KCB; n += 256) {
        float p = (float)counts[n] * (1.f/123008.f);
        h += p * logf(p + 1e-10f);
    }
    for (int off = 32; off; off >>= 1) h += __shfl_down(h, off, 64);
    if ((threadIdx.x & 63) == 0) lds[threadIdx.x >> 6] = h;
    __syncthreads();
    if (threadIdx.x == 0) {
        out[1572864] = 1.25f * sse[0] / 31490048.f;
        out[1572865] = expf(-(lds[0]+lds[1]+lds[2]+lds[3]));
    }
}

// ---------------- dt2: convT 256->3, k4, s2, NHWC bf16 input, wave-uniform parity ----------------
__global__ __launch_bounds__(256) void dt2_nhwc(
    const unsigned short* __restrict__ Y, const float* __restrict__ Wd,
    const float* __restrict__ bias, float* __restrict__ out) {
    int b = blockIdx.y;
    int wid = threadIdx.x >> 6, l = threadIdx.x & 63;
    int h = blockIdx.x*2 + (wid >> 1);
    int wpos = l*2 + (wid & 1);
    int kh0 = h & 1, kw0 = wid & 1;
    int p = kh0*2 + kw0;
    int pbase = __builtin_amdgcn_readfirstlane(p * 3072);
    int ih0 = (h - kh0) >> 1, iw0 = (wpos - kw0) >> 1;
    bool vh0 = (ih0 < 63), vh1 = (ih0 >= 1);
    bool vw0 = (iw0 < 63), vw1 = (iw0 >= 1);
    const unsigned short* yb = Y + (size_t)b*HW1*256;
    const unsigned short* tp[4];
    bool tv[4];
    tp[0] = yb + ((size_t)(ih0*63 + iw0))*256;         tv[0] = vh0 && vw0;
    tp[1] = yb + ((size_t)(ih0*63 + iw0 - 1))*256;     tv[1] = vh0 && vw1;
    tp[2] = yb + ((size_t)((ih0-1)*63 + iw0))*256;     tv[2] = vh1 && vw0;
    tp[3] = yb + ((size_t)((ih0-1)*63 + iw0 - 1))*256; tv[3] = vh1 && vw1;
    float a0 = bias[0], a1 = bias[1], a2 = bias[2];
    #pragma unroll
    for (int j = 0; j < 4; ++j) {
        if (!tv[j]) continue;
        const unsigned short* src = tp[j];
        const float* wj = Wd + pbase + j*768;
        for (int c0 = 0; c0 < 256; c0 += 8) {
            short8 v = *(const short8*)(src + c0);
            const float* wc = wj + c0*3;
            #pragma unroll
            for (int q = 0; q < 8; ++q) {
                float f = bf2f((unsigned short)v[q]);
                a0 = fmaf(f, wc[q*3+0], a0);
                a1 = fmaf(f, wc[q*3+1], a1);
                a2 = fmaf(f, wc[q*3+2], a2);
            }
        }
    }
    size_t ob = ((size_t)(b*3)*128 + h)*128 + wpos;
    out[ob]         = a0;
    out[ob + 16384] = a1;
    out[ob + 32768] = a2;
}

// ---------------- launch ----------------
extern "C" void kernel_launch(void* const* d_in, const int* in_sizes, int n_in,
                              void* d_out, int out_size, void* d_ws, size_t ws_size,
                              hipStream_t stream) {
    const float* x      = (const float*)d_in[0];
    const float* ec1_w  = (const float*)d_in[1];
    const float* ec1_b  = (const float*)d_in[2];
    const float* ec2_w  = (const float*)d_in[3];
    const float* ec2_b  = (const float*)d_in[4];
    const float* se1_w1 = (const float*)d_in[5];
    const float* se1_b1 = (const float*)d_in[6];
    const float* se1_w2 = (const float*)d_in[7];
    const float* se1_b2 = (const float*)d_in[8];
    const float* sa1_w  = (const float*)d_in[9];
    const float* se2_w1 = (const float*)d_in[10];
    const float* se2_b1 = (const float*)d_in[11];
    const float* se2_w2 = (const float*)d_in[12];
    const float* se2_b2 = (const float*)d_in[13];
    const float* sa2_w  = (const float*)d_in[14];
    const float* cbk    = (const float*)d_in[15];
    const float* dt1_w  = (const float*)d_in[16];
    const float* dt1_b  = (const float*)d_in[17];
    const float* dt2_w  = (const float*)d_in[18];
    const float* dt2_b  = (const float*)d_in[19];
    const float* dse_w1 = (const float*)d_in[20];
    const float* dse_b1 = (const float*)d_in[21];
    const float* dse_w2 = (const float*)d_in[22];
    const float* dse_b2 = (const float*)d_in[23];
    const float* dsa_w  = (const float*)d_in[24];
    float* out = (float*)d_out;

    float* BIG         = (float*)d_ws;                    // T63 fp32 (130 MB)
    unsigned short* U0 = (unsigned short*)(BIG + T63);    // T63 bf16 (65 MB)
    unsigned short* U1 = U0 + T63;                         // T63 bf16 (65 MB)
    float* pooled = (float*)(U1 + T63);
    float* g      = pooled + 8192;
    float* am     = g + 8192;
    float* ssmap  = am + (size_t)NB*2*HW1;
    float* cbn    = ssmap + (size_t)NB*HW1;
    unsigned short* apackE = (unsigned short*)(cbn + 512);
    unsigned short* apackD = apackE + 262144;
    unsigned short* cbp    = apackD + 262144;
    float* Wd     = (float*)(cbp + 131072);
    float* sse    = Wd + 12288;
    int*   counts = (int*)(sse + 1);
    int*   idx    = counts + 512;

    // prep
    zero_small<<<1, 256, 0, stream>>>(sse, counts);
    prepack_w<<<1024, 256, 0, stream>>>(ec2_w, apackE, 0);
    prepack_w<<<1024, 256, 0, stream>>>(dt1_w, apackD, 1);
    prepack_dt2<<<48, 256, 0, stream>>>(dt2_w, Wd);
    cb_norm<<<1, 256, 0, stream>>>(cbk, cbn);
    cb_pack<<<512, 256, 0, stream>>>(cbk, cbp);

    // encoder conv1 -> U0 bf16 NHWC; cbam1 on NHWC
    conv1_nhwc<<<dim3(16, NB), 256, 0, stream>>>(x, ec1_w, ec1_b, U0);
    zero_pooled<<<32, 256, 0, stream>>>(pooled);
    gap_nhwc<<<dim3(8, NB), 256, 0, stream>>>(U0, pooled, HW1, 1.f/HW1);
    se_mlp<<<NB, 256, 0, stream>>>(pooled, se1_w1, se1_b1, se1_w2, se1_b2, g);
    chanpool_nhwc<<<dim3(16, NB), 256, 0, stream>>>(U0, g, am, HW1);
    spatial_conv<<<dim3(16, NB), 256, 0, stream>>>(am, sa1_w, ssmap, 63, 63, 0);
    cbam_mul_nhwc<<<dim3(16, NB), 256, 0, stream>>>(U0, g, ssmap, HW1);

    // conv2 (U0 -> BIG fp32 NCHW) + cbam2 NCHW => z in BIG (VQ flat semantics need NCHW)
    convk2_mfma_nhwc<<<dim3(64, NB), 256, 0, stream>>>(U0, apackE, ec2_b, BIG, (unsigned short*)0, 63, 63, 62, 62, 0, 0);
    gap_kernel<<<NB*256, 256, 0, stream>>>(BIG, pooled, HW2);
    se_mlp<<<NB, 256, 0, stream>>>(pooled, se2_w1, se2_b1, se2_w2, se2_b2, g);
    chanpool<<<dim3(16, NB), 256, 0, stream>>>(BIG, g, am, HW2);
    spatial_conv<<<dim3(16, NB), 256, 0, stream>>>(am, sa2_w, ssmap, 62, 62, 0);
    cbam_final<<<dim3(HW2, NB), 256, 0, stream>>>(BIG, g, ssmap, HW2);

    // VQ: z in BIG -> q in BIG (in-place), then q -> U1 bf16 NHWC
    vq_assign_mfma<<<NROWS/64, 256, 0, stream>>>(BIG, cbp, cbn, idx);
    vq_gather<<<GATHER_BLOCKS, 256, 0, stream>>>(BIG, cbk, idx, sse, counts);
    vq_finalize<<<1, 256, 0, stream>>>(sse, counts, out);
    to_nhwc_bf16<<<dim3(16, NB), 256, 0, stream>>>(BIG, U1, HW2);

    // decoder dt1 (U1 -> U0 bf16 NHWC) + cbam3 on NHWC
    convk2_mfma_nhwc<<<dim3(64, NB), 256, 0, stream>>>(U1, apackD, dt1_b, (float*)0, U0, 62, 62, 63, 63, 1, 1);
    zero_pooled<<<32, 256, 0, stream>>>(pooled);
    gap_nhwc<<<dim3(8, NB), 256, 0, stream>>>(U0, pooled, HW1, 1.f/HW1);
    se_mlp<<<NB, 256, 0, stream>>>(pooled, dse_w1, dse_b1, dse_w2, dse_b2, g);
    chanpool_nhwc<<<dim3(16, NB), 256, 0, stream>>>(U0, g, am, HW1);
    spatial_conv<<<dim3(16, NB), 256, 0, stream>>>(am, dsa_w, ssmap, 63, 63, 1);
    cbam_mul_nhwc<<<dim3(16, NB), 256, 0, stream>>>(U0, g, ssmap, HW1);

    // final convT -> out
    dt2_nhwc<<<dim3(64, NB), 256, 0, stream>>>(U0, Wd, dt2_b, out);
}

// Round 10
// 1025.564 us; speedup vs baseline: 5.9405x; 1.1426x over previous
//
#include <hip/hip_runtime.h>
#include <math.h>

// ---------------- sizes ----------------
#define NB 32
#define HID 256
#define HW1 (63*63)      // 3969
#define HW2 (62*62)      // 3844
#define T63 ((size_t)NB*HID*HW1)   // 32,514,048
#define T62 ((size_t)NB*HID*HW2)   // 31,490,048
#define NROWS 123008               // T62 / 256
#define KCB 512
#define GATHER_BLOCKS 1024

typedef __attribute__((ext_vector_type(8))) short short8;
typedef __attribute__((ext_vector_type(4))) float f32x4;
typedef __attribute__((ext_vector_type(4))) unsigned short us4;

__device__ __forceinline__ unsigned short f2bf(float f) {
    union { float f; unsigned int u; } v; v.f = f;
    unsigned int u = v.u;
    return (unsigned short)((u + 0x7FFFu + ((u >> 16) & 1u)) >> 16);
}
__device__ __forceinline__ float bf2f(unsigned short u) {
    union { unsigned int i; float f; } v; v.i = ((unsigned int)u) << 16;
    return v.f;
}

// ---------------- zero helpers ----------------
__global__ __launch_bounds__(256) void zero_small(float* __restrict__ sse, int* __restrict__ counts) {
    if (threadIdx.x == 0) sse[0] = 0.f;
    for (int i = threadIdx.x; i < KCB; i += 256) counts[i] = 0;
}
__global__ __launch_bounds__(256) void zero_pooled(float* __restrict__ pooled) {
    pooled[blockIdx.x*256 + threadIdx.x] = 0.f;
}

// ---------------- conv1 weight prepack: [kc][co][lk][8] bf16, K=48 padded to 64 ----------------
__global__ __launch_bounds__(256) void prepack_c1(
    const float* __restrict__ w, unsigned short* __restrict__ pack) {
    int t = blockIdx.x*256 + threadIdx.x;   // 64 blocks -> 16384
    if (t >= 16384) return;
    int j = t & 7, lk = (t >> 3) & 3, co = (t >> 5) & 255, kc = t >> 13;
    int k = kc*32 + lk*8 + j;               // k = ci*16 + kh*4 + kw
    pack[t] = (k < 48) ? f2bf(w[co*48 + k]) : (unsigned short)0;
}

// ---------------- conv1: 3->256, k4, s2, relu -> bf16 NHWC via im2col MFMA ----------------
// block: 8x8 px tile x 256 co; 4 waves, each 64co x 64px; K = 64 (48 real + pad).
__global__ __launch_bounds__(256) void conv1_mfma(
    const float* __restrict__ x, const unsigned short* __restrict__ apack,
    const float* __restrict__ bias, unsigned short* __restrict__ X0) {
    __shared__ float xs[3][18][18];
    __shared__ __align__(16) unsigned short Bm[64*72];   // [px][k], stride 72 (16B-aligned rows)
    int b = blockIdx.y, t = blockIdx.x;
    int oh0 = (t >> 3)*8, ow0 = (t & 7)*8;
    int ih0 = oh0*2, iw0 = ow0*2;
    const float* xb = x + (size_t)b*3*128*128;
    // stage raw 3x18x18 input window
    for (int i = threadIdx.x; i < 972; i += 256) {
        int c = i / 324, rem = i - c*324, r = rem / 18, cl = rem - r*18;
        int ih = ih0 + r, iw = iw0 + cl;
        xs[c][r][cl] = (ih < 128 && iw < 128) ? xb[((size_t)c*128 + ih)*128 + iw] : 0.f;
    }
    __syncthreads();
    // build im2col Bm[px][64k] bf16 (k>=48 zero), u32-paired writes
    for (int i = threadIdx.x; i < 2048; i += 256) {
        int px = i >> 5, kp = (i & 31)*2;
        int ph = px >> 3, pw = px & 7;
        unsigned int pk = 0;
        #pragma unroll
        for (int u = 0; u < 2; ++u) {
            int k = kp + u;
            float v = 0.f;
            if (k < 48) {
                int c = k >> 4, k2 = k & 15, kh = k2 >> 2, kw = k2 & 3;
                v = xs[c][ph*2+kh][pw*2+kw];
            }
            pk |= ((unsigned int)f2bf(v)) << (16*u);
        }
        *(unsigned int*)&Bm[px*72 + kp] = pk;
    }
    __syncthreads();

    int w = threadIdx.x >> 6, l = threadIdx.x & 63;
    int lr = l & 15, lk = l >> 4;
    f32x4 acc[4][4];
    #pragma unroll
    for (int i = 0; i < 4; ++i)
        #pragma unroll
        for (int j = 0; j < 4; ++j) acc[i][j] = (f32x4){0.f,0.f,0.f,0.f};

    #pragma unroll
    for (int kc = 0; kc < 2; ++kc) {
        short8 bf[4];
        #pragma unroll
        for (int pxf = 0; pxf < 4; ++pxf)
            bf[pxf] = *(const short8*)&Bm[(pxf*16+lr)*72 + kc*32 + lk*8];
        #pragma unroll
        for (int cof = 0; cof < 4; ++cof) {
            int co = w*64 + cof*16 + lr;
            short8 af = *(const short8*)(apack + (((size_t)kc*256 + co)*4 + (size_t)lk)*8);
            acc[cof][0] = __builtin_amdgcn_mfma_f32_16x16x32_bf16(af, bf[0], acc[cof][0], 0, 0, 0);
            acc[cof][1] = __builtin_amdgcn_mfma_f32_16x16x32_bf16(af, bf[1], acc[cof][1], 0, 0, 0);
            acc[cof][2] = __builtin_amdgcn_mfma_f32_16x16x32_bf16(af, bf[2], acc[cof][2], 0, 0, 0);
            acc[cof][3] = __builtin_amdgcn_mfma_f32_16x16x32_bf16(af, bf[3], acc[cof][3], 0, 0, 0);
        }
    }
    #pragma unroll
    for (int cof = 0; cof < 4; ++cof) {
        int cob = w*64 + cof*16 + lk*4;
        float4 bz = *(const float4*)&bias[cob];
        #pragma unroll
        for (int pxf = 0; pxf < 4; ++pxf) {
            int px = pxf*16 + lr;
            int oh = oh0 + (px >> 3), ow = ow0 + (px & 7);
            if (oh < 63 && ow < 63) {
                f32x4 a = acc[cof][pxf];
                us4 pk = { f2bf(fmaxf(a.x + bz.x, 0.f)), f2bf(fmaxf(a.y + bz.y, 0.f)),
                           f2bf(fmaxf(a.z + bz.z, 0.f)), f2bf(fmaxf(a.w + bz.w, 0.f)) };
                *(us4*)(X0 + ((size_t)b*HW1 + (size_t)oh*63 + ow)*256 + cob) = pk;
            }
        }
    }
}

// ---------------- gap over NHWC bf16 (atomic accumulate; pooled pre-zeroed) ----------------
__global__ __launch_bounds__(256) void gap_nhwc(
    const unsigned short* __restrict__ X, float* __restrict__ pooled,
    int HW, float inv) {
    int b = blockIdx.y;
    int px0 = blockIdx.x * 512;
    int o = threadIdx.x & 31, pg = threadIdx.x >> 5;
    const unsigned short* xb = X + (size_t)b*HW*256 + o*8;
    float acc[8];
    #pragma unroll
    for (int j = 0; j < 8; ++j) acc[j] = 0.f;
    for (int i = 0; i < 64; ++i) {
        int px = px0 + pg + i*8;
        if (px < HW) {
            short8 v = *(const short8*)(xb + (size_t)px*256);
            #pragma unroll
            for (int j = 0; j < 8; ++j) acc[j] += bf2f((unsigned short)v[j]);
        }
    }
    __shared__ float pool2[8][256];
    #pragma unroll
    for (int j = 0; j < 8; ++j) pool2[pg][o*8+j] = acc[j];
    __syncthreads();
    float s = 0.f;
    #pragma unroll
    for (int p = 0; p < 8; ++p) s += pool2[p][threadIdx.x];
    atomicAdd(pooled + b*256 + threadIdx.x, s * inv);
}

// ---------------- gap NCHW (encoder-2) ----------------
__global__ __launch_bounds__(256) void gap_kernel(
    const float* __restrict__ x, float* __restrict__ pooled, int HW) {
    int bc = blockIdx.x;
    const float* p = x + (size_t)bc*HW;
    float s = 0.f;
    for (int i = threadIdx.x; i < HW; i += 256) s += p[i];
    __shared__ float lds[4];
    for (int off = 32; off; off >>= 1) s += __shfl_down(s, off, 64);
    if ((threadIdx.x & 63) == 0) lds[threadIdx.x >> 6] = s;
    __syncthreads();
    if (threadIdx.x == 0) pooled[bc] = (lds[0]+lds[1]+lds[2]+lds[3]) / (float)HW;
}

// ---------------- SE MLP ----------------
__global__ __launch_bounds__(256) void se_mlp(
    const float* __restrict__ pooled, const float* __restrict__ w1,
    const float* __restrict__ b1, const float* __restrict__ w2,
    const float* __restrict__ b2, float* __restrict__ g) {
    int b = blockIdx.x;
    __shared__ float ps[256], hs[16];
    ps[threadIdx.x] = pooled[b*256 + threadIdx.x];
    __syncthreads();
    if (threadIdx.x < 16) {
        float a = b1[threadIdx.x];
        const float* wr = w1 + threadIdx.x*256;
        for (int k = 0; k < 256; ++k) a = fmaf(ps[k], wr[k], a);
        hs[threadIdx.x] = fmaxf(a, 0.f);
    }
    __syncthreads();
    float a = b2[threadIdx.x];
    const float* wr = w2 + threadIdx.x*16;
    #pragma unroll
    for (int j = 0; j < 16; ++j) a = fmaf(hs[j], wr[j], a);
    g[b*256 + threadIdx.x] = 1.f / (1.f + expf(-a));
}

// ---------------- channel mean/max of x*g (NHWC bf16) ----------------
__global__ __launch_bounds__(256) void chanpool_nhwc(
    const unsigned short* __restrict__ X, const float* __restrict__ g,
    float* __restrict__ am, int HW) {
    int b = blockIdx.y;
    __shared__ float gs[256];
    gs[threadIdx.x] = g[b*256 + threadIdx.x];
    __syncthreads();
    int p = blockIdx.x*256 + threadIdx.x;
    if (p >= HW) return;
    const unsigned short* xp = X + ((size_t)b*HW + p)*256;
    float s = 0.f, mx = -3.0e38f;
    for (int o = 0; o < 32; ++o) {
        short8 v = *(const short8*)(xp + o*8);
        #pragma unroll
        for (int j = 0; j < 8; ++j) {
            float f = bf2f((unsigned short)v[j]) * gs[o*8+j];
            s += f; mx = fmaxf(mx, f);
        }
    }
    am[((size_t)b*2)*HW + p]   = s * (1.f/256.f);
    am[((size_t)b*2+1)*HW + p] = mx;
}

// ---------------- channel mean/max of x*g (NCHW fp32, encoder-2) ----------------
__global__ __launch_bounds__(256) void chanpool(
    const float* __restrict__ x, const float* __restrict__ g,
    float* __restrict__ am, int HW) {
    int b = blockIdx.y;
    int p = blockIdx.x*256 + threadIdx.x;
    if (p >= HW) return;
    const float* xb = x + (size_t)b*256*HW + p;
    const float* gb = g + b*256;
    float s = 0.f, mx = -3.0e38f;
    for (int c = 0; c < 256; ++c) {
        float v = xb[(size_t)c*HW] * gb[c];
        s += v; mx = fmaxf(mx, v);
    }
    am[((size_t)b*2)*HW + p]   = s * (1.f/256.f);
    am[((size_t)b*2+1)*HW + p] = mx;
}

// ---------------- 7x7 spatial conv on [mean,max], sigmoid ----------------
__global__ __launch_bounds__(256) void spatial_conv(
    const float* __restrict__ am, const float* __restrict__ sw,
    float* __restrict__ ss, int H, int W, int transpose) {
    int b = blockIdx.y;
    int p = blockIdx.x*256 + threadIdx.x;
    __shared__ float ws[98];
    if (threadIdx.x < 98) {
        int c = threadIdx.x / 49, k = threadIdx.x % 49;
        int kh = k / 7, kw = k % 7;
        ws[threadIdx.x] = transpose ? sw[c*49 + (6-kh)*7 + (6-kw)]
                                    : sw[c*49 + kh*7 + kw];
    }
    __syncthreads();
    if (p >= H*W) return;
    int oh = p / W, ow = p % W;
    float acc = 0.f;
    #pragma unroll
    for (int c = 0; c < 2; ++c) {
        const float* ab = am + ((size_t)b*2 + c)*H*W;
        for (int kh = 0; kh < 7; ++kh) {
            int ih = oh + kh - 3;
            if (ih < 0 || ih >= H) continue;
            for (int kw = 0; kw < 7; ++kw) {
                int iw = ow + kw - 3;
                if (iw < 0 || iw >= W) continue;
                acc = fmaf(ab[(size_t)ih*W + iw], ws[c*49 + kh*7 + kw], acc);
            }
        }
    }
    ss[(size_t)b*H*W + p] = 1.f / (1.f + expf(-acc));
}

// ---------------- IN-PLACE NHWC bf16: x = x*x*g*sig(s) ----------------
__global__ __launch_bounds__(256) void cbam_mul_nhwc(
    unsigned short* X, const float* __restrict__ g,
    const float* __restrict__ ss, int HW) {
    int b = blockIdx.y;
    __shared__ float gs[256];
    gs[threadIdx.x] = g[b*256 + threadIdx.x];
    __syncthreads();
    int p = blockIdx.x*256 + threadIdx.x;
    if (p >= HW) return;
    float sv = ss[(size_t)b*HW + p];
    unsigned short* xp = X + ((size_t)b*HW + p)*256;
    for (int o = 0; o < 32; ++o) {
        short8 v = *(const short8*)(xp + o*8);
        unsigned int pk[4];
        #pragma unroll
        for (int j = 0; j < 4; ++j) {
            float f0 = bf2f((unsigned short)v[2*j]);
            float f1 = bf2f((unsigned short)v[2*j+1]);
            f0 = f0*f0*gs[o*8+2*j]*sv;
            f1 = f1*f1*gs[o*8+2*j+1]*sv;
            pk[j] = (unsigned int)f2bf(f0) | ((unsigned int)f2bf(f1) << 16);
        }
        *(short8*)(xp + o*8) = *(const short8*)pk;
    }
}

// ---------------- IN-PLACE NCHW fp32: x = x*x*g*sig(s) (encoder-2) ----------------
__global__ __launch_bounds__(256) void cbam_final(
    float* x, const float* __restrict__ g,
    const float* __restrict__ ss, int HW) {
    int b = blockIdx.y;
    size_t e = (size_t)blockIdx.x*256 + threadIdx.x;
    if (e >= (size_t)256*HW) return;
    int c = (int)(e / HW), p = (int)(e % HW);
    float* px = x + (size_t)b*256*HW + e;
    float xv = *px;
    *px = xv * xv * g[b*256+c] * ss[(size_t)b*HW + p];
}

// ---------------- NCHW fp32 -> NHWC bf16 (q after VQ) ----------------
__global__ __launch_bounds__(256) void to_nhwc_bf16(
    const float* __restrict__ in, unsigned short* __restrict__ X, int HW) {
    int b = blockIdx.y;
    int p = blockIdx.x*256 + threadIdx.x;
    bool valid = p < HW;
    const float* inb = in + (size_t)b*256*HW + p;
    unsigned short* dst = X + ((size_t)b*HW + p)*256;
    #pragma unroll
    for (int ch = 0; ch < 4; ++ch) {
        unsigned int pk[32];
        #pragma unroll
        for (int j = 0; j < 32; ++j) {
            int c0 = ch*64 + j*2;
            float v0 = valid ? inb[(size_t)c0*HW] : 0.f;
            float v1 = valid ? inb[(size_t)(c0+1)*HW] : 0.f;
            pk[j] = (unsigned int)f2bf(v0) | ((unsigned int)f2bf(v1) << 16);
        }
        if (valid) {
            #pragma unroll
            for (int j2 = 0; j2 < 8; ++j2)
                *(short8*)(dst + ch*64 + j2*8) = *(const short8*)&pk[j2*4];
        }
    }
}

// ---------------- weight prepack into MFMA-fragment layout (bf16) ----------------
__global__ __launch_bounds__(256) void prepack_w(
    const float* __restrict__ w, unsigned short* __restrict__ pack, int transpose_flip) {
    int t = blockIdx.x*256 + threadIdx.x;
    int j = t & 7, koct = (t >> 3) & 3, co = (t >> 5) & 255, tap = (t >> 13) & 3, cc = t >> 15;
    int ci = cc*32 + koct*8 + j;
    int kh = tap >> 1, kw = tap & 1;
    float v;
    if (transpose_flip) v = w[((size_t)ci*256 + co)*4 + (1-kh)*2 + (1-kw)];
    else                v = w[((size_t)co*256 + ci)*4 + kh*2 + kw];
    pack[t] = f2bf(v);
}

// ---------------- dt2 weight prepack: Wd[p][j][ci][co] fp32 ----------------
__global__ __launch_bounds__(256) void prepack_dt2(
    const float* __restrict__ w, float* __restrict__ Wd) {
    int t = blockIdx.x*256 + threadIdx.x;
    if (t >= 12288) return;
    int co = t % 3, ci = (t/3) % 256, j = (t/768) % 4, p = t/3072;
    int kh0 = p >> 1, kw0 = p & 1;
    const int dj[4] = {0, 2, 8, 10};
    Wd[t] = w[(size_t)ci*48 + co*16 + kh0*4 + kw0 + dj[j]];
}

// ---------------- MFMA conv k=2 s=1, NHWC bf16 input; mode 0: fp32 NCHW out, 1: bf16 NHWC out ----------------
__global__ __launch_bounds__(256) void convk2_mfma_nhwc(
    const unsigned short* __restrict__ Xin, const unsigned short* __restrict__ apack,
    const float* __restrict__ bias, float* __restrict__ outF,
    unsigned short* __restrict__ outU,
    int inH, int inW, int outH, int outW, int pad, int mode) {
    __shared__ __align__(16) unsigned short Iraw[2][85*40];
    int b = blockIdx.y;
    int t = blockIdx.x;
    int oh0 = (t >> 2) * 4, ow0 = (t & 3) * 16;
    int w = threadIdx.x >> 6, l = threadIdx.x & 63;
    int lr = l & 15, lk = l >> 4;
    const unsigned short* src = Xin + (size_t)b*inH*inW*256;

    f32x4 acc[4][4];
    #pragma unroll
    for (int i = 0; i < 4; ++i)
        #pragma unroll
        for (int j = 0; j < 4; ++j) acc[i][j] = (f32x4){0.f,0.f,0.f,0.f};

    auto STAGE = [&](int cc, int bufi) {
        #pragma unroll
        for (int pass = 0; pass < 2; ++pass) {
            int u = pass*256 + threadIdx.x;
            if (u < 340) {
                int sp = u >> 2, q = u & 3;
                int r = (sp*241) >> 12, c = sp - r*17;
                int gh = oh0 + r - pad, gw = ow0 + c - pad;
                short8 v = (short8){0,0,0,0,0,0,0,0};
                if (gh >= 0 && gh < inH && gw >= 0 && gw < inW)
                    v = *(const short8*)(src + ((size_t)gh*inW + gw)*256 + cc*32 + q*8);
                *(short8*)&Iraw[bufi][sp*40 + q*8] = v;
            }
        }
    };

    STAGE(0, 0);
    for (int cc = 0; cc < 8; ++cc) {
        __syncthreads();
        if (cc < 7) STAGE(cc+1, (cc+1)&1);
        const unsigned short* Ib = Iraw[cc & 1];
        #pragma unroll
        for (int tap = 0; tap < 4; ++tap) {
            int kh = tap >> 1, kw = tap & 1;
            int spb = kh*17 + kw + lr;
            short8 b0 = *(const short8*)&Ib[(spb     )*40 + lk*8];
            short8 b1 = *(const short8*)&Ib[(spb + 17)*40 + lk*8];
            short8 b2 = *(const short8*)&Ib[(spb + 34)*40 + lk*8];
            short8 b3 = *(const short8*)&Ib[(spb + 51)*40 + lk*8];
            const unsigned short* abase = apack + (((size_t)(cc*4 + tap)*256)*4 + (size_t)lk)*8;
            #pragma unroll
            for (int cof = 0; cof < 4; ++cof) {
                int co = w*64 + cof*16 + lr;
                short8 af = *(const short8*)(abase + (size_t)co*32);
                acc[cof][0] = __builtin_amdgcn_mfma_f32_16x16x32_bf16(af, b0, acc[cof][0], 0, 0, 0);
                acc[cof][1] = __builtin_amdgcn_mfma_f32_16x16x32_bf16(af, b1, acc[cof][1], 0, 0, 0);
                acc[cof][2] = __builtin_amdgcn_mfma_f32_16x16x32_bf16(af, b2, acc[cof][2], 0, 0, 0);
                acc[cof][3] = __builtin_amdgcn_mfma_f32_16x16x32_bf16(af, b3, acc[cof][3], 0, 0, 0);
            }
        }
    }
    int ow = ow0 + lr;
    #pragma unroll
    for (int cof = 0; cof < 4; ++cof) {
        int cob = w*64 + cof*16 + lk*4;
        float4 bz = *(const float4*)&bias[cob];
        #pragma unroll
        for (int pxf = 0; pxf < 4; ++pxf) {
            int oh = oh0 + pxf;
            if (oh < outH && ow < outW) {
                f32x4 a = acc[cof][pxf];
                float r0 = fmaxf(a.x + bz.x, 0.f);
                float r1 = fmaxf(a.y + bz.y, 0.f);
                float r2 = fmaxf(a.z + bz.z, 0.f);
                float r3 = fmaxf(a.w + bz.w, 0.f);
                if (mode == 0) {
                    size_t base = ((size_t)(b*256 + cob)*outH + oh)*outW + ow;
                    size_t st = (size_t)outH*outW;
                    outF[base]        = r0;
                    outF[base +   st] = r1;
                    outF[base + 2*st] = r2;
                    outF[base + 3*st] = r3;
                } else {
                    us4 pk = { f2bf(r0), f2bf(r1), f2bf(r2), f2bf(r3) };
                    *(us4*)(outU + ((size_t)b*outH*outW + (size_t)oh*outW + ow)*256 + cob) = pk;
                }
            }
        }
    }
}

// ---------------- codebook norms ----------------
__global__ __launch_bounds__(256) void cb_norm(
    const float* __restrict__ cb, float* __restrict__ cbn) {
    for (int n = threadIdx.x; n < KCB; n += 256) {
        float s = 0.f;
        for (int k = 0; k < 256; ++k) { float v = cb[(size_t)n*256+k]; s = fmaf(v,v,s); }
        cbn[n] = s;
    }
}

// ---------------- codebook bf16 pack ----------------
__global__ __launch_bounds__(256) void cb_pack(
    const float* __restrict__ cb, unsigned short* __restrict__ cbp) {
    int t = blockIdx.x*256 + threadIdx.x;
    cbp[t] = f2bf(cb[t]);
}

// ---------------- MFMA VQ assign: LDS-staged codebook, 64 rows/block ----------------
__global__ __launch_bounds__(256) void vq_assign_mfma(
    const float* __restrict__ z, const unsigned short* __restrict__ cbp,
    const float* __restrict__ cbn, int* __restrict__ idx) {
    __shared__ __align__(16) unsigned short zb[64*264];
    __shared__ __align__(16) unsigned short cbs[2][32*264];
    __shared__ float cbl[KCB];
    int r0 = blockIdx.x * 64;
    for (int v = threadIdx.x; v < 4096; v += 256) {
        int row = v >> 6, col4 = v & 63;
        float4 u = *(const float4*)&z[(size_t)(r0+row)*256 + col4*4];
        us4 pk = { f2bf(u.x), f2bf(u.y), f2bf(u.z), f2bf(u.w) };
        *(us4*)&zb[row*264 + col4*4] = pk;
    }
    for (int i = threadIdx.x; i < KCB; i += 256) cbl[i] = cbn[i];
    int tcode = threadIdx.x >> 3, tk = threadIdx.x & 7;
    auto STAGE_CB = [&](int c, int bufi) {
        const unsigned short* src = cbp + ((size_t)(c*32 + tcode))*256 + tk*8;
        unsigned short* dst = &cbs[bufi][tcode*264 + tk*8];
        #pragma unroll
        for (int j = 0; j < 4; ++j)
            *(short8*)(dst + j*64) = *(const short8*)(src + j*64);
    };
    STAGE_CB(0, 0);
    __syncthreads();

    int w = threadIdx.x >> 6, l = threadIdx.x & 63;
    int lr = l & 15, lk = l >> 4;
    short8 afr[8];
    #pragma unroll
    for (int ks = 0; ks < 8; ++ks)
        afr[ks] = *(const short8*)&zb[(w*16 + lr)*264 + ks*32 + lk*8];

    float bd[4]; int bi[4];
    #pragma unroll
    for (int r = 0; r < 4; ++r) { bd[r] = 3.0e38f; bi[r] = 0; }

    for (int c = 0; c < 16; ++c) {
        if (c < 15) STAGE_CB(c+1, (c+1)&1);
        const unsigned short* Cb = cbs[c & 1];
        #pragma unroll
        for (int f = 0; f < 2; ++f) {
            f32x4 acc = (f32x4){0.f,0.f,0.f,0.f};
            #pragma unroll
            for (int ks = 0; ks < 8; ++ks) {
                short8 bfr = *(const short8*)&Cb[(f*16 + lr)*264 + ks*32 + lk*8];
                acc = __builtin_amdgcn_mfma_f32_16x16x32_bf16(afr[ks], bfr, acc, 0, 0, 0);
            }
            int n = c*32 + f*16 + lr;
            float cn = cbl[n];
            #pragma unroll
            for (int r = 0; r < 4; ++r) {
                float dist = fmaf(-2.f, acc[r], cn);
                if (dist < bd[r]) { bd[r] = dist; bi[r] = n; }
            }
        }
        __syncthreads();
    }
    #pragma unroll
    for (int r = 0; r < 4; ++r) {
        #pragma unroll
        for (int off = 1; off < 16; off <<= 1) {
            float od = __shfl_xor(bd[r], off, 64);
            int   oi = __shfl_xor(bi[r], off, 64);
            if (od < bd[r] || (od == bd[r] && oi < bi[r])) { bd[r] = od; bi[r] = oi; }
        }
    }
    if (lr == 0) {
        #pragma unroll
        for (int r = 0; r < 4; ++r)
            idx[r0 + w*16 + lk*4 + r] = bi[r];
    }
}

// ---------------- IN-PLACE VQ gather ----------------
__global__ __launch_bounds__(256) void vq_gather(
    float* zq, const float* __restrict__ cb,
    const int* __restrict__ idx, float* __restrict__ sse, int* __restrict__ counts) {
    __shared__ int hist[KCB];
    for (int i = threadIdx.x; i < KCB; i += 256) hist[i] = 0;
    __syncthreads();
    float local = 0.f;
    for (int r = blockIdx.x; r < NROWS; r += GATHER_BLOCKS) {
        int id = idx[r];
        if (threadIdx.x == 0) atomicAdd(&hist[id], 1);
        float qv = cb[(size_t)id*256 + threadIdx.x];
        float* pz = zq + (size_t)r*256 + threadIdx.x;
        float zv = *pz;
        *pz = qv;
        float d = qv - zv;
        local = fmaf(d, d, local);
    }
    __shared__ float lds[4];
    for (int off = 32; off; off >>= 1) local += __shfl_down(local, off, 64);
    if ((threadIdx.x & 63) == 0) lds[threadIdx.x >> 6] = local;
    __syncthreads();
    if (threadIdx.x == 0) atomicAdd(sse, lds[0]+lds[1]+lds[2]+lds[3]);
    for (int i = threadIdx.x; i < KCB; i += 256) {
        int h = hist[i];
        if (h) atomicAdd(counts + i, h);
    }
}

// ---------------- loss + perplexity ----------------
__global__ __launch_bounds__(256) void vq_finalize(
    const float* __restrict__ sse, const int* __restrict__ counts,
    float* __restrict__ out) {
    __shared__ float lds[4];
    float h = 0.f;
    for (int n = threadIdx.x; n < KCB; n += 256) {
        float p = (float)counts[n] * (1.f/123008.f);
        h += p * logf(p + 1e-10f);
    }
    for (int off = 32; off; off >>= 1) h += __shfl_down(h, off, 64);
    if ((threadIdx.x & 63) == 0) lds[threadIdx.x >> 6] = h;
    __syncthreads();
    if (threadIdx.x == 0) {
        out[1572864] = 1.25f * sse[0] / 31490048.f;
        out[1572865] = expf(-(lds[0]+lds[1]+lds[2]+lds[3]));
    }
}

// ---------------- dt2: convT 256->3, k4, s2, NHWC bf16 input, wave-uniform parity ----------------
__global__ __launch_bounds__(256) void dt2_nhwc(
    const unsigned short* __restrict__ Y, const float* __restrict__ Wd,
    const float* __restrict__ bias, float* __restrict__ out) {
    int b = blockIdx.y;
    int wid = threadIdx.x >> 6, l = threadIdx.x & 63;
    int h = blockIdx.x*2 + (wid >> 1);
    int wpos = l*2 + (wid & 1);
    int kh0 = h & 1, kw0 = wid & 1;
    int p = kh0*2 + kw0;
    int pbase = __builtin_amdgcn_readfirstlane(p * 3072);
    int ih0 = (h - kh0) >> 1, iw0 = (wpos - kw0) >> 1;
    bool vh0 = (ih0 < 63), vh1 = (ih0 >= 1);
    bool vw0 = (iw0 < 63), vw1 = (iw0 >= 1);
    const unsigned short* yb = Y + (size_t)b*HW1*256;
    const unsigned short* tp[4];
    bool tv[4];
    tp[0] = yb + ((size_t)(ih0*63 + iw0))*256;         tv[0] = vh0 && vw0;
    tp[1] = yb + ((size_t)(ih0*63 + iw0 - 1))*256;     tv[1] = vh0 && vw1;
    tp[2] = yb + ((size_t)((ih0-1)*63 + iw0))*256;     tv[2] = vh1 && vw0;
    tp[3] = yb + ((size_t)((ih0-1)*63 + iw0 - 1))*256; tv[3] = vh1 && vw1;
    float a0 = bias[0], a1 = bias[1], a2 = bias[2];
    #pragma unroll
    for (int j = 0; j < 4; ++j) {
        if (!tv[j]) continue;
        const unsigned short* src = tp[j];
        const float* wj = Wd + pbase + j*768;
        for (int c0 = 0; c0 < 256; c0 += 8) {
            short8 v = *(const short8*)(src + c0);
            const float* wc = wj + c0*3;
            #pragma unroll
            for (int q = 0; q < 8; ++q) {
                float f = bf2f((unsigned short)v[q]);
                a0 = fmaf(f, wc[q*3+0], a0);
                a1 = fmaf(f, wc[q*3+1], a1);
                a2 = fmaf(f, wc[q*3+2], a2);
            }
        }
    }
    size_t ob = ((size_t)(b*3)*128 + h)*128 + wpos;
    out[ob]         = a0;
    out[ob + 16384] = a1;
    out[ob + 32768] = a2;
}

// ---------------- launch ----------------
extern "C" void kernel_launch(void* const* d_in, const int* in_sizes, int n_in,
                              void* d_out, int out_size, void* d_ws, size_t ws_size,
                              hipStream_t stream) {
    const float* x      = (const float*)d_in[0];
    const float* ec1_w  = (const float*)d_in[1];
    const float* ec1_b  = (const float*)d_in[2];
    const float* ec2_w  = (const float*)d_in[3];
    const float* ec2_b  = (const float*)d_in[4];
    const float* se1_w1 = (const float*)d_in[5];
    const float* se1_b1 = (const float*)d_in[6];
    const float* se1_w2 = (const float*)d_in[7];
    const float* se1_b2 = (const float*)d_in[8];
    const float* sa1_w  = (const float*)d_in[9];
    const float* se2_w1 = (const float*)d_in[10];
    const float* se2_b1 = (const float*)d_in[11];
    const float* se2_w2 = (const float*)d_in[12];
    const float* se2_b2 = (const float*)d_in[13];
    const float* sa2_w  = (const float*)d_in[14];
    const float* cbk    = (const float*)d_in[15];
    const float* dt1_w  = (const float*)d_in[16];
    const float* dt1_b  = (const float*)d_in[17];
    const float* dt2_w  = (const float*)d_in[18];
    const float* dt2_b  = (const float*)d_in[19];
    const float* dse_w1 = (const float*)d_in[20];
    const float* dse_b1 = (const float*)d_in[21];
    const float* dse_w2 = (const float*)d_in[22];
    const float* dse_b2 = (const float*)d_in[23];
    const float* dsa_w  = (const float*)d_in[24];
    float* out = (float*)d_out;

    float* BIG         = (float*)d_ws;                    // T63 fp32 (130 MB)
    unsigned short* U0 = (unsigned short*)(BIG + T63);    // T63 bf16 (65 MB)
    unsigned short* U1 = U0 + T63;                         // T63 bf16 (65 MB)
    float* pooled = (float*)(U1 + T63);
    float* g      = pooled + 8192;
    float* am     = g + 8192;
    float* ssmap  = am + (size_t)NB*2*HW1;
    float* cbn    = ssmap + (size_t)NB*HW1;
    unsigned short* apackE = (unsigned short*)(cbn + 512);
    unsigned short* apackD = apackE + 262144;
    unsigned short* cbp    = apackD + 262144;
    unsigned short* apackC = cbp + 131072;                 // 16384 ushorts (conv1)
    float* Wd     = (float*)(apackC + 16384);
    float* sse    = Wd + 12288;
    int*   counts = (int*)(sse + 1);
    int*   idx    = counts + 512;

    // prep
    zero_small<<<1, 256, 0, stream>>>(sse, counts);
    prepack_w<<<1024, 256, 0, stream>>>(ec2_w, apackE, 0);
    prepack_w<<<1024, 256, 0, stream>>>(dt1_w, apackD, 1);
    prepack_c1<<<64, 256, 0, stream>>>(ec1_w, apackC);
    prepack_dt2<<<48, 256, 0, stream>>>(dt2_w, Wd);
    cb_norm<<<1, 256, 0, stream>>>(cbk, cbn);
    cb_pack<<<512, 256, 0, stream>>>(cbk, cbp);

    // encoder conv1 (MFMA im2col) -> U0 bf16 NHWC; cbam1 on NHWC
    conv1_mfma<<<dim3(64, NB), 256, 0, stream>>>(x, apackC, ec1_b, U0);
    zero_pooled<<<32, 256, 0, stream>>>(pooled);
    gap_nhwc<<<dim3(8, NB), 256, 0, stream>>>(U0, pooled, HW1, 1.f/HW1);
    se_mlp<<<NB, 256, 0, stream>>>(pooled, se1_w1, se1_b1, se1_w2, se1_b2, g);
    chanpool_nhwc<<<dim3(16, NB), 256, 0, stream>>>(U0, g, am, HW1);
    spatial_conv<<<dim3(16, NB), 256, 0, stream>>>(am, sa1_w, ssmap, 63, 63, 0);
    cbam_mul_nhwc<<<dim3(16, NB), 256, 0, stream>>>(U0, g, ssmap, HW1);

    // conv2 (U0 -> BIG fp32 NCHW) + cbam2 NCHW => z in BIG (VQ flat semantics need NCHW)
    convk2_mfma_nhwc<<<dim3(64, NB), 256, 0, stream>>>(U0, apackE, ec2_b, BIG, (unsigned short*)0, 63, 63, 62, 62, 0, 0);
    gap_kernel<<<NB*256, 256, 0, stream>>>(BIG, pooled, HW2);
    se_mlp<<<NB, 256, 0, stream>>>(pooled, se2_w1, se2_b1, se2_w2, se2_b2, g);
    chanpool<<<dim3(16, NB), 256, 0, stream>>>(BIG, g, am, HW2);
    spatial_conv<<<dim3(16, NB), 256, 0, stream>>>(am, sa2_w, ssmap, 62, 62, 0);
    cbam_final<<<dim3(HW2, NB), 256, 0, stream>>>(BIG, g, ssmap, HW2);

    // VQ: z in BIG -> q in BIG (in-place), then q -> U1 bf16 NHWC
    vq_assign_mfma<<<NROWS/64, 256, 0, stream>>>(BIG, cbp, cbn, idx);
    vq_gather<<<GATHER_BLOCKS, 256, 0, stream>>>(BIG, cbk, idx, sse, counts);
    vq_finalize<<<1, 256, 0, stream>>>(sse, counts, out);
    to_nhwc_bf16<<<dim3(16, NB), 256, 0, stream>>>(BIG, U1, HW2);

    // decoder dt1 (U1 -> U0 bf16 NHWC) + cbam3 on NHWC
    convk2_mfma_nhwc<<<dim3(64, NB), 256, 0, stream>>>(U1, apackD, dt1_b, (float*)0, U0, 62, 62, 63, 63, 1, 1);
    zero_pooled<<<32, 256, 0, stream>>>(pooled);
    gap_nhwc<<<dim3(8, NB), 256, 0, stream>>>(U0, pooled, HW1, 1.f/HW1);
    se_mlp<<<NB, 256, 0, stream>>>(pooled, dse_w1, dse_b1, dse_w2, dse_b2, g);
    chanpool_nhwc<<<dim3(16, NB), 256, 0, stream>>>(U0, g, am, HW1);
    spatial_conv<<<dim3(16, NB), 256, 0, stream>>>(am, dsa_w, ssmap, 63, 63, 1);
    cbam_mul_nhwc<<<dim3(16, NB), 256, 0, stream>>>(U0, g, ssmap, HW1);

    // final convT -> out
    dt2_nhwc<<<dim3(64, NB), 256, 0, stream>>>(U0, Wd, dt2_b, out);
}

// Round 11
// 914.657 us; speedup vs baseline: 6.6608x; 1.1213x over previous
//
#include <hip/hip_runtime.h>
#include <math.h>

// ---------------- sizes ----------------
#define NB 32
#define HID 256
#define HW1 (63*63)      // 3969
#define HW2 (62*62)      // 3844
#define T63 ((size_t)NB*HID*HW1)   // 32,514,048
#define T62 ((size_t)NB*HID*HW2)   // 31,490,048
#define NROWS 123008               // T62 / 256
#define KCB 512
#define GATHER_BLOCKS 1024

typedef __attribute__((ext_vector_type(8))) short short8;
typedef __attribute__((ext_vector_type(4))) float f32x4;
typedef __attribute__((ext_vector_type(4))) unsigned short us4;

__device__ __forceinline__ unsigned short f2bf(float f) {
    union { float f; unsigned int u; } v; v.f = f;
    unsigned int u = v.u;
    return (unsigned short)((u + 0x7FFFu + ((u >> 16) & 1u)) >> 16);
}
__device__ __forceinline__ float bf2f(unsigned short u) {
    union { unsigned int i; float f; } v; v.i = ((unsigned int)u) << 16;
    return v.f;
}

// ---------------- zero helpers ----------------
__global__ __launch_bounds__(256) void zero_small(float* __restrict__ sse, int* __restrict__ counts) {
    if (threadIdx.x == 0) sse[0] = 0.f;
    for (int i = threadIdx.x; i < KCB; i += 256) counts[i] = 0;
}
__global__ __launch_bounds__(256) void zero_pooled(float* __restrict__ pooled) {
    pooled[blockIdx.x*256 + threadIdx.x] = 0.f;
}

// ---------------- conv1 weight prepack: [kc][co][lk][8] bf16, K=48 padded to 64 ----------------
__global__ __launch_bounds__(256) void prepack_c1(
    const float* __restrict__ w, unsigned short* __restrict__ pack) {
    int t = blockIdx.x*256 + threadIdx.x;   // 64 blocks -> 16384
    if (t >= 16384) return;
    int j = t & 7, lk = (t >> 3) & 3, co = (t >> 5) & 255, kc = t >> 13;
    int k = kc*32 + lk*8 + j;               // k = ci*16 + kh*4 + kw
    pack[t] = (k < 48) ? f2bf(w[co*48 + k]) : (unsigned short)0;
}

// ---------------- conv1: 3->256, k4, s2, relu -> bf16 NHWC via im2col MFMA ----------------
__global__ __launch_bounds__(256) void conv1_mfma(
    const float* __restrict__ x, const unsigned short* __restrict__ apack,
    const float* __restrict__ bias, unsigned short* __restrict__ X0) {
    __shared__ float xs[3][18][18];
    __shared__ __align__(16) unsigned short Bm[64*72];
    int b = blockIdx.y, t = blockIdx.x;
    int oh0 = (t >> 3)*8, ow0 = (t & 7)*8;
    int ih0 = oh0*2, iw0 = ow0*2;
    const float* xb = x + (size_t)b*3*128*128;
    for (int i = threadIdx.x; i < 972; i += 256) {
        int c = i / 324, rem = i - c*324, r = rem / 18, cl = rem - r*18;
        int ih = ih0 + r, iw = iw0 + cl;
        xs[c][r][cl] = (ih < 128 && iw < 128) ? xb[((size_t)c*128 + ih)*128 + iw] : 0.f;
    }
    __syncthreads();
    for (int i = threadIdx.x; i < 2048; i += 256) {
        int px = i >> 5, kp = (i & 31)*2;
        int ph = px >> 3, pw = px & 7;
        unsigned int pk = 0;
        #pragma unroll
        for (int u = 0; u < 2; ++u) {
            int k = kp + u;
            float v = 0.f;
            if (k < 48) {
                int c = k >> 4, k2 = k & 15, kh = k2 >> 2, kw = k2 & 3;
                v = xs[c][ph*2+kh][pw*2+kw];
            }
            pk |= ((unsigned int)f2bf(v)) << (16*u);
        }
        *(unsigned int*)&Bm[px*72 + kp] = pk;
    }
    __syncthreads();

    int w = threadIdx.x >> 6, l = threadIdx.x & 63;
    int lr = l & 15, lk = l >> 4;
    f32x4 acc[4][4];
    #pragma unroll
    for (int i = 0; i < 4; ++i)
        #pragma unroll
        for (int j = 0; j < 4; ++j) acc[i][j] = (f32x4){0.f,0.f,0.f,0.f};

    #pragma unroll
    for (int kc = 0; kc < 2; ++kc) {
        short8 bf[4];
        #pragma unroll
        for (int pxf = 0; pxf < 4; ++pxf)
            bf[pxf] = *(const short8*)&Bm[(pxf*16+lr)*72 + kc*32 + lk*8];
        #pragma unroll
        for (int cof = 0; cof < 4; ++cof) {
            int co = w*64 + cof*16 + lr;
            short8 af = *(const short8*)(apack + (((size_t)kc*256 + co)*4 + (size_t)lk)*8);
            acc[cof][0] = __builtin_amdgcn_mfma_f32_16x16x32_bf16(af, bf[0], acc[cof][0], 0, 0, 0);
            acc[cof][1] = __builtin_amdgcn_mfma_f32_16x16x32_bf16(af, bf[1], acc[cof][1], 0, 0, 0);
            acc[cof][2] = __builtin_amdgcn_mfma_f32_16x16x32_bf16(af, bf[2], acc[cof][2], 0, 0, 0);
            acc[cof][3] = __builtin_amdgcn_mfma_f32_16x16x32_bf16(af, bf[3], acc[cof][3], 0, 0, 0);
        }
    }
    #pragma unroll
    for (int cof = 0; cof < 4; ++cof) {
        int cob = w*64 + cof*16 + lk*4;
        float4 bz = *(const float4*)&bias[cob];
        #pragma unroll
        for (int pxf = 0; pxf < 4; ++pxf) {
            int px = pxf*16 + lr;
            int oh = oh0 + (px >> 3), ow = ow0 + (px & 7);
            if (oh < 63 && ow < 63) {
                f32x4 a = acc[cof][pxf];
                us4 pk = { f2bf(fmaxf(a.x + bz.x, 0.f)), f2bf(fmaxf(a.y + bz.y, 0.f)),
                           f2bf(fmaxf(a.z + bz.z, 0.f)), f2bf(fmaxf(a.w + bz.w, 0.f)) };
                *(us4*)(X0 + ((size_t)b*HW1 + (size_t)oh*63 + ow)*256 + cob) = pk;
            }
        }
    }
}

// ---------------- gap over NHWC bf16 (atomic accumulate; pooled pre-zeroed) ----------------
__global__ __launch_bounds__(256) void gap_nhwc(
    const unsigned short* __restrict__ X, float* __restrict__ pooled,
    int HW, float inv) {
    int b = blockIdx.y;
    int px0 = blockIdx.x * 512;
    int o = threadIdx.x & 31, pg = threadIdx.x >> 5;
    const unsigned short* xb = X + (size_t)b*HW*256 + o*8;
    float acc[8];
    #pragma unroll
    for (int j = 0; j < 8; ++j) acc[j] = 0.f;
    for (int i = 0; i < 64; ++i) {
        int px = px0 + pg + i*8;
        if (px < HW) {
            short8 v = *(const short8*)(xb + (size_t)px*256);
            #pragma unroll
            for (int j = 0; j < 8; ++j) acc[j] += bf2f((unsigned short)v[j]);
        }
    }
    __shared__ float pool2[8][256];
    #pragma unroll
    for (int j = 0; j < 8; ++j) pool2[pg][o*8+j] = acc[j];
    __syncthreads();
    float s = 0.f;
    #pragma unroll
    for (int p = 0; p < 8; ++p) s += pool2[p][threadIdx.x];
    atomicAdd(pooled + b*256 + threadIdx.x, s * inv);
}

// ---------------- gap NCHW (encoder-2) ----------------
__global__ __launch_bounds__(256) void gap_kernel(
    const float* __restrict__ x, float* __restrict__ pooled, int HW) {
    int bc = blockIdx.x;
    const float* p = x + (size_t)bc*HW;
    float s = 0.f;
    for (int i = threadIdx.x; i < HW; i += 256) s += p[i];
    __shared__ float lds[4];
    for (int off = 32; off; off >>= 1) s += __shfl_down(s, off, 64);
    if ((threadIdx.x & 63) == 0) lds[threadIdx.x >> 6] = s;
    __syncthreads();
    if (threadIdx.x == 0) pooled[bc] = (lds[0]+lds[1]+lds[2]+lds[3]) / (float)HW;
}

// ---------------- SE MLP ----------------
__global__ __launch_bounds__(256) void se_mlp(
    const float* __restrict__ pooled, const float* __restrict__ w1,
    const float* __restrict__ b1, const float* __restrict__ w2,
    const float* __restrict__ b2, float* __restrict__ g) {
    int b = blockIdx.x;
    __shared__ float ps[256], hs[16];
    ps[threadIdx.x] = pooled[b*256 + threadIdx.x];
    __syncthreads();
    if (threadIdx.x < 16) {
        float a = b1[threadIdx.x];
        const float* wr = w1 + threadIdx.x*256;
        for (int k = 0; k < 256; ++k) a = fmaf(ps[k], wr[k], a);
        hs[threadIdx.x] = fmaxf(a, 0.f);
    }
    __syncthreads();
    float a = b2[threadIdx.x];
    const float* wr = w2 + threadIdx.x*16;
    #pragma unroll
    for (int j = 0; j < 16; ++j) a = fmaf(hs[j], wr[j], a);
    g[b*256 + threadIdx.x] = 1.f / (1.f + expf(-a));
}

// ---------------- channel mean/max of x*g (NHWC bf16) ----------------
__global__ __launch_bounds__(256) void chanpool_nhwc(
    const unsigned short* __restrict__ X, const float* __restrict__ g,
    float* __restrict__ am, int HW) {
    int b = blockIdx.y;
    __shared__ float gs[256];
    gs[threadIdx.x] = g[b*256 + threadIdx.x];
    __syncthreads();
    int p = blockIdx.x*256 + threadIdx.x;
    if (p >= HW) return;
    const unsigned short* xp = X + ((size_t)b*HW + p)*256;
    float s = 0.f, mx = -3.0e38f;
    for (int o = 0; o < 32; ++o) {
        short8 v = *(const short8*)(xp + o*8);
        #pragma unroll
        for (int j = 0; j < 8; ++j) {
            float f = bf2f((unsigned short)v[j]) * gs[o*8+j];
            s += f; mx = fmaxf(mx, f);
        }
    }
    am[((size_t)b*2)*HW + p]   = s * (1.f/256.f);
    am[((size_t)b*2+1)*HW + p] = mx;
}

// ---------------- channel mean/max of x*g (NCHW fp32, encoder-2) ----------------
__global__ __launch_bounds__(256) void chanpool(
    const float* __restrict__ x, const float* __restrict__ g,
    float* __restrict__ am, int HW) {
    int b = blockIdx.y;
    int p = blockIdx.x*256 + threadIdx.x;
    if (p >= HW) return;
    const float* xb = x + (size_t)b*256*HW + p;
    const float* gb = g + b*256;
    float s = 0.f, mx = -3.0e38f;
    for (int c = 0; c < 256; ++c) {
        float v = xb[(size_t)c*HW] * gb[c];
        s += v; mx = fmaxf(mx, v);
    }
    am[((size_t)b*2)*HW + p]   = s * (1.f/256.f);
    am[((size_t)b*2+1)*HW + p] = mx;
}

// ---------------- 7x7 spatial conv on [mean,max], sigmoid ----------------
__global__ __launch_bounds__(256) void spatial_conv(
    const float* __restrict__ am, const float* __restrict__ sw,
    float* __restrict__ ss, int H, int W, int transpose) {
    int b = blockIdx.y;
    int p = blockIdx.x*256 + threadIdx.x;
    __shared__ float ws[98];
    if (threadIdx.x < 98) {
        int c = threadIdx.x / 49, k = threadIdx.x % 49;
        int kh = k / 7, kw = k % 7;
        ws[threadIdx.x] = transpose ? sw[c*49 + (6-kh)*7 + (6-kw)]
                                    : sw[c*49 + kh*7 + kw];
    }
    __syncthreads();
    if (p >= H*W) return;
    int oh = p / W, ow = p % W;
    float acc = 0.f;
    #pragma unroll
    for (int c = 0; c < 2; ++c) {
        const float* ab = am + ((size_t)b*2 + c)*H*W;
        for (int kh = 0; kh < 7; ++kh) {
            int ih = oh + kh - 3;
            if (ih < 0 || ih >= H) continue;
            for (int kw = 0; kw < 7; ++kw) {
                int iw = ow + kw - 3;
                if (iw < 0 || iw >= W) continue;
                acc = fmaf(ab[(size_t)ih*W + iw], ws[c*49 + kh*7 + kw], acc);
            }
        }
    }
    ss[(size_t)b*H*W + p] = 1.f / (1.f + expf(-acc));
}

// ---------------- IN-PLACE NHWC bf16: x = x*x*g*sig(s) ----------------
__global__ __launch_bounds__(256) void cbam_mul_nhwc(
    unsigned short* X, const float* __restrict__ g,
    const float* __restrict__ ss, int HW) {
    int b = blockIdx.y;
    __shared__ float gs[256];
    gs[threadIdx.x] = g[b*256 + threadIdx.x];
    __syncthreads();
    int p = blockIdx.x*256 + threadIdx.x;
    if (p >= HW) return;
    float sv = ss[(size_t)b*HW + p];
    unsigned short* xp = X + ((size_t)b*HW + p)*256;
    for (int o = 0; o < 32; ++o) {
        short8 v = *(const short8*)(xp + o*8);
        unsigned int pk[4];
        #pragma unroll
        for (int j = 0; j < 4; ++j) {
            float f0 = bf2f((unsigned short)v[2*j]);
            float f1 = bf2f((unsigned short)v[2*j+1]);
            f0 = f0*f0*gs[o*8+2*j]*sv;
            f1 = f1*f1*gs[o*8+2*j+1]*sv;
            pk[j] = (unsigned int)f2bf(f0) | ((unsigned int)f2bf(f1) << 16);
        }
        *(short8*)(xp + o*8) = *(const short8*)pk;
    }
}

// ---------------- IN-PLACE NCHW fp32: x = x*x*g*sig(s) (encoder-2) ----------------
__global__ __launch_bounds__(256) void cbam_final(
    float* x, const float* __restrict__ g,
    const float* __restrict__ ss, int HW) {
    int b = blockIdx.y;
    size_t e = (size_t)blockIdx.x*256 + threadIdx.x;
    if (e >= (size_t)256*HW) return;
    int c = (int)(e / HW), p = (int)(e % HW);
    float* px = x + (size_t)b*256*HW + e;
    float xv = *px;
    *px = xv * xv * g[b*256+c] * ss[(size_t)b*HW + p];
}

// ---------------- NCHW fp32 -> NHWC bf16 (q after VQ) ----------------
__global__ __launch_bounds__(256) void to_nhwc_bf16(
    const float* __restrict__ in, unsigned short* __restrict__ X, int HW) {
    int b = blockIdx.y;
    int p = blockIdx.x*256 + threadIdx.x;
    bool valid = p < HW;
    const float* inb = in + (size_t)b*256*HW + p;
    unsigned short* dst = X + ((size_t)b*HW + p)*256;
    #pragma unroll
    for (int ch = 0; ch < 4; ++ch) {
        unsigned int pk[32];
        #pragma unroll
        for (int j = 0; j < 32; ++j) {
            int c0 = ch*64 + j*2;
            float v0 = valid ? inb[(size_t)c0*HW] : 0.f;
            float v1 = valid ? inb[(size_t)(c0+1)*HW] : 0.f;
            pk[j] = (unsigned int)f2bf(v0) | ((unsigned int)f2bf(v1) << 16);
        }
        if (valid) {
            #pragma unroll
            for (int j2 = 0; j2 < 8; ++j2)
                *(short8*)(dst + ch*64 + j2*8) = *(const short8*)&pk[j2*4];
        }
    }
}

// ---------------- weight prepack into MFMA-fragment layout (bf16) ----------------
__global__ __launch_bounds__(256) void prepack_w(
    const float* __restrict__ w, unsigned short* __restrict__ pack, int transpose_flip) {
    int t = blockIdx.x*256 + threadIdx.x;
    int j = t & 7, koct = (t >> 3) & 3, co = (t >> 5) & 255, tap = (t >> 13) & 3, cc = t >> 15;
    int ci = cc*32 + koct*8 + j;
    int kh = tap >> 1, kw = tap & 1;
    float v;
    if (transpose_flip) v = w[((size_t)ci*256 + co)*4 + (1-kh)*2 + (1-kw)];
    else                v = w[((size_t)co*256 + ci)*4 + kh*2 + kw];
    pack[t] = f2bf(v);
}

// ---------------- dt2 weight prepack (MFMA A-frag): [p][cc][j][co16][lk][8] bf16 ----------------
__global__ __launch_bounds__(256) void prepack_dt2b(
    const float* __restrict__ w, unsigned short* __restrict__ pk) {
    int t = blockIdx.x*256 + threadIdx.x;   // 256 blocks -> 65536
    int jj = t & 7, lk = (t >> 3) & 3, co = (t >> 5) & 15, j = (t >> 9) & 3, cc = (t >> 11) & 7, p = t >> 14;
    int ci = cc*32 + lk*8 + jj;
    int kh0 = p >> 1, kw0 = p & 1;
    const int dj[4] = {0, 2, 8, 10};
    float v = 0.f;
    if (co < 3) v = w[(size_t)ci*48 + co*16 + kh0*4 + kw0 + dj[j]];
    pk[t] = f2bf(v);
}

// ---------------- MFMA conv k=2 s=1, NHWC bf16 input; mode 0: fp32 NCHW out, 1: bf16 NHWC out ----------------
__global__ __launch_bounds__(256) void convk2_mfma_nhwc(
    const unsigned short* __restrict__ Xin, const unsigned short* __restrict__ apack,
    const float* __restrict__ bias, float* __restrict__ outF,
    unsigned short* __restrict__ outU,
    int inH, int inW, int outH, int outW, int pad, int mode) {
    __shared__ __align__(16) unsigned short Iraw[2][85*40];
    int b = blockIdx.y;
    int t = blockIdx.x;
    int oh0 = (t >> 2) * 4, ow0 = (t & 3) * 16;
    int w = threadIdx.x >> 6, l = threadIdx.x & 63;
    int lr = l & 15, lk = l >> 4;
    const unsigned short* src = Xin + (size_t)b*inH*inW*256;

    f32x4 acc[4][4];
    #pragma unroll
    for (int i = 0; i < 4; ++i)
        #pragma unroll
        for (int j = 0; j < 4; ++j) acc[i][j] = (f32x4){0.f,0.f,0.f,0.f};

    auto STAGE = [&](int cc, int bufi) {
        #pragma unroll
        for (int pass = 0; pass < 2; ++pass) {
            int u = pass*256 + threadIdx.x;
            if (u < 340) {
                int sp = u >> 2, q = u & 3;
                int r = (sp*241) >> 12, c = sp - r*17;
                int gh = oh0 + r - pad, gw = ow0 + c - pad;
                short8 v = (short8){0,0,0,0,0,0,0,0};
                if (gh >= 0 && gh < inH && gw >= 0 && gw < inW)
                    v = *(const short8*)(src + ((size_t)gh*inW + gw)*256 + cc*32 + q*8);
                *(short8*)&Iraw[bufi][sp*40 + q*8] = v;
            }
        }
    };

    STAGE(0, 0);
    for (int cc = 0; cc < 8; ++cc) {
        __syncthreads();
        if (cc < 7) STAGE(cc+1, (cc+1)&1);
        const unsigned short* Ib = Iraw[cc & 1];
        #pragma unroll
        for (int tap = 0; tap < 4; ++tap) {
            int kh = tap >> 1, kw = tap & 1;
            int spb = kh*17 + kw + lr;
            short8 b0 = *(const short8*)&Ib[(spb     )*40 + lk*8];
            short8 b1 = *(const short8*)&Ib[(spb + 17)*40 + lk*8];
            short8 b2 = *(const short8*)&Ib[(spb + 34)*40 + lk*8];
            short8 b3 = *(const short8*)&Ib[(spb + 51)*40 + lk*8];
            const unsigned short* abase = apack + (((size_t)(cc*4 + tap)*256)*4 + (size_t)lk)*8;
            #pragma unroll
            for (int cof = 0; cof < 4; ++cof) {
                int co = w*64 + cof*16 + lr;
                short8 af = *(const short8*)(abase + (size_t)co*32);
                acc[cof][0] = __builtin_amdgcn_mfma_f32_16x16x32_bf16(af, b0, acc[cof][0], 0, 0, 0);
                acc[cof][1] = __builtin_amdgcn_mfma_f32_16x16x32_bf16(af, b1, acc[cof][1], 0, 0, 0);
                acc[cof][2] = __builtin_amdgcn_mfma_f32_16x16x32_bf16(af, b2, acc[cof][2], 0, 0, 0);
                acc[cof][3] = __builtin_amdgcn_mfma_f32_16x16x32_bf16(af, b3, acc[cof][3], 0, 0, 0);
            }
        }
    }
    int ow = ow0 + lr;
    #pragma unroll
    for (int cof = 0; cof < 4; ++cof) {
        int cob = w*64 + cof*16 + lk*4;
        float4 bz = *(const float4*)&bias[cob];
        #pragma unroll
        for (int pxf = 0; pxf < 4; ++pxf) {
            int oh = oh0 + pxf;
            if (oh < outH && ow < outW) {
                f32x4 a = acc[cof][pxf];
                float r0 = fmaxf(a.x + bz.x, 0.f);
                float r1 = fmaxf(a.y + bz.y, 0.f);
                float r2 = fmaxf(a.z + bz.z, 0.f);
                float r3 = fmaxf(a.w + bz.w, 0.f);
                if (mode == 0) {
                    size_t base = ((size_t)(b*256 + cob)*outH + oh)*outW + ow;
                    size_t st = (size_t)outH*outW;
                    outF[base]        = r0;
                    outF[base +   st] = r1;
                    outF[base + 2*st] = r2;
                    outF[base + 3*st] = r3;
                } else {
                    us4 pk = { f2bf(r0), f2bf(r1), f2bf(r2), f2bf(r3) };
                    *(us4*)(outU + ((size_t)b*outH*outW + (size_t)oh*outW + ow)*256 + cob) = pk;
                }
            }
        }
    }
}

// ---------------- codebook norms ----------------
__global__ __launch_bounds__(256) void cb_norm(
    const float* __restrict__ cb, float* __restrict__ cbn) {
    for (int n = threadIdx.x; n < KCB; n += 256) {
        float s = 0.f;
        for (int k = 0; k < 256; ++k) { float v = cb[(size_t)n*256+k]; s = fmaf(v,v,s); }
        cbn[n] = s;
    }
}

// ---------------- codebook bf16 pack ----------------
__global__ __launch_bounds__(256) void cb_pack(
    const float* __restrict__ cb, unsigned short* __restrict__ cbp) {
    int t = blockIdx.x*256 + threadIdx.x;
    cbp[t] = f2bf(cb[t]);
}

// ---------------- MFMA VQ assign: LDS-staged codebook, 64 rows/block ----------------
__global__ __launch_bounds__(256) void vq_assign_mfma(
    const float* __restrict__ z, const unsigned short* __restrict__ cbp,
    const float* __restrict__ cbn, int* __restrict__ idx) {
    __shared__ __align__(16) unsigned short zb[64*264];
    __shared__ __align__(16) unsigned short cbs[2][32*264];
    __shared__ float cbl[KCB];
    int r0 = blockIdx.x * 64;
    for (int v = threadIdx.x; v < 4096; v += 256) {
        int row = v >> 6, col4 = v & 63;
        float4 u = *(const float4*)&z[(size_t)(r0+row)*256 + col4*4];
        us4 pk = { f2bf(u.x), f2bf(u.y), f2bf(u.z), f2bf(u.w) };
        *(us4*)&zb[row*264 + col4*4] = pk;
    }
    for (int i = threadIdx.x; i < KCB; i += 256) cbl[i] = cbn[i];
    int tcode = threadIdx.x >> 3, tk = threadIdx.x & 7;
    auto STAGE_CB = [&](int c, int bufi) {
        const unsigned short* src = cbp + ((size_t)(c*32 + tcode))*256 + tk*8;
        unsigned short* dst = &cbs[bufi][tcode*264 + tk*8];
        #pragma unroll
        for (int j = 0; j < 4; ++j)
            *(short8*)(dst + j*64) = *(const short8*)(src + j*64);
    };
    STAGE_CB(0, 0);
    __syncthreads();

    int w = threadIdx.x >> 6, l = threadIdx.x & 63;
    int lr = l & 15, lk = l >> 4;
    short8 afr[8];
    #pragma unroll
    for (int ks = 0; ks < 8; ++ks)
        afr[ks] = *(const short8*)&zb[(w*16 + lr)*264 + ks*32 + lk*8];

    float bd[4]; int bi[4];
    #pragma unroll
    for (int r = 0; r < 4; ++r) { bd[r] = 3.0e38f; bi[r] = 0; }

    for (int c = 0; c < 16; ++c) {
        if (c < 15) STAGE_CB(c+1, (c+1)&1);
        const unsigned short* Cb = cbs[c & 1];
        #pragma unroll
        for (int f = 0; f < 2; ++f) {
            f32x4 acc = (f32x4){0.f,0.f,0.f,0.f};
            #pragma unroll
            for (int ks = 0; ks < 8; ++ks) {
                short8 bfr = *(const short8*)&Cb[(f*16 + lr)*264 + ks*32 + lk*8];
                acc = __builtin_amdgcn_mfma_f32_16x16x32_bf16(afr[ks], bfr, acc, 0, 0, 0);
            }
            int n = c*32 + f*16 + lr;
            float cn = cbl[n];
            #pragma unroll
            for (int r = 0; r < 4; ++r) {
                float dist = fmaf(-2.f, acc[r], cn);
                if (dist < bd[r]) { bd[r] = dist; bi[r] = n; }
            }
        }
        __syncthreads();
    }
    #pragma unroll
    for (int r = 0; r < 4; ++r) {
        #pragma unroll
        for (int off = 1; off < 16; off <<= 1) {
            float od = __shfl_xor(bd[r], off, 64);
            int   oi = __shfl_xor(bi[r], off, 64);
            if (od < bd[r] || (od == bd[r] && oi < bi[r])) { bd[r] = od; bi[r] = oi; }
        }
    }
    if (lr == 0) {
        #pragma unroll
        for (int r = 0; r < 4; ++r)
            idx[r0 + w*16 + lk*4 + r] = bi[r];
    }
}

// ---------------- IN-PLACE VQ gather ----------------
__global__ __launch_bounds__(256) void vq_gather(
    float* zq, const float* __restrict__ cb,
    const int* __restrict__ idx, float* __restrict__ sse, int* __restrict__ counts) {
    __shared__ int hist[KCB];
    for (int i = threadIdx.x; i < KCB; i += 256) hist[i] = 0;
    __syncthreads();
    float local = 0.f;
    for (int r = blockIdx.x; r < NROWS; r += GATHER_BLOCKS) {
        int id = idx[r];
        if (threadIdx.x == 0) atomicAdd(&hist[id], 1);
        float qv = cb[(size_t)id*256 + threadIdx.x];
        float* pz = zq + (size_t)r*256 + threadIdx.x;
        float zv = *pz;
        *pz = qv;
        float d = qv - zv;
        local = fmaf(d, d, local);
    }
    __shared__ float lds[4];
    for (int off = 32; off; off >>= 1) local += __shfl_down(local, off, 64);
    if ((threadIdx.x & 63) == 0) lds[threadIdx.x >> 6] = local;
    __syncthreads();
    if (threadIdx.x == 0) atomicAdd(sse, lds[0]+lds[1]+lds[2]+lds[3]);
    for (int i = threadIdx.x; i < KCB; i += 256) {
        int h = hist[i];
        if (h) atomicAdd(counts + i, h);
    }
}

// ---------------- loss + perplexity ----------------
__global__ __launch_bounds__(256) void vq_finalize(
    const float* __restrict__ sse, const int* __restrict__ counts,
    float* __restrict__ out) {
    __shared__ float lds[4];
    float h = 0.f;
    for (int n = threadIdx.x; n < KCB; n += 256) {
        float p = (float)counts[n] * (1.f/123008.f);
        h += p * logf(p + 1e-10f);
    }
    for (int off = 32; off; off >>= 1) h += __shfl_down(h, off, 64);
    if ((threadIdx.x & 63) == 0) lds[threadIdx.x >> 6] = h;
    __syncthreads();
    if (threadIdx.x == 0) {
        out[1572864] = 1.25f * sse[0] / 31490048.f;
        out[1572865] = expf(-(lds[0]+lds[1]+lds[2]+lds[3]));
    }
}

// ---------------- dt2 via parity-split MFMA: block = 32x32 out px, wave = parity ----------------
// Per parity (kh0,kw0): out[2a+kh0, 2b+kw0, co] = sum_{jh,jw,ci} Y[a-jh, b-jw, ci]*W
// Block stages 17x17 halo x 32ci (double-buffered); each wave: 16 N-frags x 4 taps x 8 cc.
__global__ __launch_bounds__(256) void dt2_mfma(
    const unsigned short* __restrict__ Y, const unsigned short* __restrict__ apack,
    const float* __restrict__ bias, float* __restrict__ out) {
    __shared__ __align__(16) unsigned short Iraw[2][289*40];
    int b = blockIdx.y, t = blockIdx.x;
    int a0 = (t >> 2)*16, b0 = (t & 3)*16;
    int p = threadIdx.x >> 6;               // wave = parity
    int l = threadIdx.x & 63;
    int lr = l & 15, lk = l >> 4;
    const unsigned short* src = Y + (size_t)b*HW1*256;

    auto STAGE = [&](int cc, int bufi) {
        #pragma unroll
        for (int pass = 0; pass < 5; ++pass) {
            int u = pass*256 + threadIdx.x;
            if (u < 1156) {                 // 289 sp x 4 quads of 16B
                int sp = u >> 2, q = u & 3;
                int r = (sp*241) >> 12, c = sp - r*17;
                int ia = a0 - 1 + r, ib = b0 - 1 + c;
                short8 v = (short8){0,0,0,0,0,0,0,0};
                if (ia >= 0 && ia < 63 && ib >= 0 && ib < 63)
                    v = *(const short8*)(src + ((size_t)ia*63 + ib)*256 + cc*32 + q*8);
                *(short8*)&Iraw[bufi][sp*40 + q*8] = v;
            }
        }
    };

    f32x4 acc[16];
    #pragma unroll
    for (int i = 0; i < 16; ++i) acc[i] = (f32x4){0.f,0.f,0.f,0.f};

    STAGE(0, 0);
    for (int cc = 0; cc < 8; ++cc) {
        __syncthreads();
        if (cc < 7) STAGE(cc+1, (cc+1)&1);
        const unsigned short* Ib = Iraw[cc & 1];
        #pragma unroll
        for (int j = 0; j < 4; ++j) {       // tap: input (a-jh, b-jw)
            int jh = j >> 1, jw = j & 1;
            short8 af = *(const short8*)(apack +
                ((size_t)((p*8 + cc)*4 + j))*512 + lr*32 + lk*8);
            int sp0 = (1 - jh)*17 + (lr + 1 - jw);
            #pragma unroll
            for (int nf = 0; nf < 16; ++nf) {
                short8 bf = *(const short8*)&Ib[(sp0 + nf*17)*40 + lk*8];
                acc[nf] = __builtin_amdgcn_mfma_f32_16x16x32_bf16(af, bf, acc[nf], 0, 0, 0);
            }
        }
    }
    // epilogue: only lk==0 lanes hold real co (rows 0..2); parity -> strided NCHW out
    if (lk == 0) {
        int kh0 = p >> 1, kw0 = p & 1;
        float bz0 = bias[0], bz1 = bias[1], bz2 = bias[2];
        int wp = 2*(b0 + lr) + kw0;
        #pragma unroll
        for (int nf = 0; nf < 16; ++nf) {
            int h = 2*(a0 + nf) + kh0;
            size_t ob = (size_t)(b*3)*16384 + (size_t)h*128 + wp;
            out[ob]         = acc[nf].x + bz0;
            out[ob + 16384] = acc[nf].y + bz1;
            out[ob + 32768] = acc[nf].z + bz2;
        }
    }
}

// ---------------- launch ----------------
extern "C" void kernel_launch(void* const* d_in, const int* in_sizes, int n_in,
                              void* d_out, int out_size, void* d_ws, size_t ws_size,
                              hipStream_t stream) {
    const float* x      = (const float*)d_in[0];
    const float* ec1_w  = (const float*)d_in[1];
    const float* ec1_b  = (const float*)d_in[2];
    const float* ec2_w  = (const float*)d_in[3];
    const float* ec2_b  = (const float*)d_in[4];
    const float* se1_w1 = (const float*)d_in[5];
    const float* se1_b1 = (const float*)d_in[6];
    const float* se1_w2 = (const float*)d_in[7];
    const float* se1_b2 = (const float*)d_in[8];
    const float* sa1_w  = (const float*)d_in[9];
    const float* se2_w1 = (const float*)d_in[10];
    const float* se2_b1 = (const float*)d_in[11];
    const float* se2_w2 = (const float*)d_in[12];
    const float* se2_b2 = (const float*)d_in[13];
    const float* sa2_w  = (const float*)d_in[14];
    const float* cbk    = (const float*)d_in[15];
    const float* dt1_w  = (const float*)d_in[16];
    const float* dt1_b  = (const float*)d_in[17];
    const float* dt2_w  = (const float*)d_in[18];
    const float* dt2_b  = (const float*)d_in[19];
    const float* dse_w1 = (const float*)d_in[20];
    const float* dse_b1 = (const float*)d_in[21];
    const float* dse_w2 = (const float*)d_in[22];
    const float* dse_b2 = (const float*)d_in[23];
    const float* dsa_w  = (const float*)d_in[24];
    float* out = (float*)d_out;

    float* BIG         = (float*)d_ws;                    // T63 fp32 (130 MB)
    unsigned short* U0 = (unsigned short*)(BIG + T63);    // T63 bf16 (65 MB)
    unsigned short* U1 = U0 + T63;                         // T63 bf16 (65 MB)
    float* pooled = (float*)(U1 + T63);
    float* g      = pooled + 8192;
    float* am     = g + 8192;
    float* ssmap  = am + (size_t)NB*2*HW1;
    float* cbn    = ssmap + (size_t)NB*HW1;
    unsigned short* apackE = (unsigned short*)(cbn + 512);
    unsigned short* apackD = apackE + 262144;
    unsigned short* cbp    = apackD + 262144;
    unsigned short* apackC = cbp + 131072;                 // 16384 ushorts (conv1)
    unsigned short* apack2 = apackC + 16384;               // 65536 ushorts (dt2 MFMA)
    float* sse    = (float*)(apack2 + 65536);
    int*   counts = (int*)(sse + 1);
    int*   idx    = counts + 512;

    // prep
    zero_small<<<1, 256, 0, stream>>>(sse, counts);
    prepack_w<<<1024, 256, 0, stream>>>(ec2_w, apackE, 0);
    prepack_w<<<1024, 256, 0, stream>>>(dt1_w, apackD, 1);
    prepack_c1<<<64, 256, 0, stream>>>(ec1_w, apackC);
    prepack_dt2b<<<256, 256, 0, stream>>>(dt2_w, apack2);
    cb_norm<<<1, 256, 0, stream>>>(cbk, cbn);
    cb_pack<<<512, 256, 0, stream>>>(cbk, cbp);

    // encoder conv1 (MFMA im2col) -> U0 bf16 NHWC; cbam1 on NHWC
    conv1_mfma<<<dim3(64, NB), 256, 0, stream>>>(x, apackC, ec1_b, U0);
    zero_pooled<<<32, 256, 0, stream>>>(pooled);
    gap_nhwc<<<dim3(8, NB), 256, 0, stream>>>(U0, pooled, HW1, 1.f/HW1);
    se_mlp<<<NB, 256, 0, stream>>>(pooled, se1_w1, se1_b1, se1_w2, se1_b2, g);
    chanpool_nhwc<<<dim3(16, NB), 256, 0, stream>>>(U0, g, am, HW1);
    spatial_conv<<<dim3(16, NB), 256, 0, stream>>>(am, sa1_w, ssmap, 63, 63, 0);
    cbam_mul_nhwc<<<dim3(16, NB), 256, 0, stream>>>(U0, g, ssmap, HW1);

    // conv2 (U0 -> BIG fp32 NCHW) + cbam2 NCHW => z in BIG (VQ flat semantics need NCHW)
    convk2_mfma_nhwc<<<dim3(64, NB), 256, 0, stream>>>(U0, apackE, ec2_b, BIG, (unsigned short*)0, 63, 63, 62, 62, 0, 0);
    gap_kernel<<<NB*256, 256, 0, stream>>>(BIG, pooled, HW2);
    se_mlp<<<NB, 256, 0, stream>>>(pooled, se2_w1, se2_b1, se2_w2, se2_b2, g);
    chanpool<<<dim3(16, NB), 256, 0, stream>>>(BIG, g, am, HW2);
    spatial_conv<<<dim3(16, NB), 256, 0, stream>>>(am, sa2_w, ssmap, 62, 62, 0);
    cbam_final<<<dim3(HW2, NB), 256, 0, stream>>>(BIG, g, ssmap, HW2);

    // VQ: z in BIG -> q in BIG (in-place), then q -> U1 bf16 NHWC
    vq_assign_mfma<<<NROWS/64, 256, 0, stream>>>(BIG, cbp, cbn, idx);
    vq_gather<<<GATHER_BLOCKS, 256, 0, stream>>>(BIG, cbk, idx, sse, counts);
    vq_finalize<<<1, 256, 0, stream>>>(sse, counts, out);
    to_nhwc_bf16<<<dim3(16, NB), 256, 0, stream>>>(BIG, U1, HW2);

    // decoder dt1 (U1 -> U0 bf16 NHWC) + cbam3 on NHWC
    convk2_mfma_nhwc<<<dim3(64, NB), 256, 0, stream>>>(U1, apackD, dt1_b, (float*)0, U0, 62, 62, 63, 63, 1, 1);
    zero_pooled<<<32, 256, 0, stream>>>(pooled);
    gap_nhwc<<<dim3(8, NB), 256, 0, stream>>>(U0, pooled, HW1, 1.f/HW1);
    se_mlp<<<NB, 256, 0, stream>>>(pooled, dse_w1, dse_b1, dse_w2, dse_b2, g);
    chanpool_nhwc<<<dim3(16, NB), 256, 0, stream>>>(U0, g, am, HW1);
    spatial_conv<<<dim3(16, NB), 256, 0, stream>>>(am, dsa_w, ssmap, 63, 63, 1);
    cbam_mul_nhwc<<<dim3(16, NB), 256, 0, stream>>>(U0, g, ssmap, HW1);

    // final convT (parity-split MFMA) -> out
    dt2_mfma<<<dim3(16, NB), 256, 0, stream>>>(U0, apack2, dt2_b, out);
}

// Round 12
// 816.951 us; speedup vs baseline: 7.4575x; 1.1196x over previous
//
#include <hip/hip_runtime.h>
#include <math.h>

// ---------------- sizes ----------------
#define NB 32
#define HID 256
#define HW1 (63*63)      // 3969
#define HW2 (62*62)      // 3844
#define T63 ((size_t)NB*HID*HW1)   // 32,514,048
#define T62 ((size_t)NB*HID*HW2)   // 31,490,048
#define NROWS 123008               // T62 / 256
#define KCB 512
#define GATHER_BLOCKS 1024

typedef __attribute__((ext_vector_type(8))) short short8;
typedef __attribute__((ext_vector_type(4))) float f32x4;
typedef __attribute__((ext_vector_type(4))) unsigned short us4;

__device__ __forceinline__ unsigned short f2bf(float f) {
    union { float f; unsigned int u; } v; v.f = f;
    unsigned int u = v.u;
    return (unsigned short)((u + 0x7FFFu + ((u >> 16) & 1u)) >> 16);
}
__device__ __forceinline__ float bf2f(unsigned short u) {
    union { unsigned int i; float f; } v; v.i = ((unsigned int)u) << 16;
    return v.f;
}

// ---------------- zero helpers ----------------
__global__ __launch_bounds__(256) void zero_small(float* __restrict__ sse, int* __restrict__ counts) {
    if (threadIdx.x == 0) sse[0] = 0.f;
    for (int i = threadIdx.x; i < KCB; i += 256) counts[i] = 0;
}
__global__ __launch_bounds__(256) void zero_pooled(float* __restrict__ pooled) {
    pooled[blockIdx.x*256 + threadIdx.x] = 0.f;
}

// ---------------- conv1 weight prepack ----------------
__global__ __launch_bounds__(256) void prepack_c1(
    const float* __restrict__ w, unsigned short* __restrict__ pack) {
    int t = blockIdx.x*256 + threadIdx.x;
    if (t >= 16384) return;
    int j = t & 7, lk = (t >> 3) & 3, co = (t >> 5) & 255, kc = t >> 13;
    int k = kc*32 + lk*8 + j;
    pack[t] = (k < 48) ? f2bf(w[co*48 + k]) : (unsigned short)0;
}

// ---------------- conv1: 3->256, k4, s2, relu -> bf16 NHWC via im2col MFMA ----------------
__global__ __launch_bounds__(256) void conv1_mfma(
    const float* __restrict__ x, const unsigned short* __restrict__ apack,
    const float* __restrict__ bias, unsigned short* __restrict__ X0) {
    __shared__ float xs[3][18][18];
    __shared__ __align__(16) unsigned short Bm[64*72];
    int b = blockIdx.y, t = blockIdx.x;
    int oh0 = (t >> 3)*8, ow0 = (t & 7)*8;
    int ih0 = oh0*2, iw0 = ow0*2;
    const float* xb = x + (size_t)b*3*128*128;
    for (int i = threadIdx.x; i < 972; i += 256) {
        int c = i / 324, rem = i - c*324, r = rem / 18, cl = rem - r*18;
        int ih = ih0 + r, iw = iw0 + cl;
        xs[c][r][cl] = (ih < 128 && iw < 128) ? xb[((size_t)c*128 + ih)*128 + iw] : 0.f;
    }
    __syncthreads();
    for (int i = threadIdx.x; i < 2048; i += 256) {
        int px = i >> 5, kp = (i & 31)*2;
        int ph = px >> 3, pw = px & 7;
        unsigned int pk = 0;
        #pragma unroll
        for (int u = 0; u < 2; ++u) {
            int k = kp + u;
            float v = 0.f;
            if (k < 48) {
                int c = k >> 4, k2 = k & 15, kh = k2 >> 2, kw = k2 & 3;
                v = xs[c][ph*2+kh][pw*2+kw];
            }
            pk |= ((unsigned int)f2bf(v)) << (16*u);
        }
        *(unsigned int*)&Bm[px*72 + kp] = pk;
    }
    __syncthreads();

    int w = threadIdx.x >> 6, l = threadIdx.x & 63;
    int lr = l & 15, lk = l >> 4;
    f32x4 acc[4][4];
    #pragma unroll
    for (int i = 0; i < 4; ++i)
        #pragma unroll
        for (int j = 0; j < 4; ++j) acc[i][j] = (f32x4){0.f,0.f,0.f,0.f};

    #pragma unroll
    for (int kc = 0; kc < 2; ++kc) {
        short8 bf[4];
        #pragma unroll
        for (int pxf = 0; pxf < 4; ++pxf)
            bf[pxf] = *(const short8*)&Bm[(pxf*16+lr)*72 + kc*32 + lk*8];
        #pragma unroll
        for (int cof = 0; cof < 4; ++cof) {
            int co = w*64 + cof*16 + lr;
            short8 af = *(const short8*)(apack + (((size_t)kc*256 + co)*4 + (size_t)lk)*8);
            acc[cof][0] = __builtin_amdgcn_mfma_f32_16x16x32_bf16(af, bf[0], acc[cof][0], 0, 0, 0);
            acc[cof][1] = __builtin_amdgcn_mfma_f32_16x16x32_bf16(af, bf[1], acc[cof][1], 0, 0, 0);
            acc[cof][2] = __builtin_amdgcn_mfma_f32_16x16x32_bf16(af, bf[2], acc[cof][2], 0, 0, 0);
            acc[cof][3] = __builtin_amdgcn_mfma_f32_16x16x32_bf16(af, bf[3], acc[cof][3], 0, 0, 0);
        }
    }
    #pragma unroll
    for (int cof = 0; cof < 4; ++cof) {
        int cob = w*64 + cof*16 + lk*4;
        float4 bz = *(const float4*)&bias[cob];
        #pragma unroll
        for (int pxf = 0; pxf < 4; ++pxf) {
            int px = pxf*16 + lr;
            int oh = oh0 + (px >> 3), ow = ow0 + (px & 7);
            if (oh < 63 && ow < 63) {
                f32x4 a = acc[cof][pxf];
                us4 pk = { f2bf(fmaxf(a.x + bz.x, 0.f)), f2bf(fmaxf(a.y + bz.y, 0.f)),
                           f2bf(fmaxf(a.z + bz.z, 0.f)), f2bf(fmaxf(a.w + bz.w, 0.f)) };
                *(us4*)(X0 + ((size_t)b*HW1 + (size_t)oh*63 + ow)*256 + cob) = pk;
            }
        }
    }
}

// ---------------- gap over NHWC bf16 (atomic accumulate; pooled pre-zeroed) ----------------
__global__ __launch_bounds__(256) void gap_nhwc(
    const unsigned short* __restrict__ X, float* __restrict__ pooled,
    int HW, float inv) {
    int b = blockIdx.y;
    int px0 = blockIdx.x * 512;
    int o = threadIdx.x & 31, pg = threadIdx.x >> 5;
    const unsigned short* xb = X + (size_t)b*HW*256 + o*8;
    float acc[8];
    #pragma unroll
    for (int j = 0; j < 8; ++j) acc[j] = 0.f;
    for (int i = 0; i < 64; ++i) {
        int px = px0 + pg + i*8;
        if (px < HW) {
            short8 v = *(const short8*)(xb + (size_t)px*256);
            #pragma unroll
            for (int j = 0; j < 8; ++j) acc[j] += bf2f((unsigned short)v[j]);
        }
    }
    __shared__ float pool2[8][256];
    #pragma unroll
    for (int j = 0; j < 8; ++j) pool2[pg][o*8+j] = acc[j];
    __syncthreads();
    float s = 0.f;
    #pragma unroll
    for (int p = 0; p < 8; ++p) s += pool2[p][threadIdx.x];
    atomicAdd(pooled + b*256 + threadIdx.x, s * inv);
}

// ---------------- gap over bf16 NCHW (encoder-2 z) ----------------
__global__ __launch_bounds__(256) void gap_z(
    const unsigned short* __restrict__ Z, float* __restrict__ pooled, int HW) {
    int bc = blockIdx.x;
    const unsigned int* p = (const unsigned int*)(Z + (size_t)bc*HW);
    int n2 = HW >> 1;
    float s = 0.f;
    for (int i = threadIdx.x; i < n2; i += 256) {
        unsigned int v = p[i];
        s += bf2f((unsigned short)(v & 0xffff)) + bf2f((unsigned short)(v >> 16));
    }
    __shared__ float lds[4];
    for (int off = 32; off; off >>= 1) s += __shfl_down(s, off, 64);
    if ((threadIdx.x & 63) == 0) lds[threadIdx.x >> 6] = s;
    __syncthreads();
    if (threadIdx.x == 0) pooled[bc] = (lds[0]+lds[1]+lds[2]+lds[3]) / (float)HW;
}

// ---------------- SE MLP ----------------
__global__ __launch_bounds__(256) void se_mlp(
    const float* __restrict__ pooled, const float* __restrict__ w1,
    const float* __restrict__ b1, const float* __restrict__ w2,
    const float* __restrict__ b2, float* __restrict__ g) {
    int b = blockIdx.x;
    __shared__ float ps[256], hs[16];
    ps[threadIdx.x] = pooled[b*256 + threadIdx.x];
    __syncthreads();
    if (threadIdx.x < 16) {
        float a = b1[threadIdx.x];
        const float* wr = w1 + threadIdx.x*256;
        for (int k = 0; k < 256; ++k) a = fmaf(ps[k], wr[k], a);
        hs[threadIdx.x] = fmaxf(a, 0.f);
    }
    __syncthreads();
    float a = b2[threadIdx.x];
    const float* wr = w2 + threadIdx.x*16;
    #pragma unroll
    for (int j = 0; j < 16; ++j) a = fmaf(hs[j], wr[j], a);
    g[b*256 + threadIdx.x] = 1.f / (1.f + expf(-a));
}

// ---------------- channel mean/max of x*g (NHWC bf16) ----------------
__global__ __launch_bounds__(256) void chanpool_nhwc(
    const unsigned short* __restrict__ X, const float* __restrict__ g,
    float* __restrict__ am, int HW) {
    int b = blockIdx.y;
    __shared__ float gs[256];
    gs[threadIdx.x] = g[b*256 + threadIdx.x];
    __syncthreads();
    int p = blockIdx.x*256 + threadIdx.x;
    if (p >= HW) return;
    const unsigned short* xp = X + ((size_t)b*HW + p)*256;
    float s = 0.f, mx = -3.0e38f;
    for (int o = 0; o < 32; ++o) {
        short8 v = *(const short8*)(xp + o*8);
        #pragma unroll
        for (int j = 0; j < 8; ++j) {
            float f = bf2f((unsigned short)v[j]) * gs[o*8+j];
            s += f; mx = fmaxf(mx, f);
        }
    }
    am[((size_t)b*2)*HW + p]   = s * (1.f/256.f);
    am[((size_t)b*2+1)*HW + p] = mx;
}

// ---------------- channel mean/max of x*g (bf16 NCHW, encoder-2 z) ----------------
__global__ __launch_bounds__(256) void chanpool_z(
    const unsigned short* __restrict__ Z, const float* __restrict__ g,
    float* __restrict__ am, int HW) {
    int b = blockIdx.y;
    __shared__ float gs[256];
    gs[threadIdx.x] = g[b*256 + threadIdx.x];
    __syncthreads();
    int p = blockIdx.x*256 + threadIdx.x;
    if (p >= HW) return;
    const unsigned short* xb = Z + (size_t)b*256*HW + p;
    float s = 0.f, mx = -3.0e38f;
    for (int c = 0; c < 256; ++c) {
        float v = bf2f(xb[(size_t)c*HW]) * gs[c];
        s += v; mx = fmaxf(mx, v);
    }
    am[((size_t)b*2)*HW + p]   = s * (1.f/256.f);
    am[((size_t)b*2+1)*HW + p] = mx;
}

// ---------------- 7x7 spatial conv on [mean,max], sigmoid ----------------
__global__ __launch_bounds__(256) void spatial_conv(
    const float* __restrict__ am, const float* __restrict__ sw,
    float* __restrict__ ss, int H, int W, int transpose) {
    int b = blockIdx.y;
    int p = blockIdx.x*256 + threadIdx.x;
    __shared__ float ws[98];
    if (threadIdx.x < 98) {
        int c = threadIdx.x / 49, k = threadIdx.x % 49;
        int kh = k / 7, kw = k % 7;
        ws[threadIdx.x] = transpose ? sw[c*49 + (6-kh)*7 + (6-kw)]
                                    : sw[c*49 + kh*7 + kw];
    }
    __syncthreads();
    if (p >= H*W) return;
    int oh = p / W, ow = p % W;
    float acc = 0.f;
    #pragma unroll
    for (int c = 0; c < 2; ++c) {
        const float* ab = am + ((size_t)b*2 + c)*H*W;
        for (int kh = 0; kh < 7; ++kh) {
            int ih = oh + kh - 3;
            if (ih < 0 || ih >= H) continue;
            for (int kw = 0; kw < 7; ++kw) {
                int iw = ow + kw - 3;
                if (iw < 0 || iw >= W) continue;
                acc = fmaf(ab[(size_t)ih*W + iw], ws[c*49 + kh*7 + kw], acc);
            }
        }
    }
    ss[(size_t)b*H*W + p] = 1.f / (1.f + expf(-acc));
}

// ---------------- IN-PLACE NHWC bf16: x = x*x*g*sig(s) ----------------
__global__ __launch_bounds__(256) void cbam_mul_nhwc(
    unsigned short* X, const float* __restrict__ g,
    const float* __restrict__ ss, int HW) {
    int b = blockIdx.y;
    __shared__ float gs[256];
    gs[threadIdx.x] = g[b*256 + threadIdx.x];
    __syncthreads();
    int p = blockIdx.x*256 + threadIdx.x;
    if (p >= HW) return;
    float sv = ss[(size_t)b*HW + p];
    unsigned short* xp = X + ((size_t)b*HW + p)*256;
    for (int o = 0; o < 32; ++o) {
        short8 v = *(const short8*)(xp + o*8);
        unsigned int pk[4];
        #pragma unroll
        for (int j = 0; j < 4; ++j) {
            float f0 = bf2f((unsigned short)v[2*j]);
            float f1 = bf2f((unsigned short)v[2*j+1]);
            f0 = f0*f0*gs[o*8+2*j]*sv;
            f1 = f1*f1*gs[o*8+2*j+1]*sv;
            pk[j] = (unsigned int)f2bf(f0) | ((unsigned int)f2bf(f1) << 16);
        }
        *(short8*)(xp + o*8) = *(const short8*)pk;
    }
}

// ---------------- IN-PLACE bf16 NCHW: z = z*z*g*sig(s) (encoder-2) ----------------
__global__ __launch_bounds__(256) void cbam_z(
    unsigned short* Z, const float* __restrict__ g,
    const float* __restrict__ ss, int HW) {
    int b = blockIdx.y;
    int e2 = blockIdx.x*256 + threadIdx.x;
    if (e2 >= 128*HW) return;
    size_t e = (size_t)e2*2;
    int c = (int)(e / HW), p = (int)(e % HW);
    float gc = g[b*256 + c];
    float s0 = ss[(size_t)b*HW + p];
    float s1 = ss[(size_t)b*HW + p + 1];
    unsigned int* px = (unsigned int*)(Z + (size_t)b*256*HW + e);
    unsigned int v = *px;
    float f0 = bf2f((unsigned short)(v & 0xffff));
    float f1 = bf2f((unsigned short)(v >> 16));
    f0 = f0*f0*gc*s0;
    f1 = f1*f1*gc*s1;
    *px = (unsigned int)f2bf(f0) | ((unsigned int)f2bf(f1) << 16);
}

// ---------------- bf16 NCHW -> NHWC bf16 (q after VQ) ----------------
__global__ __launch_bounds__(256) void to_nhwc_bf16(
    const unsigned short* __restrict__ Z, unsigned short* __restrict__ X, int HW) {
    int b = blockIdx.y;
    int p = blockIdx.x*256 + threadIdx.x;
    bool valid = p < HW;
    const unsigned short* inb = Z + (size_t)b*256*HW + p;
    unsigned short* dst = X + ((size_t)b*HW + p)*256;
    #pragma unroll
    for (int ch = 0; ch < 4; ++ch) {
        unsigned short buf[64];
        #pragma unroll
        for (int j = 0; j < 64; ++j)
            buf[j] = valid ? inb[(size_t)(ch*64 + j)*HW] : (unsigned short)0;
        if (valid) {
            #pragma unroll
            for (int j2 = 0; j2 < 8; ++j2)
                *(short8*)(dst + ch*64 + j2*8) = *(const short8*)&buf[j2*8];
        }
    }
}

// ---------------- weight prepack into MFMA-fragment layout (bf16) ----------------
__global__ __launch_bounds__(256) void prepack_w(
    const float* __restrict__ w, unsigned short* __restrict__ pack, int transpose_flip) {
    int t = blockIdx.x*256 + threadIdx.x;
    int j = t & 7, koct = (t >> 3) & 3, co = (t >> 5) & 255, tap = (t >> 13) & 3, cc = t >> 15;
    int ci = cc*32 + koct*8 + j;
    int kh = tap >> 1, kw = tap & 1;
    float v;
    if (transpose_flip) v = w[((size_t)ci*256 + co)*4 + (1-kh)*2 + (1-kw)];
    else                v = w[((size_t)co*256 + ci)*4 + kh*2 + kw];
    pack[t] = f2bf(v);
}

// ---------------- dt2 weight prepack (MFMA A-frag) ----------------
__global__ __launch_bounds__(256) void prepack_dt2b(
    const float* __restrict__ w, unsigned short* __restrict__ pk) {
    int t = blockIdx.x*256 + threadIdx.x;
    int jj = t & 7, lk = (t >> 3) & 3, co = (t >> 5) & 15, j = (t >> 9) & 3, cc = (t >> 11) & 7, p = t >> 14;
    int ci = cc*32 + lk*8 + jj;
    int kh0 = p >> 1, kw0 = p & 1;
    const int dj[4] = {0, 2, 8, 10};
    float v = 0.f;
    if (co < 3) v = w[(size_t)ci*48 + co*16 + kh0*4 + kw0 + dj[j]];
    pk[t] = f2bf(v);
}

// ---------------- MFMA conv k=2 s=1, NHWC bf16 input ----------------
// MODE 0: bf16 NCHW out (conv2 -> z). MODE 1: bf16 NHWC out via LDS-staged epilogue (dt1).
template <int MODE>
__global__ __launch_bounds__(256) void convk2_mfma_nhwc(
    const unsigned short* __restrict__ Xin, const unsigned short* __restrict__ apack,
    const float* __restrict__ bias, unsigned short* __restrict__ outZ,
    unsigned short* __restrict__ outU,
    int inH, int inW, int outH, int outW, int pad) {
    __shared__ __align__(16) unsigned short Sh[MODE ? 16896 : 6800];
    unsigned short* Ir0 = Sh;
    unsigned short* Ir1 = Sh + 3400;
    int b = blockIdx.y;
    int t = blockIdx.x;
    int oh0 = (t >> 2) * 4, ow0 = (t & 3) * 16;
    int w = threadIdx.x >> 6, l = threadIdx.x & 63;
    int lr = l & 15, lk = l >> 4;
    const unsigned short* src = Xin + (size_t)b*inH*inW*256;

    f32x4 acc[4][4];
    #pragma unroll
    for (int i = 0; i < 4; ++i)
        #pragma unroll
        for (int j = 0; j < 4; ++j) acc[i][j] = (f32x4){0.f,0.f,0.f,0.f};

    auto STAGE = [&](int cc, int bufi) {
        unsigned short* Ib = bufi ? Ir1 : Ir0;
        #pragma unroll
        for (int pass = 0; pass < 2; ++pass) {
            int u = pass*256 + threadIdx.x;
            if (u < 340) {
                int sp = u >> 2, q = u & 3;
                int r = (sp*241) >> 12, c = sp - r*17;
                int gh = oh0 + r - pad, gw = ow0 + c - pad;
                short8 v = (short8){0,0,0,0,0,0,0,0};
                if (gh >= 0 && gh < inH && gw >= 0 && gw < inW)
                    v = *(const short8*)(src + ((size_t)gh*inW + gw)*256 + cc*32 + q*8);
                *(short8*)&Ib[sp*40 + q*8] = v;
            }
        }
    };

    STAGE(0, 0);
    for (int cc = 0; cc < 8; ++cc) {
        __syncthreads();
        if (cc < 7) STAGE(cc+1, (cc+1)&1);
        const unsigned short* Ib = (cc & 1) ? Ir1 : Ir0;
        #pragma unroll
        for (int tap = 0; tap < 4; ++tap) {
            int kh = tap >> 1, kw = tap & 1;
            int spb = kh*17 + kw + lr;
            short8 b0 = *(const short8*)&Ib[(spb     )*40 + lk*8];
            short8 b1 = *(const short8*)&Ib[(spb + 17)*40 + lk*8];
            short8 b2 = *(const short8*)&Ib[(spb + 34)*40 + lk*8];
            short8 b3 = *(const short8*)&Ib[(spb + 51)*40 + lk*8];
            const unsigned short* abase = apack + (((size_t)(cc*4 + tap)*256)*4 + (size_t)lk)*8;
            #pragma unroll
            for (int cof = 0; cof < 4; ++cof) {
                int co = w*64 + cof*16 + lr;
                short8 af = *(const short8*)(abase + (size_t)co*32);
                acc[cof][0] = __builtin_amdgcn_mfma_f32_16x16x32_bf16(af, b0, acc[cof][0], 0, 0, 0);
                acc[cof][1] = __builtin_amdgcn_mfma_f32_16x16x32_bf16(af, b1, acc[cof][1], 0, 0, 0);
                acc[cof][2] = __builtin_amdgcn_mfma_f32_16x16x32_bf16(af, b2, acc[cof][2], 0, 0, 0);
                acc[cof][3] = __builtin_amdgcn_mfma_f32_16x16x32_bf16(af, b3, acc[cof][3], 0, 0, 0);
            }
        }
    }
    if (MODE == 0) {
        int ow = ow0 + lr;
        #pragma unroll
        for (int cof = 0; cof < 4; ++cof) {
            int cob = w*64 + cof*16 + lk*4;
            float4 bz = *(const float4*)&bias[cob];
            #pragma unroll
            for (int pxf = 0; pxf < 4; ++pxf) {
                int oh = oh0 + pxf;
                if (oh < outH && ow < outW) {
                    f32x4 a = acc[cof][pxf];
                    size_t base = ((size_t)(b*256 + cob)*outH + oh)*outW + ow;
                    size_t st = (size_t)outH*outW;
                    outZ[base]        = f2bf(fmaxf(a.x + bz.x, 0.f));
                    outZ[base +   st] = f2bf(fmaxf(a.y + bz.y, 0.f));
                    outZ[base + 2*st] = f2bf(fmaxf(a.z + bz.z, 0.f));
                    outZ[base + 3*st] = f2bf(fmaxf(a.w + bz.w, 0.f));
                }
            }
        }
    } else {
        // stage block output tile (64 px x 256 co) in LDS, then contiguous NHWC writes
        __syncthreads();
        #pragma unroll
        for (int cof = 0; cof < 4; ++cof) {
            int cob = w*64 + cof*16 + lk*4;
            float4 bz = *(const float4*)&bias[cob];
            #pragma unroll
            for (int pxf = 0; pxf < 4; ++pxf) {
                f32x4 a = acc[cof][pxf];
                us4 pk = { f2bf(fmaxf(a.x + bz.x, 0.f)), f2bf(fmaxf(a.y + bz.y, 0.f)),
                           f2bf(fmaxf(a.z + bz.z, 0.f)), f2bf(fmaxf(a.w + bz.w, 0.f)) };
                *(us4*)&Sh[(pxf*16 + lr)*264 + cob] = pk;
            }
        }
        __syncthreads();
        int owp = threadIdx.x >> 4, c0 = (threadIdx.x & 15)*16;
        int ow = ow0 + owp;
        #pragma unroll
        for (int row = 0; row < 4; ++row) {
            int oh = oh0 + row;
            if (oh < outH && ow < outW) {
                unsigned short* dst = outU + (((size_t)b*outH + oh)*outW + ow)*256 + c0;
                *(short8*)dst       = *(const short8*)&Sh[(row*16 + owp)*264 + c0];
                *(short8*)(dst + 8) = *(const short8*)&Sh[(row*16 + owp)*264 + c0 + 8];
            }
        }
    }
}

// ---------------- codebook norms ----------------
__global__ __launch_bounds__(256) void cb_norm(
    const float* __restrict__ cb, float* __restrict__ cbn) {
    for (int n = threadIdx.x; n < KCB; n += 256) {
        float s = 0.f;
        for (int k = 0; k < 256; ++k) { float v = cb[(size_t)n*256+k]; s = fmaf(v,v,s); }
        cbn[n] = s;
    }
}

// ---------------- codebook bf16 pack ----------------
__global__ __launch_bounds__(256) void cb_pack(
    const float* __restrict__ cb, unsigned short* __restrict__ cbp) {
    int t = blockIdx.x*256 + threadIdx.x;
    cbp[t] = f2bf(cb[t]);
}

// ---------------- MFMA VQ assign: bf16 z, LDS-staged codebook, 64 rows/block ----------------
__global__ __launch_bounds__(256) void vq_assign_mfma(
    const unsigned short* __restrict__ z, const unsigned short* __restrict__ cbp,
    const float* __restrict__ cbn, int* __restrict__ idx) {
    __shared__ __align__(16) unsigned short zb[64*264];
    __shared__ __align__(16) unsigned short cbs[2][32*264];
    __shared__ float cbl[KCB];
    int r0 = blockIdx.x * 64;
    for (int v = threadIdx.x; v < 2048; v += 256) {
        int row = v >> 5, o = v & 31;
        *(short8*)&zb[row*264 + o*8] = *(const short8*)&z[(size_t)(r0+row)*256 + o*8];
    }
    for (int i = threadIdx.x; i < KCB; i += 256) cbl[i] = cbn[i];
    int tcode = threadIdx.x >> 3, tk = threadIdx.x & 7;
    auto STAGE_CB = [&](int c, int bufi) {
        const unsigned short* src = cbp + ((size_t)(c*32 + tcode))*256 + tk*8;
        unsigned short* dst = &cbs[bufi][tcode*264 + tk*8];
        #pragma unroll
        for (int j = 0; j < 4; ++j)
            *(short8*)(dst + j*64) = *(const short8*)(src + j*64);
    };
    STAGE_CB(0, 0);
    __syncthreads();

    int w = threadIdx.x >> 6, l = threadIdx.x & 63;
    int lr = l & 15, lk = l >> 4;
    short8 afr[8];
    #pragma unroll
    for (int ks = 0; ks < 8; ++ks)
        afr[ks] = *(const short8*)&zb[(w*16 + lr)*264 + ks*32 + lk*8];

    float bd[4]; int bi[4];
    #pragma unroll
    for (int r = 0; r < 4; ++r) { bd[r] = 3.0e38f; bi[r] = 0; }

    for (int c = 0; c < 16; ++c) {
        if (c < 15) STAGE_CB(c+1, (c+1)&1);
        const unsigned short* Cb = cbs[c & 1];
        #pragma unroll
        for (int f = 0; f < 2; ++f) {
            f32x4 acc = (f32x4){0.f,0.f,0.f,0.f};
            #pragma unroll
            for (int ks = 0; ks < 8; ++ks) {
                short8 bfr = *(const short8*)&Cb[(f*16 + lr)*264 + ks*32 + lk*8];
                acc = __builtin_amdgcn_mfma_f32_16x16x32_bf16(afr[ks], bfr, acc, 0, 0, 0);
            }
            int n = c*32 + f*16 + lr;
            float cn = cbl[n];
            #pragma unroll
            for (int r = 0; r < 4; ++r) {
                float dist = fmaf(-2.f, acc[r], cn);
                if (dist < bd[r]) { bd[r] = dist; bi[r] = n; }
            }
        }
        __syncthreads();
    }
    #pragma unroll
    for (int r = 0; r < 4; ++r) {
        #pragma unroll
        for (int off = 1; off < 16; off <<= 1) {
            float od = __shfl_xor(bd[r], off, 64);
            int   oi = __shfl_xor(bi[r], off, 64);
            if (od < bd[r] || (od == bd[r] && oi < bi[r])) { bd[r] = od; bi[r] = oi; }
        }
    }
    if (lr == 0) {
        #pragma unroll
        for (int r = 0; r < 4; ++r)
            idx[r0 + w*16 + lk*4 + r] = bi[r];
    }
}

// ---------------- IN-PLACE VQ gather (bf16 z -> bf16 q) ----------------
__global__ __launch_bounds__(256) void vq_gather(
    unsigned short* zq, const float* __restrict__ cb,
    const int* __restrict__ idx, float* __restrict__ sse, int* __restrict__ counts) {
    __shared__ int hist[KCB];
    for (int i = threadIdx.x; i < KCB; i += 256) hist[i] = 0;
    __syncthreads();
    float local = 0.f;
    for (int r = blockIdx.x; r < NROWS; r += GATHER_BLOCKS) {
        int id = idx[r];
        if (threadIdx.x == 0) atomicAdd(&hist[id], 1);
        float qv = cb[(size_t)id*256 + threadIdx.x];
        unsigned short* pz = zq + (size_t)r*256 + threadIdx.x;
        float zv = bf2f(*pz);
        *pz = f2bf(qv);
        float d = qv - zv;
        local = fmaf(d, d, local);
    }
    __shared__ float lds[4];
    for (int off = 32; off; off >>= 1) local += __shfl_down(local, off, 64);
    if ((threadIdx.x & 63) == 0) lds[threadIdx.x >> 6] = local;
    __syncthreads();
    if (threadIdx.x == 0) atomicAdd(sse, lds[0]+lds[1]+lds[2]+lds[3]);
    for (int i = threadIdx.x; i < KCB; i += 256) {
        int h = hist[i];
        if (h) atomicAdd(counts + i, h);
    }
}

// ---------------- loss + perplexity ----------------
__global__ __launch_bounds__(256) void vq_finalize(
    const float* __restrict__ sse, const int* __restrict__ counts,
    float* __restrict__ out) {
    __shared__ float lds[4];
    float h = 0.f;
    for (int n = threadIdx.x; n < KCB; n += 256) {
        float p = (float)counts[n] * (1.f/123008.f);
        h += p * logf(p + 1e-10f);
    }
    for (int off = 32; off; off >>= 1) h += __shfl_down(h, off, 64);
    if ((threadIdx.x & 63) == 0) lds[threadIdx.x >> 6] = h;
    __syncthreads();
    if (threadIdx.x == 0) {
        out[1572864] = 1.25f * sse[0] / 31490048.f;
        out[1572865] = expf(-(lds[0]+lds[1]+lds[2]+lds[3]));
    }
}

// ---------------- dt2 via parity-split MFMA ----------------
__global__ __launch_bounds__(256) void dt2_mfma(
    const unsigned short* __restrict__ Y, const unsigned short* __restrict__ apack,
    const float* __restrict__ bias, float* __restrict__ out) {
    __shared__ __align__(16) unsigned short Iraw[2][289*40];
    int b = blockIdx.y, t = blockIdx.x;
    int a0 = (t >> 2)*16, b0 = (t & 3)*16;
    int p = threadIdx.x >> 6;
    int l = threadIdx.x & 63;
    int lr = l & 15, lk = l >> 4;
    const unsigned short* src = Y + (size_t)b*HW1*256;

    auto STAGE = [&](int cc, int bufi) {
        #pragma unroll
        for (int pass = 0; pass < 5; ++pass) {
            int u = pass*256 + threadIdx.x;
            if (u < 1156) {
                int sp = u >> 2, q = u & 3;
                int r = (sp*241) >> 12, c = sp - r*17;
                int ia = a0 - 1 + r, ib = b0 - 1 + c;
                short8 v = (short8){0,0,0,0,0,0,0,0};
                if (ia >= 0 && ia < 63 && ib >= 0 && ib < 63)
                    v = *(const short8*)(src + ((size_t)ia*63 + ib)*256 + cc*32 + q*8);
                *(short8*)&Iraw[bufi][sp*40 + q*8] = v;
            }
        }
    };

    f32x4 acc[16];
    #pragma unroll
    for (int i = 0; i < 16; ++i) acc[i] = (f32x4){0.f,0.f,0.f,0.f};

    STAGE(0, 0);
    for (int cc = 0; cc < 8; ++cc) {
        __syncthreads();
        if (cc < 7) STAGE(cc+1, (cc+1)&1);
        const unsigned short* Ib = Iraw[cc & 1];
        #pragma unroll
        for (int j = 0; j < 4; ++j) {
            int jh = j >> 1, jw = j & 1;
            short8 af = *(const short8*)(apack +
                ((size_t)((p*8 + cc)*4 + j))*512 + lr*32 + lk*8);
            int sp0 = (1 - jh)*17 + (lr + 1 - jw);
            #pragma unroll
            for (int nf = 0; nf < 16; ++nf) {
                short8 bf = *(const short8*)&Ib[(sp0 + nf*17)*40 + lk*8];
                acc[nf] = __builtin_amdgcn_mfma_f32_16x16x32_bf16(af, bf, acc[nf], 0, 0, 0);
            }
        }
    }
    if (lk == 0) {
        int kh0 = p >> 1, kw0 = p & 1;
        float bz0 = bias[0], bz1 = bias[1], bz2 = bias[2];
        int wp = 2*(b0 + lr) + kw0;
        #pragma unroll
        for (int nf = 0; nf < 16; ++nf) {
            int h = 2*(a0 + nf) + kh0;
            size_t ob = (size_t)(b*3)*16384 + (size_t)h*128 + wp;
            out[ob]         = acc[nf].x + bz0;
            out[ob + 16384] = acc[nf].y + bz1;
            out[ob + 32768] = acc[nf].z + bz2;
        }
    }
}

// ---------------- launch ----------------
extern "C" void kernel_launch(void* const* d_in, const int* in_sizes, int n_in,
                              void* d_out, int out_size, void* d_ws, size_t ws_size,
                              hipStream_t stream) {
    const float* x      = (const float*)d_in[0];
    const float* ec1_w  = (const float*)d_in[1];
    const float* ec1_b  = (const float*)d_in[2];
    const float* ec2_w  = (const float*)d_in[3];
    const float* ec2_b  = (const float*)d_in[4];
    const float* se1_w1 = (const float*)d_in[5];
    const float* se1_b1 = (const float*)d_in[6];
    const float* se1_w2 = (const float*)d_in[7];
    const float* se1_b2 = (const float*)d_in[8];
    const float* sa1_w  = (const float*)d_in[9];
    const float* se2_w1 = (const float*)d_in[10];
    const float* se2_b1 = (const float*)d_in[11];
    const float* se2_w2 = (const float*)d_in[12];
    const float* se2_b2 = (const float*)d_in[13];
    const float* sa2_w  = (const float*)d_in[14];
    const float* cbk    = (const float*)d_in[15];
    const float* dt1_w  = (const float*)d_in[16];
    const float* dt1_b  = (const float*)d_in[17];
    const float* dt2_w  = (const float*)d_in[18];
    const float* dt2_b  = (const float*)d_in[19];
    const float* dse_w1 = (const float*)d_in[20];
    const float* dse_b1 = (const float*)d_in[21];
    const float* dse_w2 = (const float*)d_in[22];
    const float* dse_b2 = (const float*)d_in[23];
    const float* dsa_w  = (const float*)d_in[24];
    float* out = (float*)d_out;

    unsigned short* Zb = (unsigned short*)d_ws;           // T62 bf16 NCHW z/q (63 MB)
    unsigned short* U0 = Zb + T62;                         // T63 bf16 NHWC (65 MB)
    unsigned short* U1 = U0 + T63;                         // T63 bf16 NHWC (65 MB)
    float* pooled = (float*)(U1 + T63);
    float* g      = pooled + 8192;
    float* am     = g + 8192;
    float* ssmap  = am + (size_t)NB*2*HW1;
    float* cbn    = ssmap + (size_t)NB*HW1;
    unsigned short* apackE = (unsigned short*)(cbn + 512);
    unsigned short* apackD = apackE + 262144;
    unsigned short* cbp    = apackD + 262144;
    unsigned short* apackC = cbp + 131072;
    unsigned short* apack2 = apackC + 16384;
    float* sse    = (float*)(apack2 + 65536);
    int*   counts = (int*)(sse + 1);
    int*   idx    = counts + 512;

    // prep
    zero_small<<<1, 256, 0, stream>>>(sse, counts);
    prepack_w<<<1024, 256, 0, stream>>>(ec2_w, apackE, 0);
    prepack_w<<<1024, 256, 0, stream>>>(dt1_w, apackD, 1);
    prepack_c1<<<64, 256, 0, stream>>>(ec1_w, apackC);
    prepack_dt2b<<<256, 256, 0, stream>>>(dt2_w, apack2);
    cb_norm<<<1, 256, 0, stream>>>(cbk, cbn);
    cb_pack<<<512, 256, 0, stream>>>(cbk, cbp);

    // encoder conv1 (MFMA im2col) -> U0 bf16 NHWC; cbam1 on NHWC
    conv1_mfma<<<dim3(64, NB), 256, 0, stream>>>(x, apackC, ec1_b, U0);
    zero_pooled<<<32, 256, 0, stream>>>(pooled);
    gap_nhwc<<<dim3(8, NB), 256, 0, stream>>>(U0, pooled, HW1, 1.f/HW1);
    se_mlp<<<NB, 256, 0, stream>>>(pooled, se1_w1, se1_b1, se1_w2, se1_b2, g);
    chanpool_nhwc<<<dim3(16, NB), 256, 0, stream>>>(U0, g, am, HW1);
    spatial_conv<<<dim3(16, NB), 256, 0, stream>>>(am, sa1_w, ssmap, 63, 63, 0);
    cbam_mul_nhwc<<<dim3(16, NB), 256, 0, stream>>>(U0, g, ssmap, HW1);

    // conv2 (U0 -> Zb bf16 NCHW) + cbam2 on bf16 NCHW => z in Zb
    convk2_mfma_nhwc<0><<<dim3(64, NB), 256, 0, stream>>>(U0, apackE, ec2_b, Zb, (unsigned short*)0, 63, 63, 62, 62, 0);
    gap_z<<<NB*256, 256, 0, stream>>>(Zb, pooled, HW2);
    se_mlp<<<NB, 256, 0, stream>>>(pooled, se2_w1, se2_b1, se2_w2, se2_b2, g);
    chanpool_z<<<dim3(16, NB), 256, 0, stream>>>(Zb, g, am, HW2);
    spatial_conv<<<dim3(16, NB), 256, 0, stream>>>(am, sa2_w, ssmap, 62, 62, 0);
    cbam_z<<<dim3(1922, NB), 256, 0, stream>>>(Zb, g, ssmap, HW2);

    // VQ: z in Zb -> q in Zb (in-place bf16), then q -> U1 bf16 NHWC
    vq_assign_mfma<<<NROWS/64, 256, 0, stream>>>(Zb, cbp, cbn, idx);
    vq_gather<<<GATHER_BLOCKS, 256, 0, stream>>>(Zb, cbk, idx, sse, counts);
    vq_finalize<<<1, 256, 0, stream>>>(sse, counts, out);
    to_nhwc_bf16<<<dim3(16, NB), 256, 0, stream>>>(Zb, U1, HW2);

    // decoder dt1 (U1 -> U0 bf16 NHWC, LDS-staged epilogue) + cbam3 on NHWC
    convk2_mfma_nhwc<1><<<dim3(64, NB), 256, 0, stream>>>(U1, apackD, dt1_b, (unsigned short*)0, U0, 62, 62, 63, 63, 1);
    zero_pooled<<<32, 256, 0, stream>>>(pooled);
    gap_nhwc<<<dim3(8, NB), 256, 0, stream>>>(U0, pooled, HW1, 1.f/HW1);
    se_mlp<<<NB, 256, 0, stream>>>(pooled, dse_w1, dse_b1, dse_w2, dse_b2, g);
    chanpool_nhwc<<<dim3(16, NB), 256, 0, stream>>>(U0, g, am, HW1);
    spatial_conv<<<dim3(16, NB), 256, 0, stream>>>(am, dsa_w, ssmap, 63, 63, 1);
    cbam_mul_nhwc<<<dim3(16, NB), 256, 0, stream>>>(U0, g, ssmap, HW1);

    // final convT (parity-split MFMA) -> out
    dt2_mfma<<<dim3(16, NB), 256, 0, stream>>>(U0, apack2, dt2_b, out);
}